// Round 4
// baseline (3077.484 us; speedup 1.0000x reference)
//
#include <hip/hip_runtime.h>

// ---------------------------------------------------------------------------
// DGNLB fused pipeline.  ALL inputs/outputs are FP32 (reference is jnp.float32).
// B=2, C=64, H=W=64, N=4096.  Attention GEMMs run on bf16 MFMA (operands
// produced bf16 by the projection kernels); everything else fp32.
// ---------------------------------------------------------------------------

typedef float f32x4 __attribute__((ext_vector_type(4)));
typedef __bf16 bf16x8 __attribute__((ext_vector_type(8)));
typedef int int4v __attribute__((ext_vector_type(4)));

#define DI __device__ __forceinline__

DI float bf2f(unsigned short u) { union { unsigned int i; float f; } x; x.i = ((unsigned int)u) << 16; return x.f; }
DI unsigned short f2bf(float f) { union { float f; unsigned int i; } x; x.f = f; unsigned int r = x.i + 0x7fff + ((x.i >> 16) & 1); return (unsigned short)(r >> 16); }
// NaN/inf squash (insurance in softmax paths only).
DI float sane(float x) { return (x > -1e8f) ? ((x < 1e8f) ? x : 1e8f) : -1e8f; }

__global__ __launch_bounds__(256) void diag_fill(float* __restrict__ out, int n, float val)
{
    int i = blockIdx.x * 256 + threadIdx.x;
    if (i < n) out[i] = val;
}

// ---------------------------------------------------------------------------
// NT GEMM: C[M][N] = A[M][K] * B[N][K]^T, bf16 operands, fp32 accum (MFMA).
// 128x128 tile, 4 waves 2x2, each wave 4x4 of 16x16x32 MFMAs, BK=32.
// mode 1: write bf16      mode 3: split-K partial fp32 (slice per blockIdx.z)
// ---------------------------------------------------------------------------
__global__ __launch_bounds__(256) void gemm_nt(
    const unsigned short* __restrict__ A,
    const unsigned short* __restrict__ B,
    void* __restrict__ C,
    int M, int N, int K, int mode)
{
    __shared__ __align__(16) unsigned short As[128 * 32];
    __shared__ __align__(16) unsigned short Bs[128 * 32];
    const int tid  = threadIdx.x;
    const int bm   = blockIdx.y, bn = blockIdx.x;
    const int lane = tid & 63, wid = tid >> 6;
    const int wm   = (wid >> 1) * 64, wn = (wid & 1) * 64;
    const int l16  = lane & 15, quad = lane >> 4;

    f32x4 acc[4][4] = {};

    const int Kc   = K / (int)gridDim.z;
    const int kbeg = (int)blockIdx.z * Kc;
    const int kend = kbeg + Kc;

    for (int k0 = kbeg; k0 < kend; k0 += 32) {
        __syncthreads();
        #pragma unroll
        for (int c = 0; c < 2; c++) {
            int ch = tid + c * 256;               // 512 chunks of 16B per tile
            int row = ch >> 2, ko = (ch & 3) * 8;
            int ar = bm * 128 + row; if (ar > M - 1) ar = M - 1;   // clamp for M=64
            *(int4v*)&As[row * 32 + ko] = *(const int4v*)&A[(long)ar * K + k0 + ko];
            int br = bn * 128 + row;
            *(int4v*)&Bs[row * 32 + ko] = *(const int4v*)&B[(long)br * K + k0 + ko];
        }
        __syncthreads();
        bf16x8 af[4], bfr[4];
        #pragma unroll
        for (int i = 0; i < 4; i++) af[i]  = *(const bf16x8*)&As[(wm + i * 16 + l16) * 32 + quad * 8];
        #pragma unroll
        for (int j = 0; j < 4; j++) bfr[j] = *(const bf16x8*)&Bs[(wn + j * 16 + l16) * 32 + quad * 8];
        #pragma unroll
        for (int i = 0; i < 4; i++)
            #pragma unroll
            for (int j = 0; j < 4; j++)
                acc[i][j] = __builtin_amdgcn_mfma_f32_16x16x32_bf16(af[i], bfr[j], acc[i][j], 0, 0, 0);
    }

    #pragma unroll
    for (int i = 0; i < 4; i++) {
        int rb = bm * 128 + wm + i * 16 + quad * 4;   // C/D: col=lane&15, row=quad*4+reg
        #pragma unroll
        for (int j = 0; j < 4; j++) {
            int col = bn * 128 + wn + j * 16 + l16;
            #pragma unroll
            for (int r = 0; r < 4; r++) {
                int row = rb + r;
                if (row < M) {
                    long idx = (long)row * N + col;
                    float vv = acc[i][j][r];
                    if (mode == 1) ((unsigned short*)C)[idx] = f2bf(vv);
                    else           ((float*)C)[(long)blockIdx.z * M * N + idx] = vv;
                }
            }
        }
    }
}

// ---------------------------------------------------------------------------
// Row softmax over 4096 contiguous bf16 cols, in place (bf16 out).
// ---------------------------------------------------------------------------
__global__ __launch_bounds__(256) void row_softmax(unsigned short* __restrict__ buf)
{
    long row = blockIdx.x;
    unsigned short* p = buf + row * 4096L;
    const int tid = threadIdx.x, lane = tid & 63, wid = tid >> 6;
    float v[16]; float mx = -1e30f;
    #pragma unroll
    for (int t = 0; t < 16; t++) {
        float x = sane(bf2f(p[t * 256 + tid]));
        v[t] = x; mx = fmaxf(mx, x);
    }
    #pragma unroll
    for (int o = 32; o; o >>= 1) mx = fmaxf(mx, __shfl_xor(mx, o, 64));
    __shared__ float rmax[4], rsum[4];
    if (!lane) rmax[wid] = mx;
    __syncthreads();
    mx = fmaxf(fmaxf(rmax[0], rmax[1]), fmaxf(rmax[2], rmax[3]));
    float s = 0.f;
    #pragma unroll
    for (int t = 0; t < 16; t++) { v[t] = __expf(v[t] - mx); s += v[t]; }
    #pragma unroll
    for (int o = 32; o; o >>= 1) s += __shfl_xor(s, o, 64);
    if (!lane) rsum[wid] = s;
    __syncthreads();
    s = rsum[0] + rsum[1] + rsum[2] + rsum[3];
    float inv = 1.f / s;
    #pragma unroll
    for (int t = 0; t < 16; t++) p[t * 256 + tid] = f2bf(v[t] * inv);
}

// ---------------------------------------------------------------------------
// Column softmax (normalize along rows, stride ncol), bf16 in/out, in place.
// ---------------------------------------------------------------------------
__global__ __launch_bounds__(256) void col_softmax(unsigned short* __restrict__ buf, int nrow, int ncol)
{
    const int tid = threadIdx.x;
    const int c = (tid & 63) + blockIdx.x * 64;
    const int rg = tid >> 6;
    unsigned short* p = buf + c;
    float mx = -1e30f, s = 0.f;
    for (int r = rg; r < nrow; r += 4) {
        float x = sane(bf2f(p[(long)r * ncol]));
        float nm = fmaxf(mx, x);
        s = s * __expf(mx - nm) + __expf(x - nm);
        mx = nm;
    }
    __shared__ float smx[4][64], ssm[4][64];
    smx[rg][tid & 63] = mx; ssm[rg][tid & 63] = s;
    __syncthreads();
    int cl = tid & 63;
    float M = fmaxf(fmaxf(smx[0][cl], smx[1][cl]), fmaxf(smx[2][cl], smx[3][cl]));
    float S = 0.f;
    #pragma unroll
    for (int i = 0; i < 4; i++) S += ssm[i][cl] * __expf(smx[i][cl] - M);
    float inv = 1.f / S;
    for (int r = rg; r < nrow; r += 4) {
        long ix = (long)r * ncol;
        float x = sane(bf2f(p[ix]));
        p[ix] = f2bf(__expf(x - M) * inv);
    }
}

// ---------------------------------------------------------------------------
// 1x1 conv projections (fp32 in [B][64][4096], W fp32 [c][i], +bias) -> bf16.
// proj_nc writes out[B][4096][64] (N-major); proj_cn writes out[B][64][4096].
// ---------------------------------------------------------------------------
__global__ __launch_bounds__(256) void proj_nc(
    const float* __restrict__ X, const float* __restrict__ W,
    const float* __restrict__ bias, unsigned short* __restrict__ out)
{
    const int b = blockIdx.y, nt = blockIdx.x, tid = threadIdx.x;
    __shared__ float Xs[64][64];   // [i][n]
    __shared__ float Ws[64][65];   // [i][c]
    __shared__ float Bb[64];
    for (int f = tid; f < 4096; f += 256) {
        int i = f >> 6, n = f & 63;
        Xs[i][n] = X[((long)b * 64 + i) * 4096 + nt * 64 + n];
        Ws[f & 63][f >> 6] = W[f];   // W[c*64+i] -> Ws[i][c]
    }
    if (tid < 64) Bb[tid] = bias[tid];
    __syncthreads();
    const int c = tid & 63, g = tid >> 6;
    float acc[16];
    #pragma unroll
    for (int j = 0; j < 16; j++) acc[j] = Bb[c];
    for (int i = 0; i < 64; i++) {
        float wv = Ws[i][c];
        #pragma unroll
        for (int j = 0; j < 16; j++) acc[j] += wv * Xs[i][g + 4 * j];
    }
    unsigned short* ob = out + ((long)b * 4096 + nt * 64) * 64;
    #pragma unroll
    for (int j = 0; j < 16; j++) ob[(g + 4 * j) * 64 + c] = f2bf(acc[j]);
}

__global__ __launch_bounds__(256) void proj_cn(
    const float* __restrict__ X, const float* __restrict__ W,
    const float* __restrict__ bias, unsigned short* __restrict__ out)
{
    const int b = blockIdx.y, nt = blockIdx.x, tid = threadIdx.x;
    __shared__ float Xs[64][64];   // [i][n]
    __shared__ float Ws[64][64];   // [c][i]
    __shared__ float Bb[64];
    for (int f = tid; f < 4096; f += 256) {
        int i = f >> 6, n = f & 63;
        Xs[i][n] = X[((long)b * 64 + i) * 4096 + nt * 64 + n];
        Ws[f >> 6][f & 63] = W[f];
    }
    if (tid < 64) Bb[tid] = bias[tid];
    __syncthreads();
    const int n = tid & 63, g = tid >> 6;
    float acc[16];
    #pragma unroll
    for (int j = 0; j < 16; j++) acc[j] = Bb[g + 4 * j];
    for (int i = 0; i < 64; i++) {
        float xv = Xs[i][n];
        #pragma unroll
        for (int j = 0; j < 16; j++) acc[j] += Ws[g + 4 * j][i] * xv;
    }
    unsigned short* ob = out + ((long)b * 64) * 4096 + nt * 64;
    #pragma unroll
    for (int j = 0; j < 16; j++) ob[(long)(g + 4 * j) * 4096 + n] = f2bf(acc[j]);
}

// ---------------------------------------------------------------------------
// combine split-K partials: pam = gamma*(sum_k part_k) + x.  64*4096*B elems.
// ---------------------------------------------------------------------------
__global__ __launch_bounds__(256) void combine_pam(
    const float* __restrict__ part, const float* __restrict__ x,
    const float* __restrict__ gammaPtr, float* __restrict__ pam)
{
    int i = blockIdx.x * 256 + threadIdx.x;   // 262144 total
    float s = part[i] + part[262144 + i] + part[2 * 262144 + i] + part[3 * 262144 + i];
    pam[i] = gammaPtr[0] * s + x[i];
}

// ---------------------------------------------------------------------------
// 3x3 conv (SAME) + BN + PReLU, fp32 in [B][64][64][64], fp32 weights [co][ci][3][3].
// ---------------------------------------------------------------------------
__global__ __launch_bounds__(256) void conv3x3_bn(
    const float* __restrict__ X, const float* __restrict__ W9,
    const float* __restrict__ bias,
    const float* __restrict__ bns, const float* __restrict__ bnb,
    const float* __restrict__ bnm, const float* __restrict__ bnv,
    const float* __restrict__ prelu, float* __restrict__ out)
{
    const int b = blockIdx.y, h = blockIdx.x, tid = threadIdx.x;
    __shared__ float Ls[3][64][66];
    __shared__ float ep0[64], ep1[64], ep2[64];
    __shared__ float alpha;
    for (int f = tid; f < 3 * 64 * 64; f += 256) {
        int ky = f >> 12, rem = f & 4095, ci = rem >> 6, w = rem & 63;
        int hh = h + ky - 1;
        Ls[ky][ci][w + 1] = (hh >= 0 && hh < 64) ? X[(((long)b * 64 + ci) * 64 + hh) * 64 + w] : 0.f;
    }
    for (int f = tid; f < 192; f += 256) {
        int ky = f >> 6, ci = f & 63;
        Ls[ky][ci][0] = 0.f; Ls[ky][ci][65] = 0.f;
    }
    if (tid < 64) {
        float inv = bns[tid] * rsqrtf(fmaxf(bnv[tid], 0.f) + 1e-5f);
        ep0[tid] = inv; ep1[tid] = bnb[tid] - bnm[tid] * inv; ep2[tid] = bias[tid];
    }
    if (tid == 0) alpha = prelu[0];
    __syncthreads();
    const int w = tid & 63, g = tid >> 6;   // co = g*16 + j
    float acc[16];
    #pragma unroll
    for (int j = 0; j < 16; j++) acc[j] = ep2[g * 16 + j];
    for (int ci = 0; ci < 64; ci++) {
        float v0 = Ls[0][ci][w], v1 = Ls[0][ci][w + 1], v2 = Ls[0][ci][w + 2];
        float v3 = Ls[1][ci][w], v4 = Ls[1][ci][w + 1], v5 = Ls[1][ci][w + 2];
        float v6 = Ls[2][ci][w], v7 = Ls[2][ci][w + 1], v8 = Ls[2][ci][w + 2];
        #pragma unroll
        for (int j = 0; j < 16; j++) {
            const float* wp = &W9[((g * 16 + j) * 64 + ci) * 9];
            acc[j] += wp[0] * v0 + wp[1] * v1 + wp[2] * v2
                    + wp[3] * v3 + wp[4] * v4 + wp[5] * v5
                    + wp[6] * v6 + wp[7] * v7 + wp[8] * v8;
        }
    }
    #pragma unroll
    for (int j = 0; j < 16; j++) {
        int co = g * 16 + j;
        float y = acc[j] * ep0[co] + ep1[co];
        y = y > 0.f ? y : alpha * y;
        out[(((long)b * 64 + co) * 64 + h) * 64 + w] = y;
    }
}

// ---------------------------------------------------------------------------
// 1x1 conv + BN + PReLU, fp32 in [B][64][4096], fp32 out.
// ---------------------------------------------------------------------------
__global__ __launch_bounds__(256) void conv1x1_bn(
    const float* __restrict__ X, const float* __restrict__ W,
    const float* __restrict__ bias,
    const float* __restrict__ bns, const float* __restrict__ bnb,
    const float* __restrict__ bnm, const float* __restrict__ bnv,
    const float* __restrict__ prelu, float* __restrict__ out)
{
    const int b = blockIdx.y, nt = blockIdx.x, tid = threadIdx.x;
    __shared__ float Xs[64][64];   // [i][n]
    __shared__ float Ws[64][64];   // [c][i]
    __shared__ float ep0[64], ep1[64], ep2[64];
    __shared__ float alpha;
    for (int f = tid; f < 4096; f += 256) {
        int i = f >> 6, n = f & 63;
        Xs[i][n] = X[((long)b * 64 + i) * 4096 + nt * 64 + n];
        Ws[f >> 6][f & 63] = W[f];
    }
    if (tid < 64) {
        float inv = bns[tid] * rsqrtf(fmaxf(bnv[tid], 0.f) + 1e-5f);
        ep0[tid] = inv; ep1[tid] = bnb[tid] - bnm[tid] * inv; ep2[tid] = bias[tid];
    }
    if (tid == 0) alpha = prelu[0];
    __syncthreads();
    const int n = tid & 63, g = tid >> 6;
    float acc[16];
    #pragma unroll
    for (int j = 0; j < 16; j++) acc[j] = ep2[g + 4 * j];
    for (int i = 0; i < 64; i++) {
        float xv = Xs[i][n];
        #pragma unroll
        for (int j = 0; j < 16; j++) acc[j] += Ws[g + 4 * j][i] * xv;
    }
    #pragma unroll
    for (int j = 0; j < 16; j++) {
        int c = g + 4 * j;
        float y = acc[j] * ep0[c] + ep1[c];
        y = y > 0.f ? y : alpha * y;
        out[((long)b * 64 + c) * 4096 + nt * 64 + n] = y;
    }
}

// ---------------------------------------------------------------------------
// 64x64 Gram over K=4096 (fp32 in): out[b][c][d] = sum_n X[c,n]X[d,n].
// ---------------------------------------------------------------------------
__global__ __launch_bounds__(1024) void gram64(
    const float* __restrict__ X, float* __restrict__ out)
{
    const int b = blockIdx.x, tid = threadIdx.x;
    __shared__ float Xs[64][65];
    const int d = tid & 63, g = tid >> 6;   // c = g + 16*j
    float acc[4] = {0.f, 0.f, 0.f, 0.f};
    for (int k0 = 0; k0 < 4096; k0 += 64) {
        __syncthreads();
        for (int f = tid; f < 4096; f += 1024) {
            int ci = f >> 6, kk = f & 63;
            Xs[ci][kk] = X[((long)b * 64 + ci) * 4096 + k0 + kk];
        }
        __syncthreads();
        for (int kk = 0; kk < 64; kk++) {
            float xd = Xs[d][kk];
            #pragma unroll
            for (int j = 0; j < 4; j++) acc[j] += Xs[g + 16 * j][kk] * xd;
        }
    }
    #pragma unroll
    for (int j = 0; j < 4; j++) out[((long)b * 64 + (g + 16 * j)) * 64 + d] = acc[j];
}

// ---------------------------------------------------------------------------
// SE gate: gy2[b][c] = sigmoid(fc2 . relu(fc1 . mean_hw(g)))   (all fp32)
// ---------------------------------------------------------------------------
__global__ __launch_bounds__(256) void se_kernel(
    const float* __restrict__ G, const float* __restrict__ fc1,
    const float* __restrict__ fc2, float* __restrict__ gy2)
{
    const int b = blockIdx.x, tid = threadIdx.x, lane = tid & 63, wid = tid >> 6;
    __shared__ float gy[64], r1[32];
    for (int c = wid; c < 64; c += 4) {
        const float* p = G + ((long)b * 64 + c) * 4096;
        float s = 0.f;
        for (int k = lane; k < 4096; k += 64) s += p[k];
        #pragma unroll
        for (int o = 32; o; o >>= 1) s += __shfl_xor(s, o, 64);
        if (!lane) gy[c] = s * (1.f / 4096.f);
    }
    __syncthreads();
    if (tid < 32) {
        float s = 0.f;
        for (int c = 0; c < 64; c++) s += fc1[tid * 64 + c] * gy[c];
        r1[tid] = fmaxf(s, 0.f);
    }
    __syncthreads();
    if (tid < 64) {
        float s = 0.f;
        for (int r = 0; r < 32; r++) s += fc2[tid * 32 + r] * r1[r];
        gy2[b * 64 + tid] = 1.f / (1.f + __expf(-sane(s)));
    }
}

// ---------------------------------------------------------------------------
// CAM small algebra (64x64 per batch). 64 threads, one row per thread.
// ---------------------------------------------------------------------------
__global__ __launch_bounds__(64) void cam_small(
    const float* __restrict__ gramx, const float* __restrict__ gramg,
    const float* __restrict__ gy2, float* __restrict__ gattc)
{
    const int b = blockIdx.x, tid = threadIdx.x;
    __shared__ float Ac[64][65], Acg[64][65];
    __shared__ float gys[64];
    gys[tid] = gy2[b * 64 + tid];
    __syncthreads();
    {
        const float* r = gramx + ((long)b * 64 + tid) * 64;
        float mx = -1e30f;
        for (int d = 0; d < 64; d++) mx = fmaxf(mx, sane(r[d]));
        float s = 0.f;
        for (int d = 0; d < 64; d++) s += __expf(sane(r[d]) - mx);
        float inv = 1.f / s;
        for (int d = 0; d < 64; d++) Ac[tid][d] = __expf(sane(r[d]) - mx) * inv;
    }
    {
        const float* r = gramg + ((long)b * 64 + tid) * 64;
        float gc = gys[tid];
        float mx = -1e30f;
        for (int d = 0; d < 64; d++) mx = fmaxf(mx, sane(gc * gys[d] * r[d]));
        float s = 0.f;
        for (int d = 0; d < 64; d++) s += __expf(sane(gc * gys[d] * r[d]) - mx);
        float inv = 1.f / s;
        for (int d = 0; d < 64; d++) Acg[tid][d] = __expf(sane(gc * gys[d] * r[d]) - mx) * inv;
    }
    __syncthreads();
    float ge[64];
    float mx1 = -1e30f, mn = 1e30f;
    for (int d = 0; d < 64; d++) {
        float s = 0.f;
        for (int k = 0; k < 64; k++) s += Ac[tid][k] * Acg[k][d];
        ge[d] = s;
        mx1 = fmaxf(mx1, s); mn = fminf(mn, s);
    }
    float M2 = mx1 - mn;   // max of (mx1 - ge)
    float s = 0.f;
    for (int d = 0; d < 64; d++) s += __expf((mx1 - ge[d]) - M2);
    float inv = 1.f / s;
    for (int d = 0; d < 64; d++)
        gattc[((long)b * 64 + tid) * 64 + d] = __expf((mx1 - ge[d]) - M2) * inv;
}

// ---------------------------------------------------------------------------
// cam = gamma_c * (gatt_c @ pam2) + pam2   (fp32)
// ---------------------------------------------------------------------------
__global__ __launch_bounds__(256) void cam_apply(
    const float* __restrict__ pam2, const float* __restrict__ gattc,
    const float* __restrict__ gammaPtr, float* __restrict__ cam)
{
    const int b = blockIdx.y, nt = blockIdx.x, tid = threadIdx.x;
    __shared__ float Xs[64][64];   // [d][n]
    __shared__ float Gt[64][64];   // [c][d]
    for (int f = tid; f < 4096; f += 256) {
        int d = f >> 6, n = f & 63;
        Xs[d][n] = pam2[((long)b * 64 + d) * 4096 + nt * 64 + n];
        Gt[f >> 6][f & 63] = gattc[((long)b * 64 + (f >> 6)) * 64 + (f & 63)];
    }
    __syncthreads();
    const float gamma = gammaPtr[0];
    const int n = tid & 63, g = tid >> 6;
    float acc[16] = {};
    for (int d = 0; d < 64; d++) {
        float xv = Xs[d][n];
        #pragma unroll
        for (int j = 0; j < 16; j++) acc[j] += Gt[g + 4 * j][d] * xv;
    }
    #pragma unroll
    for (int j = 0; j < 16; j++) {
        int c = g + 4 * j;
        cam[((long)b * 64 + c) * 4096 + nt * 64 + n] = gamma * acc[j] + Xs[c][n];
    }
}

// ---------------------------------------------------------------------------
// host
// ---------------------------------------------------------------------------
extern "C" void kernel_launch(void* const* d_in, const int* in_sizes, int n_in,
                              void* d_out, int out_size, void* d_ws, size_t ws_size,
                              hipStream_t stream)
{
    static const int exp_sizes[51] = {
        524288, 524288,
        4096, 64, 4096, 64, 4096, 64, 4096, 64, 4096, 64,
        1, 2048, 2048, 1,
        36864, 64, 64, 64, 64, 64, 1,
        4096, 64, 64, 64, 64, 64, 1,
        36864, 64, 64, 64, 64, 64, 1,
        4096, 64, 64, 64, 64, 64, 1,
        4096, 64, 64, 64, 64, 64, 1
    };
    bool map_ok = (n_in == 51) && (out_size == 524288);
    if (map_ok) for (int i = 0; i < 51; i++) if (in_sizes[i] != exp_sizes[i]) { map_ok = false; break; }

    const int diag_grid = (out_size + 255) / 256;
    if (!map_ok) {
        diag_fill<<<diag_grid, 256, 0, stream>>>((float*)d_out, out_size, 400.0f);
        return;
    }
    const size_t NEED_FULL = 121000000;   // verified available in round 3
    if (ws_size < NEED_FULL) {
        float code = (ws_size >= 88000000) ? 100.0f : (ws_size >= 55000000 ? 200.0f : 300.0f);
        diag_fill<<<diag_grid, 256, 0, stream>>>((float*)d_out, out_size, code);
        return;
    }

    auto IN = [&](int i) { return (const float*)d_in[i]; };
    const float* X = IN(0);
    const float* G = IN(1);

    char* wp_ = (char*)d_ws;
    auto alloc = [&](size_t bytes) -> void* {
        void* p = (void*)wp_;
        wp_ += (bytes + 255) & ~(size_t)255;
        return p;
    };
    unsigned short* qT   = (unsigned short*)alloc(2L * 4096 * 64 * 2);
    unsigned short* kT   = (unsigned short*)alloc(2L * 4096 * 64 * 2);
    unsigned short* qgT  = (unsigned short*)alloc(2L * 4096 * 64 * 2);
    unsigned short* kgT  = (unsigned short*)alloc(2L * 4096 * 64 * 2);
    unsigned short* vC   = (unsigned short*)alloc(2L * 64 * 4096 * 2);
    float* part  = (float*)alloc(4L * 64 * 4096 * 4);
    float* pam   = (float*)alloc(2L * 64 * 4096 * 4);
    float* tbuf  = (float*)alloc(2L * 64 * 4096 * 4);
    float* pam2  = (float*)alloc(2L * 64 * 4096 * 4);
    float* cam   = (float*)alloc(2L * 64 * 4096 * 4);
    float* gramx = (float*)alloc(2L * 64 * 64 * 4);
    float* gramg = (float*)alloc(2L * 64 * 64 * 4);
    float* gy2   = (float*)alloc(2L * 64 * 4);
    float* gattc = (float*)alloc(2L * 64 * 64 * 4);
    unsigned short* att  = (unsigned short*)alloc(4096L * 4096 * 2);   // per-batch reuse
    unsigned short* attg = (unsigned short*)alloc(4096L * 4096 * 2);
    unsigned short* pbuf = (unsigned short*)alloc(4096L * 4096 * 2);
    float* cam2 = tbuf;   // tbuf free after cconv1; reuse for cam2

    // ---- projections (fp32 -> bf16 operands) ----
    proj_nc<<<dim3(64, 2), 256, 0, stream>>>(X, IN(2),  IN(3),  qT);
    proj_nc<<<dim3(64, 2), 256, 0, stream>>>(X, IN(4),  IN(5),  kT);
    proj_nc<<<dim3(64, 2), 256, 0, stream>>>(G, IN(8),  IN(9),  qgT);
    proj_nc<<<dim3(64, 2), 256, 0, stream>>>(G, IN(10), IN(11), kgT);
    proj_cn<<<dim3(64, 2), 256, 0, stream>>>(X, IN(6),  IN(7),  vC);

    // ---- guided position attention, per batch (reuse big buffers) ----
    for (int b = 0; b < 2; b++) {
        const unsigned short* qTb  = qT  + (long)b * 4096 * 64;
        const unsigned short* kTb  = kT  + (long)b * 4096 * 64;
        const unsigned short* qgTb = qgT + (long)b * 4096 * 64;
        const unsigned short* kgTb = kgT + (long)b * 4096 * 64;
        gemm_nt<<<dim3(32, 32, 1), 256, 0, stream>>>(qTb,  kTb,  att,  4096, 4096, 64, 1);
        gemm_nt<<<dim3(32, 32, 1), 256, 0, stream>>>(kgTb, qgTb, attg, 4096, 4096, 64, 1);
        row_softmax<<<4096, 256, 0, stream>>>(att);             // att[n][k] bf16
        col_softmax<<<64, 256, 0, stream>>>(attg, 4096, 4096);  // attg[m][k] = att_g[k][m]
        gemm_nt<<<dim3(32, 32, 1), 256, 0, stream>>>(att, attg, pbuf, 4096, 4096, 4096, 1);
        row_softmax<<<4096, 256, 0, stream>>>(pbuf);
        gemm_nt<<<dim3(32, 1, 4), 256, 0, stream>>>(vC + (long)b * 64 * 4096, pbuf, part,
                                                    64, 4096, 4096, 3);
        combine_pam<<<1024, 256, 0, stream>>>(part, X + (long)b * 64 * 4096, IN(12),
                                              pam + (long)b * 64 * 4096);
    }

    // ---- pconv head ----
    conv3x3_bn<<<dim3(64, 2), 256, 0, stream>>>(pam, IN(16), IN(17), IN(18), IN(19), IN(20), IN(21), IN(22), tbuf);
    conv1x1_bn<<<dim3(64, 2), 256, 0, stream>>>(tbuf, IN(23), IN(24), IN(25), IN(26), IN(27), IN(28), IN(29), pam2);

    // ---- guided channel attention ----
    gram64<<<2, 1024, 0, stream>>>(pam2, gramx);
    gram64<<<2, 1024, 0, stream>>>(G,    gramg);
    se_kernel<<<2, 256, 0, stream>>>(G, IN(13), IN(14), gy2);
    cam_small<<<2, 64, 0, stream>>>(gramx, gramg, gy2, gattc);
    cam_apply<<<dim3(64, 2), 256, 0, stream>>>(pam2, gattc, IN(15), cam);

    // ---- cconv + fconv heads ----
    conv3x3_bn<<<dim3(64, 2), 256, 0, stream>>>(cam, IN(30), IN(31), IN(32), IN(33), IN(34), IN(35), IN(36), pam);  // reuse pam as tmp
    conv1x1_bn<<<dim3(64, 2), 256, 0, stream>>>(pam, IN(37), IN(38), IN(39), IN(40), IN(41), IN(42), IN(43), cam2);
    conv1x1_bn<<<dim3(64, 2), 256, 0, stream>>>(cam2, IN(44), IN(45), IN(46), IN(47), IN(48), IN(49), IN(50), (float*)d_out);
}

// Round 5
// 1997.996 us; speedup vs baseline: 1.5403x; 1.5403x over previous
//
#include <hip/hip_runtime.h>

// ---------------------------------------------------------------------------
// DGNLB fused pipeline.  ALL inputs/outputs are FP32 (reference is jnp.float32).
// B=2, C=64, H=W=64, N=4096.  Attention GEMMs run on bf16 MFMA.
// R5: col_softmax -> 3-phase tiled (coalesced, 256+ blocks);
//     gemm_nt staging via __builtin_amdgcn_global_load_lds width=16.
// ---------------------------------------------------------------------------

typedef float f32x4 __attribute__((ext_vector_type(4)));
typedef __bf16 bf16x8 __attribute__((ext_vector_type(8)));
typedef int int4v __attribute__((ext_vector_type(4)));
typedef unsigned short ushort8 __attribute__((ext_vector_type(8)));

#define DI __device__ __forceinline__

DI float bf2f(unsigned short u) { union { unsigned int i; float f; } x; x.i = ((unsigned int)u) << 16; return x.f; }
DI unsigned short f2bf(float f) { union { float f; unsigned int i; } x; x.f = f; unsigned int r = x.i + 0x7fff + ((x.i >> 16) & 1); return (unsigned short)(r >> 16); }
DI float sane(float x) { return (x > -1e8f) ? ((x < 1e8f) ? x : 1e8f) : -1e8f; }

// async global->LDS, 16B per lane. LDS dest must be wave-uniform base + lane*16.
DI void async16(const unsigned short* g, unsigned short* l) {
    __builtin_amdgcn_global_load_lds(
        (const __attribute__((address_space(1))) void*)g,
        (__attribute__((address_space(3))) void*)l, 16, 0, 0);
}

__global__ __launch_bounds__(256) void diag_fill(float* __restrict__ out, int n, float val)
{
    int i = blockIdx.x * 256 + threadIdx.x;
    if (i < n) out[i] = val;
}

// ---------------------------------------------------------------------------
// NT GEMM: C[M][N] = A[M][K] * B[N][K]^T, bf16 operands, fp32 accum (MFMA).
// 128x128 tile, 4 waves 2x2, each wave 4x4 of 16x16x32 MFMAs, BK=32.
// Staging via global_load_lds dwordx4 (LDS byte offset == tid*16 + 4096*c,
// i.e. wave-uniform base + lane*16 — satisfies the HW constraint).
// mode 1: write bf16      mode 3: split-K partial fp32 (slice per blockIdx.z)
// ---------------------------------------------------------------------------
__global__ __launch_bounds__(256) void gemm_nt(
    const unsigned short* __restrict__ A,
    const unsigned short* __restrict__ B,
    void* __restrict__ C,
    int M, int N, int K, int mode)
{
    __shared__ __align__(16) unsigned short As[128 * 32];
    __shared__ __align__(16) unsigned short Bs[128 * 32];
    const int tid  = threadIdx.x;
    const int bm   = blockIdx.y, bn = blockIdx.x;
    const int lane = tid & 63, wid = tid >> 6;
    const int wm   = (wid >> 1) * 64, wn = (wid & 1) * 64;
    const int l16  = lane & 15, quad = lane >> 4;

    f32x4 acc[4][4] = {};

    const int Kc   = K / (int)gridDim.z;
    const int kbeg = (int)blockIdx.z * Kc;
    const int kend = kbeg + Kc;

    for (int k0 = kbeg; k0 < kend; k0 += 32) {
        __syncthreads();
        #pragma unroll
        for (int c = 0; c < 2; c++) {
            int ch = tid + c * 256;               // 512 chunks of 16B per tile
            int row = ch >> 2, ko = (ch & 3) * 8;
            int ar = bm * 128 + row; if (ar > M - 1) ar = M - 1;   // clamp for M=64
            int br = bn * 128 + row;
            async16(&A[(long)ar * K + k0 + ko], &As[row * 32 + ko]);
            async16(&B[(long)br * K + k0 + ko], &Bs[row * 32 + ko]);
        }
        __syncthreads();
        bf16x8 af[4], bfr[4];
        #pragma unroll
        for (int i = 0; i < 4; i++) af[i]  = *(const bf16x8*)&As[(wm + i * 16 + l16) * 32 + quad * 8];
        #pragma unroll
        for (int j = 0; j < 4; j++) bfr[j] = *(const bf16x8*)&Bs[(wn + j * 16 + l16) * 32 + quad * 8];
        #pragma unroll
        for (int i = 0; i < 4; i++)
            #pragma unroll
            for (int j = 0; j < 4; j++)
                acc[i][j] = __builtin_amdgcn_mfma_f32_16x16x32_bf16(af[i], bfr[j], acc[i][j], 0, 0, 0);
    }

    #pragma unroll
    for (int i = 0; i < 4; i++) {
        int rb = bm * 128 + wm + i * 16 + quad * 4;   // C/D: col=lane&15, row=quad*4+reg
        #pragma unroll
        for (int j = 0; j < 4; j++) {
            int col = bn * 128 + wn + j * 16 + l16;
            #pragma unroll
            for (int r = 0; r < 4; r++) {
                int row = rb + r;
                if (row < M) {
                    long idx = (long)row * N + col;
                    float vv = acc[i][j][r];
                    if (mode == 1) ((unsigned short*)C)[idx] = f2bf(vv);
                    else           ((float*)C)[(long)blockIdx.z * M * N + idx] = vv;
                }
            }
        }
    }
}

// ---------------------------------------------------------------------------
// Row softmax over 4096 contiguous bf16 cols, in place (bf16 out).
// ---------------------------------------------------------------------------
__global__ __launch_bounds__(256) void row_softmax(unsigned short* __restrict__ buf)
{
    long row = blockIdx.x;
    unsigned short* p = buf + row * 4096L;
    const int tid = threadIdx.x, lane = tid & 63, wid = tid >> 6;
    float v[16]; float mx = -1e30f;
    #pragma unroll
    for (int t = 0; t < 16; t++) {
        float x = sane(bf2f(p[t * 256 + tid]));
        v[t] = x; mx = fmaxf(mx, x);
    }
    #pragma unroll
    for (int o = 32; o; o >>= 1) mx = fmaxf(mx, __shfl_xor(mx, o, 64));
    __shared__ float rmax[4], rsum[4];
    if (!lane) rmax[wid] = mx;
    __syncthreads();
    mx = fmaxf(fmaxf(rmax[0], rmax[1]), fmaxf(rmax[2], rmax[3]));
    float s = 0.f;
    #pragma unroll
    for (int t = 0; t < 16; t++) { v[t] = __expf(v[t] - mx); s += v[t]; }
    #pragma unroll
    for (int o = 32; o; o >>= 1) s += __shfl_xor(s, o, 64);
    if (!lane) rsum[wid] = s;
    __syncthreads();
    s = rsum[0] + rsum[1] + rsum[2] + rsum[3];
    float inv = 1.f / s;
    #pragma unroll
    for (int t = 0; t < 16; t++) p[t * 256 + tid] = f2bf(v[t] * inv);
}

// ---------------------------------------------------------------------------
// Column softmax (4096x4096 bf16, normalize down the rows), 3 phases.
// Tiling: 512 cols x 128 rows per block; thread = 8 cols (ushort8) x 32 rows.
// ---------------------------------------------------------------------------
__global__ __launch_bounds__(256) void colsm_partial(
    const unsigned short* __restrict__ buf,
    float* __restrict__ pmx, float* __restrict__ psum)
{
    const int tid = threadIdx.x;
    const int colgrp = tid & 63, rg = tid >> 6;
    const int cbase = blockIdx.x * 512 + colgrp * 8;
    const int r0 = blockIdx.y * 128 + rg * 32;
    const unsigned short* p = buf + (long)r0 * 4096 + cbase;
    float mx[8], s[8];
    #pragma unroll
    for (int j = 0; j < 8; j++) { mx[j] = -1e30f; s[j] = 0.f; }
    for (int r = 0; r < 32; r++) {
        ushort8 v = *(const ushort8*)(p + (long)r * 4096);
        #pragma unroll
        for (int j = 0; j < 8; j++) {
            float x = sane(bf2f(v[j]));
            float nm = fmaxf(mx[j], x);
            s[j] = s[j] * __expf(mx[j] - nm) + __expf(x - nm);
            mx[j] = nm;
        }
    }
    __shared__ float smx[4][512], ssm[4][512];
    #pragma unroll
    for (int j = 0; j < 8; j++) { smx[rg][colgrp * 8 + j] = mx[j]; ssm[rg][colgrp * 8 + j] = s[j]; }
    __syncthreads();
    for (int c = tid; c < 512; c += 256) {
        float M = fmaxf(fmaxf(smx[0][c], smx[1][c]), fmaxf(smx[2][c], smx[3][c]));
        float S = 0.f;
        #pragma unroll
        for (int i = 0; i < 4; i++) S += ssm[i][c] * __expf(smx[i][c] - M);
        int col = blockIdx.x * 512 + c;
        pmx[blockIdx.y * 4096 + col] = M;
        psum[blockIdx.y * 4096 + col] = S;
    }
}

__global__ __launch_bounds__(256) void colsm_combine(
    const float* __restrict__ pmx, const float* __restrict__ psum,
    float* __restrict__ gM, float* __restrict__ gInv)
{
    int col = blockIdx.x * 256 + threadIdx.x;   // grid 16
    float M = -1e30f;
    for (int ch = 0; ch < 32; ch++) M = fmaxf(M, pmx[ch * 4096 + col]);
    float S = 0.f;
    for (int ch = 0; ch < 32; ch++) S += psum[ch * 4096 + col] * __expf(pmx[ch * 4096 + col] - M);
    gM[col] = M;
    gInv[col] = 1.f / S;
}

__global__ __launch_bounds__(256) void colsm_norm(
    unsigned short* __restrict__ buf,
    const float* __restrict__ gM, const float* __restrict__ gInv)
{
    const int tid = threadIdx.x;
    const int colgrp = tid & 63, rg = tid >> 6;
    const int cbase = blockIdx.x * 512 + colgrp * 8;
    const int r0 = blockIdx.y * 128 + rg * 32;
    unsigned short* p = buf + (long)r0 * 4096 + cbase;
    float M[8], inv[8];
    #pragma unroll
    for (int j = 0; j < 8; j++) { M[j] = gM[cbase + j]; inv[j] = gInv[cbase + j]; }
    for (int r = 0; r < 32; r++) {
        ushort8 v = *(const ushort8*)(p + (long)r * 4096);
        ushort8 o;
        #pragma unroll
        for (int j = 0; j < 8; j++) o[j] = f2bf(__expf(sane(bf2f(v[j])) - M[j]) * inv[j]);
        *(ushort8*)(p + (long)r * 4096) = o;
    }
}

// ---------------------------------------------------------------------------
// 1x1 conv projections (fp32 in [B][64][4096], W fp32 [c][i], +bias) -> bf16.
// ---------------------------------------------------------------------------
__global__ __launch_bounds__(256) void proj_nc(
    const float* __restrict__ X, const float* __restrict__ W,
    const float* __restrict__ bias, unsigned short* __restrict__ out)
{
    const int b = blockIdx.y, nt = blockIdx.x, tid = threadIdx.x;
    __shared__ float Xs[64][64];   // [i][n]
    __shared__ float Ws[64][65];   // [i][c]
    __shared__ float Bb[64];
    for (int f = tid; f < 4096; f += 256) {
        int i = f >> 6, n = f & 63;
        Xs[i][n] = X[((long)b * 64 + i) * 4096 + nt * 64 + n];
        Ws[f & 63][f >> 6] = W[f];   // W[c*64+i] -> Ws[i][c]
    }
    if (tid < 64) Bb[tid] = bias[tid];
    __syncthreads();
    const int c = tid & 63, g = tid >> 6;
    float acc[16];
    #pragma unroll
    for (int j = 0; j < 16; j++) acc[j] = Bb[c];
    for (int i = 0; i < 64; i++) {
        float wv = Ws[i][c];
        #pragma unroll
        for (int j = 0; j < 16; j++) acc[j] += wv * Xs[i][g + 4 * j];
    }
    unsigned short* ob = out + ((long)b * 4096 + nt * 64) * 64;
    #pragma unroll
    for (int j = 0; j < 16; j++) ob[(g + 4 * j) * 64 + c] = f2bf(acc[j]);
}

__global__ __launch_bounds__(256) void proj_cn(
    const float* __restrict__ X, const float* __restrict__ W,
    const float* __restrict__ bias, unsigned short* __restrict__ out)
{
    const int b = blockIdx.y, nt = blockIdx.x, tid = threadIdx.x;
    __shared__ float Xs[64][64];   // [i][n]
    __shared__ float Ws[64][64];   // [c][i]
    __shared__ float Bb[64];
    for (int f = tid; f < 4096; f += 256) {
        int i = f >> 6, n = f & 63;
        Xs[i][n] = X[((long)b * 64 + i) * 4096 + nt * 64 + n];
        Ws[f >> 6][f & 63] = W[f];
    }
    if (tid < 64) Bb[tid] = bias[tid];
    __syncthreads();
    const int n = tid & 63, g = tid >> 6;
    float acc[16];
    #pragma unroll
    for (int j = 0; j < 16; j++) acc[j] = Bb[g + 4 * j];
    for (int i = 0; i < 64; i++) {
        float xv = Xs[i][n];
        #pragma unroll
        for (int j = 0; j < 16; j++) acc[j] += Ws[g + 4 * j][i] * xv;
    }
    unsigned short* ob = out + ((long)b * 64) * 4096 + nt * 64;
    #pragma unroll
    for (int j = 0; j < 16; j++) ob[(long)(g + 4 * j) * 4096 + n] = f2bf(acc[j]);
}

// ---------------------------------------------------------------------------
// combine split-K partials: pam = gamma*(sum_k part_k) + x.
// ---------------------------------------------------------------------------
__global__ __launch_bounds__(256) void combine_pam(
    const float* __restrict__ part, const float* __restrict__ x,
    const float* __restrict__ gammaPtr, float* __restrict__ pam)
{
    int i = blockIdx.x * 256 + threadIdx.x;   // 262144 total
    float s = part[i] + part[262144 + i] + part[2 * 262144 + i] + part[3 * 262144 + i];
    pam[i] = gammaPtr[0] * s + x[i];
}

// ---------------------------------------------------------------------------
// 3x3 conv (SAME) + BN + PReLU, fp32.
// ---------------------------------------------------------------------------
__global__ __launch_bounds__(256) void conv3x3_bn(
    const float* __restrict__ X, const float* __restrict__ W9,
    const float* __restrict__ bias,
    const float* __restrict__ bns, const float* __restrict__ bnb,
    const float* __restrict__ bnm, const float* __restrict__ bnv,
    const float* __restrict__ prelu, float* __restrict__ out)
{
    const int b = blockIdx.y, h = blockIdx.x, tid = threadIdx.x;
    __shared__ float Ls[3][64][66];
    __shared__ float ep0[64], ep1[64], ep2[64];
    __shared__ float alpha;
    for (int f = tid; f < 3 * 64 * 64; f += 256) {
        int ky = f >> 12, rem = f & 4095, ci = rem >> 6, w = rem & 63;
        int hh = h + ky - 1;
        Ls[ky][ci][w + 1] = (hh >= 0 && hh < 64) ? X[(((long)b * 64 + ci) * 64 + hh) * 64 + w] : 0.f;
    }
    for (int f = tid; f < 192; f += 256) {
        int ky = f >> 6, ci = f & 63;
        Ls[ky][ci][0] = 0.f; Ls[ky][ci][65] = 0.f;
    }
    if (tid < 64) {
        float inv = bns[tid] * rsqrtf(fmaxf(bnv[tid], 0.f) + 1e-5f);
        ep0[tid] = inv; ep1[tid] = bnb[tid] - bnm[tid] * inv; ep2[tid] = bias[tid];
    }
    if (tid == 0) alpha = prelu[0];
    __syncthreads();
    const int w = tid & 63, g = tid >> 6;   // co = g*16 + j
    float acc[16];
    #pragma unroll
    for (int j = 0; j < 16; j++) acc[j] = ep2[g * 16 + j];
    for (int ci = 0; ci < 64; ci++) {
        float v0 = Ls[0][ci][w], v1 = Ls[0][ci][w + 1], v2 = Ls[0][ci][w + 2];
        float v3 = Ls[1][ci][w], v4 = Ls[1][ci][w + 1], v5 = Ls[1][ci][w + 2];
        float v6 = Ls[2][ci][w], v7 = Ls[2][ci][w + 1], v8 = Ls[2][ci][w + 2];
        #pragma unroll
        for (int j = 0; j < 16; j++) {
            const float* wp = &W9[((g * 16 + j) * 64 + ci) * 9];
            acc[j] += wp[0] * v0 + wp[1] * v1 + wp[2] * v2
                    + wp[3] * v3 + wp[4] * v4 + wp[5] * v5
                    + wp[6] * v6 + wp[7] * v7 + wp[8] * v8;
        }
    }
    #pragma unroll
    for (int j = 0; j < 16; j++) {
        int co = g * 16 + j;
        float y = acc[j] * ep0[co] + ep1[co];
        y = y > 0.f ? y : alpha * y;
        out[(((long)b * 64 + co) * 64 + h) * 64 + w] = y;
    }
}

// ---------------------------------------------------------------------------
// 1x1 conv + BN + PReLU, fp32.
// ---------------------------------------------------------------------------
__global__ __launch_bounds__(256) void conv1x1_bn(
    const float* __restrict__ X, const float* __restrict__ W,
    const float* __restrict__ bias,
    const float* __restrict__ bns, const float* __restrict__ bnb,
    const float* __restrict__ bnm, const float* __restrict__ bnv,
    const float* __restrict__ prelu, float* __restrict__ out)
{
    const int b = blockIdx.y, nt = blockIdx.x, tid = threadIdx.x;
    __shared__ float Xs[64][64];   // [i][n]
    __shared__ float Ws[64][64];   // [c][i]
    __shared__ float ep0[64], ep1[64], ep2[64];
    __shared__ float alpha;
    for (int f = tid; f < 4096; f += 256) {
        int i = f >> 6, n = f & 63;
        Xs[i][n] = X[((long)b * 64 + i) * 4096 + nt * 64 + n];
        Ws[f >> 6][f & 63] = W[f];
    }
    if (tid < 64) {
        float inv = bns[tid] * rsqrtf(fmaxf(bnv[tid], 0.f) + 1e-5f);
        ep0[tid] = inv; ep1[tid] = bnb[tid] - bnm[tid] * inv; ep2[tid] = bias[tid];
    }
    if (tid == 0) alpha = prelu[0];
    __syncthreads();
    const int n = tid & 63, g = tid >> 6;
    float acc[16];
    #pragma unroll
    for (int j = 0; j < 16; j++) acc[j] = ep2[g + 4 * j];
    for (int i = 0; i < 64; i++) {
        float xv = Xs[i][n];
        #pragma unroll
        for (int j = 0; j < 16; j++) acc[j] += Ws[g + 4 * j][i] * xv;
    }
    #pragma unroll
    for (int j = 0; j < 16; j++) {
        int c = g + 4 * j;
        float y = acc[j] * ep0[c] + ep1[c];
        y = y > 0.f ? y : alpha * y;
        out[((long)b * 64 + c) * 4096 + nt * 64 + n] = y;
    }
}

// ---------------------------------------------------------------------------
// 64x64 Gram over K=4096 (fp32 in): out[b][c][d] = sum_n X[c,n]X[d,n].
// ---------------------------------------------------------------------------
__global__ __launch_bounds__(1024) void gram64(
    const float* __restrict__ X, float* __restrict__ out)
{
    const int b = blockIdx.x, tid = threadIdx.x;
    __shared__ float Xs[64][65];
    const int d = tid & 63, g = tid >> 6;   // c = g + 16*j
    float acc[4] = {0.f, 0.f, 0.f, 0.f};
    for (int k0 = 0; k0 < 4096; k0 += 64) {
        __syncthreads();
        for (int f = tid; f < 4096; f += 1024) {
            int ci = f >> 6, kk = f & 63;
            Xs[ci][kk] = X[((long)b * 64 + ci) * 4096 + k0 + kk];
        }
        __syncthreads();
        for (int kk = 0; kk < 64; kk++) {
            float xd = Xs[d][kk];
            #pragma unroll
            for (int j = 0; j < 4; j++) acc[j] += Xs[g + 16 * j][kk] * xd;
        }
    }
    #pragma unroll
    for (int j = 0; j < 4; j++) out[((long)b * 64 + (g + 16 * j)) * 64 + d] = acc[j];
}

// ---------------------------------------------------------------------------
// SE gate: gy2[b][c] = sigmoid(fc2 . relu(fc1 . mean_hw(g)))   (all fp32)
// ---------------------------------------------------------------------------
__global__ __launch_bounds__(256) void se_kernel(
    const float* __restrict__ G, const float* __restrict__ fc1,
    const float* __restrict__ fc2, float* __restrict__ gy2)
{
    const int b = blockIdx.x, tid = threadIdx.x, lane = tid & 63, wid = tid >> 6;
    __shared__ float gy[64], r1[32];
    for (int c = wid; c < 64; c += 4) {
        const float* p = G + ((long)b * 64 + c) * 4096;
        float s = 0.f;
        for (int k = lane; k < 4096; k += 64) s += p[k];
        #pragma unroll
        for (int o = 32; o; o >>= 1) s += __shfl_xor(s, o, 64);
        if (!lane) gy[c] = s * (1.f / 4096.f);
    }
    __syncthreads();
    if (tid < 32) {
        float s = 0.f;
        for (int c = 0; c < 64; c++) s += fc1[tid * 64 + c] * gy[c];
        r1[tid] = fmaxf(s, 0.f);
    }
    __syncthreads();
    if (tid < 64) {
        float s = 0.f;
        for (int r = 0; r < 32; r++) s += fc2[tid * 32 + r] * r1[r];
        gy2[b * 64 + tid] = 1.f / (1.f + __expf(-sane(s)));
    }
}

// ---------------------------------------------------------------------------
// CAM small algebra (64x64 per batch). 64 threads, one row per thread.
// ---------------------------------------------------------------------------
__global__ __launch_bounds__(64) void cam_small(
    const float* __restrict__ gramx, const float* __restrict__ gramg,
    const float* __restrict__ gy2, float* __restrict__ gattc)
{
    const int b = blockIdx.x, tid = threadIdx.x;
    __shared__ float Ac[64][65], Acg[64][65];
    __shared__ float gys[64];
    gys[tid] = gy2[b * 64 + tid];
    __syncthreads();
    {
        const float* r = gramx + ((long)b * 64 + tid) * 64;
        float mx = -1e30f;
        for (int d = 0; d < 64; d++) mx = fmaxf(mx, sane(r[d]));
        float s = 0.f;
        for (int d = 0; d < 64; d++) s += __expf(sane(r[d]) - mx);
        float inv = 1.f / s;
        for (int d = 0; d < 64; d++) Ac[tid][d] = __expf(sane(r[d]) - mx) * inv;
    }
    {
        const float* r = gramg + ((long)b * 64 + tid) * 64;
        float gc = gys[tid];
        float mx = -1e30f;
        for (int d = 0; d < 64; d++) mx = fmaxf(mx, sane(gc * gys[d] * r[d]));
        float s = 0.f;
        for (int d = 0; d < 64; d++) s += __expf(sane(gc * gys[d] * r[d]) - mx);
        float inv = 1.f / s;
        for (int d = 0; d < 64; d++) Acg[tid][d] = __expf(sane(gc * gys[d] * r[d]) - mx) * inv;
    }
    __syncthreads();
    float ge[64];
    float mx1 = -1e30f, mn = 1e30f;
    for (int d = 0; d < 64; d++) {
        float s = 0.f;
        for (int k = 0; k < 64; k++) s += Ac[tid][k] * Acg[k][d];
        ge[d] = s;
        mx1 = fmaxf(mx1, s); mn = fminf(mn, s);
    }
    float M2 = mx1 - mn;   // max of (mx1 - ge)
    float s = 0.f;
    for (int d = 0; d < 64; d++) s += __expf((mx1 - ge[d]) - M2);
    float inv = 1.f / s;
    for (int d = 0; d < 64; d++)
        gattc[((long)b * 64 + tid) * 64 + d] = __expf((mx1 - ge[d]) - M2) * inv;
}

// ---------------------------------------------------------------------------
// cam = gamma_c * (gatt_c @ pam2) + pam2   (fp32)
// ---------------------------------------------------------------------------
__global__ __launch_bounds__(256) void cam_apply(
    const float* __restrict__ pam2, const float* __restrict__ gattc,
    const float* __restrict__ gammaPtr, float* __restrict__ cam)
{
    const int b = blockIdx.y, nt = blockIdx.x, tid = threadIdx.x;
    __shared__ float Xs[64][64];   // [d][n]
    __shared__ float Gt[64][64];   // [c][d]
    for (int f = tid; f < 4096; f += 256) {
        int d = f >> 6, n = f & 63;
        Xs[d][n] = pam2[((long)b * 64 + d) * 4096 + nt * 64 + n];
        Gt[f >> 6][f & 63] = gattc[((long)b * 64 + (f >> 6)) * 64 + (f & 63)];
    }
    __syncthreads();
    const float gamma = gammaPtr[0];
    const int n = tid & 63, g = tid >> 6;
    float acc[16] = {};
    for (int d = 0; d < 64; d++) {
        float xv = Xs[d][n];
        #pragma unroll
        for (int j = 0; j < 16; j++) acc[j] += Gt[g + 4 * j][d] * xv;
    }
    #pragma unroll
    for (int j = 0; j < 16; j++) {
        int c = g + 4 * j;
        cam[((long)b * 64 + c) * 4096 + nt * 64 + n] = gamma * acc[j] + Xs[c][n];
    }
}

// ---------------------------------------------------------------------------
// host
// ---------------------------------------------------------------------------
extern "C" void kernel_launch(void* const* d_in, const int* in_sizes, int n_in,
                              void* d_out, int out_size, void* d_ws, size_t ws_size,
                              hipStream_t stream)
{
    static const int exp_sizes[51] = {
        524288, 524288,
        4096, 64, 4096, 64, 4096, 64, 4096, 64, 4096, 64,
        1, 2048, 2048, 1,
        36864, 64, 64, 64, 64, 64, 1,
        4096, 64, 64, 64, 64, 64, 1,
        36864, 64, 64, 64, 64, 64, 1,
        4096, 64, 64, 64, 64, 64, 1,
        4096, 64, 64, 64, 64, 64, 1
    };
    bool map_ok = (n_in == 51) && (out_size == 524288);
    if (map_ok) for (int i = 0; i < 51; i++) if (in_sizes[i] != exp_sizes[i]) { map_ok = false; break; }

    const int diag_grid = (out_size + 255) / 256;
    if (!map_ok) {
        diag_fill<<<diag_grid, 256, 0, stream>>>((float*)d_out, out_size, 400.0f);
        return;
    }
    const size_t NEED_FULL = 121000000;   // verified available in round 3/4
    if (ws_size < NEED_FULL) {
        float code = (ws_size >= 88000000) ? 100.0f : (ws_size >= 55000000 ? 200.0f : 300.0f);
        diag_fill<<<diag_grid, 256, 0, stream>>>((float*)d_out, out_size, code);
        return;
    }

    auto IN = [&](int i) { return (const float*)d_in[i]; };
    const float* X = IN(0);
    const float* G = IN(1);

    char* wp_ = (char*)d_ws;
    auto alloc = [&](size_t bytes) -> void* {
        void* p = (void*)wp_;
        wp_ += (bytes + 255) & ~(size_t)255;
        return p;
    };
    unsigned short* qT   = (unsigned short*)alloc(2L * 4096 * 64 * 2);
    unsigned short* kT   = (unsigned short*)alloc(2L * 4096 * 64 * 2);
    unsigned short* qgT  = (unsigned short*)alloc(2L * 4096 * 64 * 2);
    unsigned short* kgT  = (unsigned short*)alloc(2L * 4096 * 64 * 2);
    unsigned short* vC   = (unsigned short*)alloc(2L * 64 * 4096 * 2);
    float* part  = (float*)alloc(4L * 64 * 4096 * 4);
    float* pam   = (float*)alloc(2L * 64 * 4096 * 4);
    float* tbuf  = (float*)alloc(2L * 64 * 4096 * 4);
    float* pam2  = (float*)alloc(2L * 64 * 4096 * 4);
    float* cam   = (float*)alloc(2L * 64 * 4096 * 4);
    float* gramx = (float*)alloc(2L * 64 * 64 * 4);
    float* gramg = (float*)alloc(2L * 64 * 64 * 4);
    float* gy2   = (float*)alloc(2L * 64 * 4);
    float* gattc = (float*)alloc(2L * 64 * 64 * 4);
    float* pmx   = (float*)alloc(32L * 4096 * 4);
    float* psum  = (float*)alloc(32L * 4096 * 4);
    float* gM    = (float*)alloc(4096L * 4);
    float* gInv  = (float*)alloc(4096L * 4);
    unsigned short* att  = (unsigned short*)alloc(4096L * 4096 * 2);   // per-batch reuse
    unsigned short* attg = (unsigned short*)alloc(4096L * 4096 * 2);
    unsigned short* pbuf = (unsigned short*)alloc(4096L * 4096 * 2);
    float* cam2 = tbuf;   // tbuf free after cconv1; reuse for cam2

    // ---- projections (fp32 -> bf16 operands) ----
    proj_nc<<<dim3(64, 2), 256, 0, stream>>>(X, IN(2),  IN(3),  qT);
    proj_nc<<<dim3(64, 2), 256, 0, stream>>>(X, IN(4),  IN(5),  kT);
    proj_nc<<<dim3(64, 2), 256, 0, stream>>>(G, IN(8),  IN(9),  qgT);
    proj_nc<<<dim3(64, 2), 256, 0, stream>>>(G, IN(10), IN(11), kgT);
    proj_cn<<<dim3(64, 2), 256, 0, stream>>>(X, IN(6),  IN(7),  vC);

    // ---- guided position attention, per batch (reuse big buffers) ----
    for (int b = 0; b < 2; b++) {
        const unsigned short* qTb  = qT  + (long)b * 4096 * 64;
        const unsigned short* kTb  = kT  + (long)b * 4096 * 64;
        const unsigned short* qgTb = qgT + (long)b * 4096 * 64;
        const unsigned short* kgTb = kgT + (long)b * 4096 * 64;
        gemm_nt<<<dim3(32, 32, 1), 256, 0, stream>>>(qTb,  kTb,  att,  4096, 4096, 64, 1);
        gemm_nt<<<dim3(32, 32, 1), 256, 0, stream>>>(kgTb, qgTb, attg, 4096, 4096, 64, 1);
        row_softmax<<<4096, 256, 0, stream>>>(att);             // att[n][k] bf16
        // col softmax of attg (3-phase, coalesced)
        colsm_partial<<<dim3(8, 32), 256, 0, stream>>>(attg, pmx, psum);
        colsm_combine<<<16, 256, 0, stream>>>(pmx, psum, gM, gInv);
        colsm_norm<<<dim3(8, 32), 256, 0, stream>>>(attg, gM, gInv);
        gemm_nt<<<dim3(32, 32, 1), 256, 0, stream>>>(att, attg, pbuf, 4096, 4096, 4096, 1);
        row_softmax<<<4096, 256, 0, stream>>>(pbuf);
        gemm_nt<<<dim3(32, 1, 4), 256, 0, stream>>>(vC + (long)b * 64 * 4096, pbuf, part,
                                                    64, 4096, 4096, 3);
        combine_pam<<<1024, 256, 0, stream>>>(part, X + (long)b * 64 * 4096, IN(12),
                                              pam + (long)b * 64 * 4096);
    }

    // ---- pconv head ----
    conv3x3_bn<<<dim3(64, 2), 256, 0, stream>>>(pam, IN(16), IN(17), IN(18), IN(19), IN(20), IN(21), IN(22), tbuf);
    conv1x1_bn<<<dim3(64, 2), 256, 0, stream>>>(tbuf, IN(23), IN(24), IN(25), IN(26), IN(27), IN(28), IN(29), pam2);

    // ---- guided channel attention ----
    gram64<<<2, 1024, 0, stream>>>(pam2, gramx);
    gram64<<<2, 1024, 0, stream>>>(G,    gramg);
    se_kernel<<<2, 256, 0, stream>>>(G, IN(13), IN(14), gy2);
    cam_small<<<2, 64, 0, stream>>>(gramx, gramg, gy2, gattc);
    cam_apply<<<dim3(64, 2), 256, 0, stream>>>(pam2, gattc, IN(15), cam);

    // ---- cconv + fconv heads ----
    conv3x3_bn<<<dim3(64, 2), 256, 0, stream>>>(cam, IN(30), IN(31), IN(32), IN(33), IN(34), IN(35), IN(36), pam);  // reuse pam as tmp
    conv1x1_bn<<<dim3(64, 2), 256, 0, stream>>>(pam, IN(37), IN(38), IN(39), IN(40), IN(41), IN(42), IN(43), cam2);
    conv1x1_bn<<<dim3(64, 2), 256, 0, stream>>>(cam2, IN(44), IN(45), IN(46), IN(47), IN(48), IN(49), IN(50), (float*)d_out);
}

// Round 6
// 1393.070 us; speedup vs baseline: 2.2091x; 1.4342x over previous
//
#include <hip/hip_runtime.h>

// ---------------------------------------------------------------------------
// DGNLB fused pipeline.  ALL inputs/outputs are FP32 (reference is jnp.float32).
// B=2, C=64, H=W=64, N=4096.  Attention GEMMs run on bf16 MFMA.
// R6: gram64 (2 blocks, 376us each) -> split-K gram_partial (128 blocks,
//     atomicAdd combine).  Everything else unchanged from the R5 winner.
// ---------------------------------------------------------------------------

typedef float f32x4 __attribute__((ext_vector_type(4)));
typedef __bf16 bf16x8 __attribute__((ext_vector_type(8)));
typedef int int4v __attribute__((ext_vector_type(4)));
typedef unsigned short ushort8 __attribute__((ext_vector_type(8)));

#define DI __device__ __forceinline__

DI float bf2f(unsigned short u) { union { unsigned int i; float f; } x; x.i = ((unsigned int)u) << 16; return x.f; }
DI unsigned short f2bf(float f) { union { float f; unsigned int i; } x; x.f = f; unsigned int r = x.i + 0x7fff + ((x.i >> 16) & 1); return (unsigned short)(r >> 16); }
DI float sane(float x) { return (x > -1e8f) ? ((x < 1e8f) ? x : 1e8f) : -1e8f; }

// async global->LDS, 16B per lane. LDS dest must be wave-uniform base + lane*16.
DI void async16(const unsigned short* g, unsigned short* l) {
    __builtin_amdgcn_global_load_lds(
        (const __attribute__((address_space(1))) void*)g,
        (__attribute__((address_space(3))) void*)l, 16, 0, 0);
}

__global__ __launch_bounds__(256) void diag_fill(float* __restrict__ out, int n, float val)
{
    int i = blockIdx.x * 256 + threadIdx.x;
    if (i < n) out[i] = val;
}

// ---------------------------------------------------------------------------
// NT GEMM: C[M][N] = A[M][K] * B[N][K]^T, bf16 operands, fp32 accum (MFMA).
// 128x128 tile, 4 waves 2x2, each wave 4x4 of 16x16x32 MFMAs, BK=32.
// mode 1: write bf16      mode 3: split-K partial fp32 (slice per blockIdx.z)
// ---------------------------------------------------------------------------
__global__ __launch_bounds__(256) void gemm_nt(
    const unsigned short* __restrict__ A,
    const unsigned short* __restrict__ B,
    void* __restrict__ C,
    int M, int N, int K, int mode)
{
    __shared__ __align__(16) unsigned short As[128 * 32];
    __shared__ __align__(16) unsigned short Bs[128 * 32];
    const int tid  = threadIdx.x;
    const int bm   = blockIdx.y, bn = blockIdx.x;
    const int lane = tid & 63, wid = tid >> 6;
    const int wm   = (wid >> 1) * 64, wn = (wid & 1) * 64;
    const int l16  = lane & 15, quad = lane >> 4;

    f32x4 acc[4][4] = {};

    const int Kc   = K / (int)gridDim.z;
    const int kbeg = (int)blockIdx.z * Kc;
    const int kend = kbeg + Kc;

    for (int k0 = kbeg; k0 < kend; k0 += 32) {
        __syncthreads();
        #pragma unroll
        for (int c = 0; c < 2; c++) {
            int ch = tid + c * 256;               // 512 chunks of 16B per tile
            int row = ch >> 2, ko = (ch & 3) * 8;
            int ar = bm * 128 + row; if (ar > M - 1) ar = M - 1;   // clamp for M=64
            int br = bn * 128 + row;
            async16(&A[(long)ar * K + k0 + ko], &As[row * 32 + ko]);
            async16(&B[(long)br * K + k0 + ko], &Bs[row * 32 + ko]);
        }
        __syncthreads();
        bf16x8 af[4], bfr[4];
        #pragma unroll
        for (int i = 0; i < 4; i++) af[i]  = *(const bf16x8*)&As[(wm + i * 16 + l16) * 32 + quad * 8];
        #pragma unroll
        for (int j = 0; j < 4; j++) bfr[j] = *(const bf16x8*)&Bs[(wn + j * 16 + l16) * 32 + quad * 8];
        #pragma unroll
        for (int i = 0; i < 4; i++)
            #pragma unroll
            for (int j = 0; j < 4; j++)
                acc[i][j] = __builtin_amdgcn_mfma_f32_16x16x32_bf16(af[i], bfr[j], acc[i][j], 0, 0, 0);
    }

    #pragma unroll
    for (int i = 0; i < 4; i++) {
        int rb = bm * 128 + wm + i * 16 + quad * 4;   // C/D: col=lane&15, row=quad*4+reg
        #pragma unroll
        for (int j = 0; j < 4; j++) {
            int col = bn * 128 + wn + j * 16 + l16;
            #pragma unroll
            for (int r = 0; r < 4; r++) {
                int row = rb + r;
                if (row < M) {
                    long idx = (long)row * N + col;
                    float vv = acc[i][j][r];
                    if (mode == 1) ((unsigned short*)C)[idx] = f2bf(vv);
                    else           ((float*)C)[(long)blockIdx.z * M * N + idx] = vv;
                }
            }
        }
    }
}

// ---------------------------------------------------------------------------
// Row softmax over 4096 contiguous bf16 cols, in place (bf16 out).
// ---------------------------------------------------------------------------
__global__ __launch_bounds__(256) void row_softmax(unsigned short* __restrict__ buf)
{
    long row = blockIdx.x;
    unsigned short* p = buf + row * 4096L;
    const int tid = threadIdx.x, lane = tid & 63, wid = tid >> 6;
    float v[16]; float mx = -1e30f;
    #pragma unroll
    for (int t = 0; t < 16; t++) {
        float x = sane(bf2f(p[t * 256 + tid]));
        v[t] = x; mx = fmaxf(mx, x);
    }
    #pragma unroll
    for (int o = 32; o; o >>= 1) mx = fmaxf(mx, __shfl_xor(mx, o, 64));
    __shared__ float rmax[4], rsum[4];
    if (!lane) rmax[wid] = mx;
    __syncthreads();
    mx = fmaxf(fmaxf(rmax[0], rmax[1]), fmaxf(rmax[2], rmax[3]));
    float s = 0.f;
    #pragma unroll
    for (int t = 0; t < 16; t++) { v[t] = __expf(v[t] - mx); s += v[t]; }
    #pragma unroll
    for (int o = 32; o; o >>= 1) s += __shfl_xor(s, o, 64);
    if (!lane) rsum[wid] = s;
    __syncthreads();
    s = rsum[0] + rsum[1] + rsum[2] + rsum[3];
    float inv = 1.f / s;
    #pragma unroll
    for (int t = 0; t < 16; t++) p[t * 256 + tid] = f2bf(v[t] * inv);
}

// ---------------------------------------------------------------------------
// Column softmax (4096x4096 bf16), 3 phases (R5 winner).
// ---------------------------------------------------------------------------
__global__ __launch_bounds__(256) void colsm_partial(
    const unsigned short* __restrict__ buf,
    float* __restrict__ pmx, float* __restrict__ psum)
{
    const int tid = threadIdx.x;
    const int colgrp = tid & 63, rg = tid >> 6;
    const int cbase = blockIdx.x * 512 + colgrp * 8;
    const int r0 = blockIdx.y * 128 + rg * 32;
    const unsigned short* p = buf + (long)r0 * 4096 + cbase;
    float mx[8], s[8];
    #pragma unroll
    for (int j = 0; j < 8; j++) { mx[j] = -1e30f; s[j] = 0.f; }
    for (int r = 0; r < 32; r++) {
        ushort8 v = *(const ushort8*)(p + (long)r * 4096);
        #pragma unroll
        for (int j = 0; j < 8; j++) {
            float x = sane(bf2f(v[j]));
            float nm = fmaxf(mx[j], x);
            s[j] = s[j] * __expf(mx[j] - nm) + __expf(x - nm);
            mx[j] = nm;
        }
    }
    __shared__ float smx[4][512], ssm[4][512];
    #pragma unroll
    for (int j = 0; j < 8; j++) { smx[rg][colgrp * 8 + j] = mx[j]; ssm[rg][colgrp * 8 + j] = s[j]; }
    __syncthreads();
    for (int c = tid; c < 512; c += 256) {
        float M = fmaxf(fmaxf(smx[0][c], smx[1][c]), fmaxf(smx[2][c], smx[3][c]));
        float S = 0.f;
        #pragma unroll
        for (int i = 0; i < 4; i++) S += ssm[i][c] * __expf(smx[i][c] - M);
        int col = blockIdx.x * 512 + c;
        pmx[blockIdx.y * 4096 + col] = M;
        psum[blockIdx.y * 4096 + col] = S;
    }
}

__global__ __launch_bounds__(256) void colsm_combine(
    const float* __restrict__ pmx, const float* __restrict__ psum,
    float* __restrict__ gM, float* __restrict__ gInv)
{
    int col = blockIdx.x * 256 + threadIdx.x;   // grid 16
    float M = -1e30f;
    for (int ch = 0; ch < 32; ch++) M = fmaxf(M, pmx[ch * 4096 + col]);
    float S = 0.f;
    for (int ch = 0; ch < 32; ch++) S += psum[ch * 4096 + col] * __expf(pmx[ch * 4096 + col] - M);
    gM[col] = M;
    gInv[col] = 1.f / S;
}

__global__ __launch_bounds__(256) void colsm_norm(
    unsigned short* __restrict__ buf,
    const float* __restrict__ gM, const float* __restrict__ gInv)
{
    const int tid = threadIdx.x;
    const int colgrp = tid & 63, rg = tid >> 6;
    const int cbase = blockIdx.x * 512 + colgrp * 8;
    const int r0 = blockIdx.y * 128 + rg * 32;
    unsigned short* p = buf + (long)r0 * 4096 + cbase;
    float M[8], inv[8];
    #pragma unroll
    for (int j = 0; j < 8; j++) { M[j] = gM[cbase + j]; inv[j] = gInv[cbase + j]; }
    for (int r = 0; r < 32; r++) {
        ushort8 v = *(const ushort8*)(p + (long)r * 4096);
        ushort8 o;
        #pragma unroll
        for (int j = 0; j < 8; j++) o[j] = f2bf(__expf(sane(bf2f(v[j])) - M[j]) * inv[j]);
        *(ushort8*)(p + (long)r * 4096) = o;
    }
}

// ---------------------------------------------------------------------------
// 1x1 conv projections (fp32 in [B][64][4096], W fp32 [c][i], +bias) -> bf16.
// ---------------------------------------------------------------------------
__global__ __launch_bounds__(256) void proj_nc(
    const float* __restrict__ X, const float* __restrict__ W,
    const float* __restrict__ bias, unsigned short* __restrict__ out)
{
    const int b = blockIdx.y, nt = blockIdx.x, tid = threadIdx.x;
    __shared__ float Xs[64][64];   // [i][n]
    __shared__ float Ws[64][65];   // [i][c]
    __shared__ float Bb[64];
    for (int f = tid; f < 4096; f += 256) {
        int i = f >> 6, n = f & 63;
        Xs[i][n] = X[((long)b * 64 + i) * 4096 + nt * 64 + n];
        Ws[f & 63][f >> 6] = W[f];   // W[c*64+i] -> Ws[i][c]
    }
    if (tid < 64) Bb[tid] = bias[tid];
    __syncthreads();
    const int c = tid & 63, g = tid >> 6;
    float acc[16];
    #pragma unroll
    for (int j = 0; j < 16; j++) acc[j] = Bb[c];
    for (int i = 0; i < 64; i++) {
        float wv = Ws[i][c];
        #pragma unroll
        for (int j = 0; j < 16; j++) acc[j] += wv * Xs[i][g + 4 * j];
    }
    unsigned short* ob = out + ((long)b * 4096 + nt * 64) * 64;
    #pragma unroll
    for (int j = 0; j < 16; j++) ob[(g + 4 * j) * 64 + c] = f2bf(acc[j]);
}

__global__ __launch_bounds__(256) void proj_cn(
    const float* __restrict__ X, const float* __restrict__ W,
    const float* __restrict__ bias, unsigned short* __restrict__ out)
{
    const int b = blockIdx.y, nt = blockIdx.x, tid = threadIdx.x;
    __shared__ float Xs[64][64];   // [i][n]
    __shared__ float Ws[64][64];   // [c][i]
    __shared__ float Bb[64];
    for (int f = tid; f < 4096; f += 256) {
        int i = f >> 6, n = f & 63;
        Xs[i][n] = X[((long)b * 64 + i) * 4096 + nt * 64 + n];
        Ws[f >> 6][f & 63] = W[f];
    }
    if (tid < 64) Bb[tid] = bias[tid];
    __syncthreads();
    const int n = tid & 63, g = tid >> 6;
    float acc[16];
    #pragma unroll
    for (int j = 0; j < 16; j++) acc[j] = Bb[g + 4 * j];
    for (int i = 0; i < 64; i++) {
        float xv = Xs[i][n];
        #pragma unroll
        for (int j = 0; j < 16; j++) acc[j] += Ws[g + 4 * j][i] * xv;
    }
    unsigned short* ob = out + ((long)b * 64) * 4096 + nt * 64;
    #pragma unroll
    for (int j = 0; j < 16; j++) ob[(long)(g + 4 * j) * 4096 + n] = f2bf(acc[j]);
}

// ---------------------------------------------------------------------------
// combine split-K partials: pam = gamma*(sum_k part_k) + x.
// ---------------------------------------------------------------------------
__global__ __launch_bounds__(256) void combine_pam(
    const float* __restrict__ part, const float* __restrict__ x,
    const float* __restrict__ gammaPtr, float* __restrict__ pam)
{
    int i = blockIdx.x * 256 + threadIdx.x;   // 262144 total
    float s = part[i] + part[262144 + i] + part[2 * 262144 + i] + part[3 * 262144 + i];
    pam[i] = gammaPtr[0] * s + x[i];
}

// ---------------------------------------------------------------------------
// 3x3 conv (SAME) + BN + PReLU, fp32.
// ---------------------------------------------------------------------------
__global__ __launch_bounds__(256) void conv3x3_bn(
    const float* __restrict__ X, const float* __restrict__ W9,
    const float* __restrict__ bias,
    const float* __restrict__ bns, const float* __restrict__ bnb,
    const float* __restrict__ bnm, const float* __restrict__ bnv,
    const float* __restrict__ prelu, float* __restrict__ out)
{
    const int b = blockIdx.y, h = blockIdx.x, tid = threadIdx.x;
    __shared__ float Ls[3][64][66];
    __shared__ float ep0[64], ep1[64], ep2[64];
    __shared__ float alpha;
    for (int f = tid; f < 3 * 64 * 64; f += 256) {
        int ky = f >> 12, rem = f & 4095, ci = rem >> 6, w = rem & 63;
        int hh = h + ky - 1;
        Ls[ky][ci][w + 1] = (hh >= 0 && hh < 64) ? X[(((long)b * 64 + ci) * 64 + hh) * 64 + w] : 0.f;
    }
    for (int f = tid; f < 192; f += 256) {
        int ky = f >> 6, ci = f & 63;
        Ls[ky][ci][0] = 0.f; Ls[ky][ci][65] = 0.f;
    }
    if (tid < 64) {
        float inv = bns[tid] * rsqrtf(fmaxf(bnv[tid], 0.f) + 1e-5f);
        ep0[tid] = inv; ep1[tid] = bnb[tid] - bnm[tid] * inv; ep2[tid] = bias[tid];
    }
    if (tid == 0) alpha = prelu[0];
    __syncthreads();
    const int w = tid & 63, g = tid >> 6;   // co = g*16 + j
    float acc[16];
    #pragma unroll
    for (int j = 0; j < 16; j++) acc[j] = ep2[g * 16 + j];
    for (int ci = 0; ci < 64; ci++) {
        float v0 = Ls[0][ci][w], v1 = Ls[0][ci][w + 1], v2 = Ls[0][ci][w + 2];
        float v3 = Ls[1][ci][w], v4 = Ls[1][ci][w + 1], v5 = Ls[1][ci][w + 2];
        float v6 = Ls[2][ci][w], v7 = Ls[2][ci][w + 1], v8 = Ls[2][ci][w + 2];
        #pragma unroll
        for (int j = 0; j < 16; j++) {
            const float* wp = &W9[((g * 16 + j) * 64 + ci) * 9];
            acc[j] += wp[0] * v0 + wp[1] * v1 + wp[2] * v2
                    + wp[3] * v3 + wp[4] * v4 + wp[5] * v5
                    + wp[6] * v6 + wp[7] * v7 + wp[8] * v8;
        }
    }
    #pragma unroll
    for (int j = 0; j < 16; j++) {
        int co = g * 16 + j;
        float y = acc[j] * ep0[co] + ep1[co];
        y = y > 0.f ? y : alpha * y;
        out[(((long)b * 64 + co) * 64 + h) * 64 + w] = y;
    }
}

// ---------------------------------------------------------------------------
// 1x1 conv + BN + PReLU, fp32.
// ---------------------------------------------------------------------------
__global__ __launch_bounds__(256) void conv1x1_bn(
    const float* __restrict__ X, const float* __restrict__ W,
    const float* __restrict__ bias,
    const float* __restrict__ bns, const float* __restrict__ bnb,
    const float* __restrict__ bnm, const float* __restrict__ bnv,
    const float* __restrict__ prelu, float* __restrict__ out)
{
    const int b = blockIdx.y, nt = blockIdx.x, tid = threadIdx.x;
    __shared__ float Xs[64][64];   // [i][n]
    __shared__ float Ws[64][64];   // [c][i]
    __shared__ float ep0[64], ep1[64], ep2[64];
    __shared__ float alpha;
    for (int f = tid; f < 4096; f += 256) {
        int i = f >> 6, n = f & 63;
        Xs[i][n] = X[((long)b * 64 + i) * 4096 + nt * 64 + n];
        Ws[f >> 6][f & 63] = W[f];
    }
    if (tid < 64) {
        float inv = bns[tid] * rsqrtf(fmaxf(bnv[tid], 0.f) + 1e-5f);
        ep0[tid] = inv; ep1[tid] = bnb[tid] - bnm[tid] * inv; ep2[tid] = bias[tid];
    }
    if (tid == 0) alpha = prelu[0];
    __syncthreads();
    const int n = tid & 63, g = tid >> 6;
    float acc[16];
    #pragma unroll
    for (int j = 0; j < 16; j++) acc[j] = ep2[g + 4 * j];
    for (int i = 0; i < 64; i++) {
        float xv = Xs[i][n];
        #pragma unroll
        for (int j = 0; j < 16; j++) acc[j] += Ws[g + 4 * j][i] * xv;
    }
    #pragma unroll
    for (int j = 0; j < 16; j++) {
        int c = g + 4 * j;
        float y = acc[j] * ep0[c] + ep1[c];
        y = y > 0.f ? y : alpha * y;
        out[((long)b * 64 + c) * 4096 + nt * 64 + n] = y;
    }
}

// ---------------------------------------------------------------------------
// Split-K Gram: grid (64 kchunks, B). Block stages 64x64 fp32 tile, computes
// 64x64 partial Gram (16 outputs/thread), atomicAdd into out[b][64][64].
// Out must be pre-zeroed.
// ---------------------------------------------------------------------------
__global__ __launch_bounds__(256) void gram_partial(
    const float* __restrict__ X, float* __restrict__ out)
{
    const int ch = blockIdx.x, b = blockIdx.y, tid = threadIdx.x;
    __shared__ float Xs[64][65];
    for (int f = tid; f < 4096; f += 256) {
        int ci = f >> 6, kk = f & 63;
        Xs[ci][kk] = X[((long)b * 64 + ci) * 4096 + ch * 64 + kk];
    }
    __syncthreads();
    const int d = tid & 63, g = tid >> 6;   // c = g + 4*j, j in [0,16)
    float acc[16] = {};
    for (int kk = 0; kk < 64; kk++) {
        float xd = Xs[d][kk];
        #pragma unroll
        for (int j = 0; j < 16; j++) acc[j] += Xs[g + 4 * j][kk] * xd;
    }
    #pragma unroll
    for (int j = 0; j < 16; j++)
        atomicAdd(&out[((long)b * 64 + (g + 4 * j)) * 64 + d], acc[j]);
}

// ---------------------------------------------------------------------------
// SE gate: gy2[b][c] = sigmoid(fc2 . relu(fc1 . mean_hw(g)))   (all fp32)
// ---------------------------------------------------------------------------
__global__ __launch_bounds__(256) void se_kernel(
    const float* __restrict__ G, const float* __restrict__ fc1,
    const float* __restrict__ fc2, float* __restrict__ gy2)
{
    const int b = blockIdx.x, tid = threadIdx.x, lane = tid & 63, wid = tid >> 6;
    __shared__ float gy[64], r1[32];
    for (int c = wid; c < 64; c += 4) {
        const float* p = G + ((long)b * 64 + c) * 4096;
        float s = 0.f;
        for (int k = lane; k < 4096; k += 64) s += p[k];
        #pragma unroll
        for (int o = 32; o; o >>= 1) s += __shfl_xor(s, o, 64);
        if (!lane) gy[c] = s * (1.f / 4096.f);
    }
    __syncthreads();
    if (tid < 32) {
        float s = 0.f;
        for (int c = 0; c < 64; c++) s += fc1[tid * 64 + c] * gy[c];
        r1[tid] = fmaxf(s, 0.f);
    }
    __syncthreads();
    if (tid < 64) {
        float s = 0.f;
        for (int r = 0; r < 32; r++) s += fc2[tid * 32 + r] * r1[r];
        gy2[b * 64 + tid] = 1.f / (1.f + __expf(-sane(s)));
    }
}

// ---------------------------------------------------------------------------
// CAM small algebra (64x64 per batch). 64 threads, one row per thread.
// ---------------------------------------------------------------------------
__global__ __launch_bounds__(64) void cam_small(
    const float* __restrict__ gramx, const float* __restrict__ gramg,
    const float* __restrict__ gy2, float* __restrict__ gattc)
{
    const int b = blockIdx.x, tid = threadIdx.x;
    __shared__ float Ac[64][65], Acg[64][65];
    __shared__ float gys[64];
    gys[tid] = gy2[b * 64 + tid];
    __syncthreads();
    {
        const float* r = gramx + ((long)b * 64 + tid) * 64;
        float mx = -1e30f;
        for (int d = 0; d < 64; d++) mx = fmaxf(mx, sane(r[d]));
        float s = 0.f;
        for (int d = 0; d < 64; d++) s += __expf(sane(r[d]) - mx);
        float inv = 1.f / s;
        for (int d = 0; d < 64; d++) Ac[tid][d] = __expf(sane(r[d]) - mx) * inv;
    }
    {
        const float* r = gramg + ((long)b * 64 + tid) * 64;
        float gc = gys[tid];
        float mx = -1e30f;
        for (int d = 0; d < 64; d++) mx = fmaxf(mx, sane(gc * gys[d] * r[d]));
        float s = 0.f;
        for (int d = 0; d < 64; d++) s += __expf(sane(gc * gys[d] * r[d]) - mx);
        float inv = 1.f / s;
        for (int d = 0; d < 64; d++) Acg[tid][d] = __expf(sane(gc * gys[d] * r[d]) - mx) * inv;
    }
    __syncthreads();
    float ge[64];
    float mx1 = -1e30f, mn = 1e30f;
    for (int d = 0; d < 64; d++) {
        float s = 0.f;
        for (int k = 0; k < 64; k++) s += Ac[tid][k] * Acg[k][d];
        ge[d] = s;
        mx1 = fmaxf(mx1, s); mn = fminf(mn, s);
    }
    float M2 = mx1 - mn;   // max of (mx1 - ge)
    float s = 0.f;
    for (int d = 0; d < 64; d++) s += __expf((mx1 - ge[d]) - M2);
    float inv = 1.f / s;
    for (int d = 0; d < 64; d++)
        gattc[((long)b * 64 + tid) * 64 + d] = __expf((mx1 - ge[d]) - M2) * inv;
}

// ---------------------------------------------------------------------------
// cam = gamma_c * (gatt_c @ pam2) + pam2   (fp32)
// ---------------------------------------------------------------------------
__global__ __launch_bounds__(256) void cam_apply(
    const float* __restrict__ pam2, const float* __restrict__ gattc,
    const float* __restrict__ gammaPtr, float* __restrict__ cam)
{
    const int b = blockIdx.y, nt = blockIdx.x, tid = threadIdx.x;
    __shared__ float Xs[64][64];   // [d][n]
    __shared__ float Gt[64][64];   // [c][d]
    for (int f = tid; f < 4096; f += 256) {
        int d = f >> 6, n = f & 63;
        Xs[d][n] = pam2[((long)b * 64 + d) * 4096 + nt * 64 + n];
        Gt[f >> 6][f & 63] = gattc[((long)b * 64 + (f >> 6)) * 64 + (f & 63)];
    }
    __syncthreads();
    const float gamma = gammaPtr[0];
    const int n = tid & 63, g = tid >> 6;
    float acc[16] = {};
    for (int d = 0; d < 64; d++) {
        float xv = Xs[d][n];
        #pragma unroll
        for (int j = 0; j < 16; j++) acc[j] += Gt[g + 4 * j][d] * xv;
    }
    #pragma unroll
    for (int j = 0; j < 16; j++) {
        int c = g + 4 * j;
        cam[((long)b * 64 + c) * 4096 + nt * 64 + n] = gamma * acc[j] + Xs[c][n];
    }
}

// ---------------------------------------------------------------------------
// host
// ---------------------------------------------------------------------------
extern "C" void kernel_launch(void* const* d_in, const int* in_sizes, int n_in,
                              void* d_out, int out_size, void* d_ws, size_t ws_size,
                              hipStream_t stream)
{
    static const int exp_sizes[51] = {
        524288, 524288,
        4096, 64, 4096, 64, 4096, 64, 4096, 64, 4096, 64,
        1, 2048, 2048, 1,
        36864, 64, 64, 64, 64, 64, 1,
        4096, 64, 64, 64, 64, 64, 1,
        36864, 64, 64, 64, 64, 64, 1,
        4096, 64, 64, 64, 64, 64, 1,
        4096, 64, 64, 64, 64, 64, 1
    };
    bool map_ok = (n_in == 51) && (out_size == 524288);
    if (map_ok) for (int i = 0; i < 51; i++) if (in_sizes[i] != exp_sizes[i]) { map_ok = false; break; }

    const int diag_grid = (out_size + 255) / 256;
    if (!map_ok) {
        diag_fill<<<diag_grid, 256, 0, stream>>>((float*)d_out, out_size, 400.0f);
        return;
    }
    const size_t NEED_FULL = 121000000;   // verified available
    if (ws_size < NEED_FULL) {
        float code = (ws_size >= 88000000) ? 100.0f : (ws_size >= 55000000 ? 200.0f : 300.0f);
        diag_fill<<<diag_grid, 256, 0, stream>>>((float*)d_out, out_size, code);
        return;
    }

    auto IN = [&](int i) { return (const float*)d_in[i]; };
    const float* X = IN(0);
    const float* G = IN(1);

    char* wp_ = (char*)d_ws;
    auto alloc = [&](size_t bytes) -> void* {
        void* p = (void*)wp_;
        wp_ += (bytes + 255) & ~(size_t)255;
        return p;
    };
    unsigned short* qT   = (unsigned short*)alloc(2L * 4096 * 64 * 2);
    unsigned short* kT   = (unsigned short*)alloc(2L * 4096 * 64 * 2);
    unsigned short* qgT  = (unsigned short*)alloc(2L * 4096 * 64 * 2);
    unsigned short* kgT  = (unsigned short*)alloc(2L * 4096 * 64 * 2);
    unsigned short* vC   = (unsigned short*)alloc(2L * 64 * 4096 * 2);
    float* part  = (float*)alloc(4L * 64 * 4096 * 4);
    float* pam   = (float*)alloc(2L * 64 * 4096 * 4);
    float* tbuf  = (float*)alloc(2L * 64 * 4096 * 4);
    float* pam2  = (float*)alloc(2L * 64 * 4096 * 4);
    float* cam   = (float*)alloc(2L * 64 * 4096 * 4);
    float* gramx = (float*)alloc(2L * 64 * 64 * 4);
    float* gramg = (float*)alloc(2L * 64 * 64 * 4);
    float* gy2   = (float*)alloc(2L * 64 * 4);
    float* gattc = (float*)alloc(2L * 64 * 64 * 4);
    float* pmx   = (float*)alloc(32L * 4096 * 4);
    float* psum  = (float*)alloc(32L * 4096 * 4);
    float* gM    = (float*)alloc(4096L * 4);
    float* gInv  = (float*)alloc(4096L * 4);
    unsigned short* att  = (unsigned short*)alloc(4096L * 4096 * 2);   // per-batch reuse
    unsigned short* attg = (unsigned short*)alloc(4096L * 4096 * 2);
    unsigned short* pbuf = (unsigned short*)alloc(4096L * 4096 * 2);
    float* cam2 = tbuf;   // tbuf free after cconv1; reuse for cam2

    // ---- projections (fp32 -> bf16 operands) ----
    proj_nc<<<dim3(64, 2), 256, 0, stream>>>(X, IN(2),  IN(3),  qT);
    proj_nc<<<dim3(64, 2), 256, 0, stream>>>(X, IN(4),  IN(5),  kT);
    proj_nc<<<dim3(64, 2), 256, 0, stream>>>(G, IN(8),  IN(9),  qgT);
    proj_nc<<<dim3(64, 2), 256, 0, stream>>>(G, IN(10), IN(11), kgT);
    proj_cn<<<dim3(64, 2), 256, 0, stream>>>(X, IN(6),  IN(7),  vC);

    // ---- guided position attention, per batch (reuse big buffers) ----
    for (int b = 0; b < 2; b++) {
        const unsigned short* qTb  = qT  + (long)b * 4096 * 64;
        const unsigned short* kTb  = kT  + (long)b * 4096 * 64;
        const unsigned short* qgTb = qgT + (long)b * 4096 * 64;
        const unsigned short* kgTb = kgT + (long)b * 4096 * 64;
        gemm_nt<<<dim3(32, 32, 1), 256, 0, stream>>>(qTb,  kTb,  att,  4096, 4096, 64, 1);
        gemm_nt<<<dim3(32, 32, 1), 256, 0, stream>>>(kgTb, qgTb, attg, 4096, 4096, 64, 1);
        row_softmax<<<4096, 256, 0, stream>>>(att);             // att[n][k] bf16
        colsm_partial<<<dim3(8, 32), 256, 0, stream>>>(attg, pmx, psum);
        colsm_combine<<<16, 256, 0, stream>>>(pmx, psum, gM, gInv);
        colsm_norm<<<dim3(8, 32), 256, 0, stream>>>(attg, gM, gInv);
        gemm_nt<<<dim3(32, 32, 1), 256, 0, stream>>>(att, attg, pbuf, 4096, 4096, 4096, 1);
        row_softmax<<<4096, 256, 0, stream>>>(pbuf);
        gemm_nt<<<dim3(32, 1, 4), 256, 0, stream>>>(vC + (long)b * 64 * 4096, pbuf, part,
                                                    64, 4096, 4096, 3);
        combine_pam<<<1024, 256, 0, stream>>>(part, X + (long)b * 64 * 4096, IN(12),
                                              pam + (long)b * 64 * 4096);
    }

    // ---- pconv head ----
    conv3x3_bn<<<dim3(64, 2), 256, 0, stream>>>(pam, IN(16), IN(17), IN(18), IN(19), IN(20), IN(21), IN(22), tbuf);
    conv1x1_bn<<<dim3(64, 2), 256, 0, stream>>>(tbuf, IN(23), IN(24), IN(25), IN(26), IN(27), IN(28), IN(29), pam2);

    // ---- guided channel attention ----
    diag_fill<<<32, 256, 0, stream>>>(gramx, 8192, 0.0f);
    diag_fill<<<32, 256, 0, stream>>>(gramg, 8192, 0.0f);
    gram_partial<<<dim3(64, 2), 256, 0, stream>>>(pam2, gramx);
    gram_partial<<<dim3(64, 2), 256, 0, stream>>>(G,    gramg);
    se_kernel<<<2, 256, 0, stream>>>(G, IN(13), IN(14), gy2);
    cam_small<<<2, 64, 0, stream>>>(gramx, gramg, gy2, gattc);
    cam_apply<<<dim3(64, 2), 256, 0, stream>>>(pam2, gattc, IN(15), cam);

    // ---- cconv + fconv heads ----
    conv3x3_bn<<<dim3(64, 2), 256, 0, stream>>>(cam, IN(30), IN(31), IN(32), IN(33), IN(34), IN(35), IN(36), pam);  // reuse pam as tmp
    conv1x1_bn<<<dim3(64, 2), 256, 0, stream>>>(pam, IN(37), IN(38), IN(39), IN(40), IN(41), IN(42), IN(43), cam2);
    conv1x1_bn<<<dim3(64, 2), 256, 0, stream>>>(cam2, IN(44), IN(45), IN(46), IN(47), IN(48), IN(49), IN(50), (float*)d_out);
}

// Round 7
// 1162.368 us; speedup vs baseline: 2.6476x; 1.1985x over previous
//
#include <hip/hip_runtime.h>

// ---------------------------------------------------------------------------
// DGNLB fused pipeline.  ALL inputs/outputs are FP32 (reference is jnp.float32).
// B=2, C=64, H=W=64, N=4096.  Attention GEMMs run on bf16 MFMA.
// R7: se_kernel (2 blocks, 273us each) -> se_mean (128 blocks) + se_gate (tiny).
// ---------------------------------------------------------------------------

typedef float f32x4 __attribute__((ext_vector_type(4)));
typedef __bf16 bf16x8 __attribute__((ext_vector_type(8)));
typedef int int4v __attribute__((ext_vector_type(4)));
typedef unsigned short ushort8 __attribute__((ext_vector_type(8)));

#define DI __device__ __forceinline__

DI float bf2f(unsigned short u) { union { unsigned int i; float f; } x; x.i = ((unsigned int)u) << 16; return x.f; }
DI unsigned short f2bf(float f) { union { float f; unsigned int i; } x; x.f = f; unsigned int r = x.i + 0x7fff + ((x.i >> 16) & 1); return (unsigned short)(r >> 16); }
DI float sane(float x) { return (x > -1e8f) ? ((x < 1e8f) ? x : 1e8f) : -1e8f; }

// async global->LDS, 16B per lane. LDS dest must be wave-uniform base + lane*16.
DI void async16(const unsigned short* g, unsigned short* l) {
    __builtin_amdgcn_global_load_lds(
        (const __attribute__((address_space(1))) void*)g,
        (__attribute__((address_space(3))) void*)l, 16, 0, 0);
}

__global__ __launch_bounds__(256) void diag_fill(float* __restrict__ out, int n, float val)
{
    int i = blockIdx.x * 256 + threadIdx.x;
    if (i < n) out[i] = val;
}

// ---------------------------------------------------------------------------
// NT GEMM: C[M][N] = A[M][K] * B[N][K]^T, bf16 operands, fp32 accum (MFMA).
// 128x128 tile, 4 waves 2x2, each wave 4x4 of 16x16x32 MFMAs, BK=32.
// mode 1: write bf16      mode 3: split-K partial fp32 (slice per blockIdx.z)
// ---------------------------------------------------------------------------
__global__ __launch_bounds__(256) void gemm_nt(
    const unsigned short* __restrict__ A,
    const unsigned short* __restrict__ B,
    void* __restrict__ C,
    int M, int N, int K, int mode)
{
    __shared__ __align__(16) unsigned short As[128 * 32];
    __shared__ __align__(16) unsigned short Bs[128 * 32];
    const int tid  = threadIdx.x;
    const int bm   = blockIdx.y, bn = blockIdx.x;
    const int lane = tid & 63, wid = tid >> 6;
    const int wm   = (wid >> 1) * 64, wn = (wid & 1) * 64;
    const int l16  = lane & 15, quad = lane >> 4;

    f32x4 acc[4][4] = {};

    const int Kc   = K / (int)gridDim.z;
    const int kbeg = (int)blockIdx.z * Kc;
    const int kend = kbeg + Kc;

    for (int k0 = kbeg; k0 < kend; k0 += 32) {
        __syncthreads();
        #pragma unroll
        for (int c = 0; c < 2; c++) {
            int ch = tid + c * 256;               // 512 chunks of 16B per tile
            int row = ch >> 2, ko = (ch & 3) * 8;
            int ar = bm * 128 + row; if (ar > M - 1) ar = M - 1;   // clamp for M=64
            int br = bn * 128 + row;
            async16(&A[(long)ar * K + k0 + ko], &As[row * 32 + ko]);
            async16(&B[(long)br * K + k0 + ko], &Bs[row * 32 + ko]);
        }
        __syncthreads();
        bf16x8 af[4], bfr[4];
        #pragma unroll
        for (int i = 0; i < 4; i++) af[i]  = *(const bf16x8*)&As[(wm + i * 16 + l16) * 32 + quad * 8];
        #pragma unroll
        for (int j = 0; j < 4; j++) bfr[j] = *(const bf16x8*)&Bs[(wn + j * 16 + l16) * 32 + quad * 8];
        #pragma unroll
        for (int i = 0; i < 4; i++)
            #pragma unroll
            for (int j = 0; j < 4; j++)
                acc[i][j] = __builtin_amdgcn_mfma_f32_16x16x32_bf16(af[i], bfr[j], acc[i][j], 0, 0, 0);
    }

    #pragma unroll
    for (int i = 0; i < 4; i++) {
        int rb = bm * 128 + wm + i * 16 + quad * 4;   // C/D: col=lane&15, row=quad*4+reg
        #pragma unroll
        for (int j = 0; j < 4; j++) {
            int col = bn * 128 + wn + j * 16 + l16;
            #pragma unroll
            for (int r = 0; r < 4; r++) {
                int row = rb + r;
                if (row < M) {
                    long idx = (long)row * N + col;
                    float vv = acc[i][j][r];
                    if (mode == 1) ((unsigned short*)C)[idx] = f2bf(vv);
                    else           ((float*)C)[(long)blockIdx.z * M * N + idx] = vv;
                }
            }
        }
    }
}

// ---------------------------------------------------------------------------
// Row softmax over 4096 contiguous bf16 cols, in place (bf16 out).
// ---------------------------------------------------------------------------
__global__ __launch_bounds__(256) void row_softmax(unsigned short* __restrict__ buf)
{
    long row = blockIdx.x;
    unsigned short* p = buf + row * 4096L;
    const int tid = threadIdx.x, lane = tid & 63, wid = tid >> 6;
    float v[16]; float mx = -1e30f;
    #pragma unroll
    for (int t = 0; t < 16; t++) {
        float x = sane(bf2f(p[t * 256 + tid]));
        v[t] = x; mx = fmaxf(mx, x);
    }
    #pragma unroll
    for (int o = 32; o; o >>= 1) mx = fmaxf(mx, __shfl_xor(mx, o, 64));
    __shared__ float rmax[4], rsum[4];
    if (!lane) rmax[wid] = mx;
    __syncthreads();
    mx = fmaxf(fmaxf(rmax[0], rmax[1]), fmaxf(rmax[2], rmax[3]));
    float s = 0.f;
    #pragma unroll
    for (int t = 0; t < 16; t++) { v[t] = __expf(v[t] - mx); s += v[t]; }
    #pragma unroll
    for (int o = 32; o; o >>= 1) s += __shfl_xor(s, o, 64);
    if (!lane) rsum[wid] = s;
    __syncthreads();
    s = rsum[0] + rsum[1] + rsum[2] + rsum[3];
    float inv = 1.f / s;
    #pragma unroll
    for (int t = 0; t < 16; t++) p[t * 256 + tid] = f2bf(v[t] * inv);
}

// ---------------------------------------------------------------------------
// Column softmax (4096x4096 bf16), 3 phases (R5 winner).
// ---------------------------------------------------------------------------
__global__ __launch_bounds__(256) void colsm_partial(
    const unsigned short* __restrict__ buf,
    float* __restrict__ pmx, float* __restrict__ psum)
{
    const int tid = threadIdx.x;
    const int colgrp = tid & 63, rg = tid >> 6;
    const int cbase = blockIdx.x * 512 + colgrp * 8;
    const int r0 = blockIdx.y * 128 + rg * 32;
    const unsigned short* p = buf + (long)r0 * 4096 + cbase;
    float mx[8], s[8];
    #pragma unroll
    for (int j = 0; j < 8; j++) { mx[j] = -1e30f; s[j] = 0.f; }
    for (int r = 0; r < 32; r++) {
        ushort8 v = *(const ushort8*)(p + (long)r * 4096);
        #pragma unroll
        for (int j = 0; j < 8; j++) {
            float x = sane(bf2f(v[j]));
            float nm = fmaxf(mx[j], x);
            s[j] = s[j] * __expf(mx[j] - nm) + __expf(x - nm);
            mx[j] = nm;
        }
    }
    __shared__ float smx[4][512], ssm[4][512];
    #pragma unroll
    for (int j = 0; j < 8; j++) { smx[rg][colgrp * 8 + j] = mx[j]; ssm[rg][colgrp * 8 + j] = s[j]; }
    __syncthreads();
    for (int c = tid; c < 512; c += 256) {
        float M = fmaxf(fmaxf(smx[0][c], smx[1][c]), fmaxf(smx[2][c], smx[3][c]));
        float S = 0.f;
        #pragma unroll
        for (int i = 0; i < 4; i++) S += ssm[i][c] * __expf(smx[i][c] - M);
        int col = blockIdx.x * 512 + c;
        pmx[blockIdx.y * 4096 + col] = M;
        psum[blockIdx.y * 4096 + col] = S;
    }
}

__global__ __launch_bounds__(256) void colsm_combine(
    const float* __restrict__ pmx, const float* __restrict__ psum,
    float* __restrict__ gM, float* __restrict__ gInv)
{
    int col = blockIdx.x * 256 + threadIdx.x;   // grid 16
    float M = -1e30f;
    for (int ch = 0; ch < 32; ch++) M = fmaxf(M, pmx[ch * 4096 + col]);
    float S = 0.f;
    for (int ch = 0; ch < 32; ch++) S += psum[ch * 4096 + col] * __expf(pmx[ch * 4096 + col] - M);
    gM[col] = M;
    gInv[col] = 1.f / S;
}

__global__ __launch_bounds__(256) void colsm_norm(
    unsigned short* __restrict__ buf,
    const float* __restrict__ gM, const float* __restrict__ gInv)
{
    const int tid = threadIdx.x;
    const int colgrp = tid & 63, rg = tid >> 6;
    const int cbase = blockIdx.x * 512 + colgrp * 8;
    const int r0 = blockIdx.y * 128 + rg * 32;
    unsigned short* p = buf + (long)r0 * 4096 + cbase;
    float M[8], inv[8];
    #pragma unroll
    for (int j = 0; j < 8; j++) { M[j] = gM[cbase + j]; inv[j] = gInv[cbase + j]; }
    for (int r = 0; r < 32; r++) {
        ushort8 v = *(const ushort8*)(p + (long)r * 4096);
        ushort8 o;
        #pragma unroll
        for (int j = 0; j < 8; j++) o[j] = f2bf(__expf(sane(bf2f(v[j])) - M[j]) * inv[j]);
        *(ushort8*)(p + (long)r * 4096) = o;
    }
}

// ---------------------------------------------------------------------------
// 1x1 conv projections (fp32 in [B][64][4096], W fp32 [c][i], +bias) -> bf16.
// ---------------------------------------------------------------------------
__global__ __launch_bounds__(256) void proj_nc(
    const float* __restrict__ X, const float* __restrict__ W,
    const float* __restrict__ bias, unsigned short* __restrict__ out)
{
    const int b = blockIdx.y, nt = blockIdx.x, tid = threadIdx.x;
    __shared__ float Xs[64][64];   // [i][n]
    __shared__ float Ws[64][65];   // [i][c]
    __shared__ float Bb[64];
    for (int f = tid; f < 4096; f += 256) {
        int i = f >> 6, n = f & 63;
        Xs[i][n] = X[((long)b * 64 + i) * 4096 + nt * 64 + n];
        Ws[f & 63][f >> 6] = W[f];   // W[c*64+i] -> Ws[i][c]
    }
    if (tid < 64) Bb[tid] = bias[tid];
    __syncthreads();
    const int c = tid & 63, g = tid >> 6;
    float acc[16];
    #pragma unroll
    for (int j = 0; j < 16; j++) acc[j] = Bb[c];
    for (int i = 0; i < 64; i++) {
        float wv = Ws[i][c];
        #pragma unroll
        for (int j = 0; j < 16; j++) acc[j] += wv * Xs[i][g + 4 * j];
    }
    unsigned short* ob = out + ((long)b * 4096 + nt * 64) * 64;
    #pragma unroll
    for (int j = 0; j < 16; j++) ob[(g + 4 * j) * 64 + c] = f2bf(acc[j]);
}

__global__ __launch_bounds__(256) void proj_cn(
    const float* __restrict__ X, const float* __restrict__ W,
    const float* __restrict__ bias, unsigned short* __restrict__ out)
{
    const int b = blockIdx.y, nt = blockIdx.x, tid = threadIdx.x;
    __shared__ float Xs[64][64];   // [i][n]
    __shared__ float Ws[64][64];   // [c][i]
    __shared__ float Bb[64];
    for (int f = tid; f < 4096; f += 256) {
        int i = f >> 6, n = f & 63;
        Xs[i][n] = X[((long)b * 64 + i) * 4096 + nt * 64 + n];
        Ws[f >> 6][f & 63] = W[f];
    }
    if (tid < 64) Bb[tid] = bias[tid];
    __syncthreads();
    const int n = tid & 63, g = tid >> 6;
    float acc[16];
    #pragma unroll
    for (int j = 0; j < 16; j++) acc[j] = Bb[g + 4 * j];
    for (int i = 0; i < 64; i++) {
        float xv = Xs[i][n];
        #pragma unroll
        for (int j = 0; j < 16; j++) acc[j] += Ws[g + 4 * j][i] * xv;
    }
    unsigned short* ob = out + ((long)b * 64) * 4096 + nt * 64;
    #pragma unroll
    for (int j = 0; j < 16; j++) ob[(long)(g + 4 * j) * 4096 + n] = f2bf(acc[j]);
}

// ---------------------------------------------------------------------------
// combine split-K partials: pam = gamma*(sum_k part_k) + x.
// ---------------------------------------------------------------------------
__global__ __launch_bounds__(256) void combine_pam(
    const float* __restrict__ part, const float* __restrict__ x,
    const float* __restrict__ gammaPtr, float* __restrict__ pam)
{
    int i = blockIdx.x * 256 + threadIdx.x;   // 262144 total
    float s = part[i] + part[262144 + i] + part[2 * 262144 + i] + part[3 * 262144 + i];
    pam[i] = gammaPtr[0] * s + x[i];
}

// ---------------------------------------------------------------------------
// 3x3 conv (SAME) + BN + PReLU, fp32.
// ---------------------------------------------------------------------------
__global__ __launch_bounds__(256) void conv3x3_bn(
    const float* __restrict__ X, const float* __restrict__ W9,
    const float* __restrict__ bias,
    const float* __restrict__ bns, const float* __restrict__ bnb,
    const float* __restrict__ bnm, const float* __restrict__ bnv,
    const float* __restrict__ prelu, float* __restrict__ out)
{
    const int b = blockIdx.y, h = blockIdx.x, tid = threadIdx.x;
    __shared__ float Ls[3][64][66];
    __shared__ float ep0[64], ep1[64], ep2[64];
    __shared__ float alpha;
    for (int f = tid; f < 3 * 64 * 64; f += 256) {
        int ky = f >> 12, rem = f & 4095, ci = rem >> 6, w = rem & 63;
        int hh = h + ky - 1;
        Ls[ky][ci][w + 1] = (hh >= 0 && hh < 64) ? X[(((long)b * 64 + ci) * 64 + hh) * 64 + w] : 0.f;
    }
    for (int f = tid; f < 192; f += 256) {
        int ky = f >> 6, ci = f & 63;
        Ls[ky][ci][0] = 0.f; Ls[ky][ci][65] = 0.f;
    }
    if (tid < 64) {
        float inv = bns[tid] * rsqrtf(fmaxf(bnv[tid], 0.f) + 1e-5f);
        ep0[tid] = inv; ep1[tid] = bnb[tid] - bnm[tid] * inv; ep2[tid] = bias[tid];
    }
    if (tid == 0) alpha = prelu[0];
    __syncthreads();
    const int w = tid & 63, g = tid >> 6;   // co = g*16 + j
    float acc[16];
    #pragma unroll
    for (int j = 0; j < 16; j++) acc[j] = ep2[g * 16 + j];
    for (int ci = 0; ci < 64; ci++) {
        float v0 = Ls[0][ci][w], v1 = Ls[0][ci][w + 1], v2 = Ls[0][ci][w + 2];
        float v3 = Ls[1][ci][w], v4 = Ls[1][ci][w + 1], v5 = Ls[1][ci][w + 2];
        float v6 = Ls[2][ci][w], v7 = Ls[2][ci][w + 1], v8 = Ls[2][ci][w + 2];
        #pragma unroll
        for (int j = 0; j < 16; j++) {
            const float* wp = &W9[((g * 16 + j) * 64 + ci) * 9];
            acc[j] += wp[0] * v0 + wp[1] * v1 + wp[2] * v2
                    + wp[3] * v3 + wp[4] * v4 + wp[5] * v5
                    + wp[6] * v6 + wp[7] * v7 + wp[8] * v8;
        }
    }
    #pragma unroll
    for (int j = 0; j < 16; j++) {
        int co = g * 16 + j;
        float y = acc[j] * ep0[co] + ep1[co];
        y = y > 0.f ? y : alpha * y;
        out[(((long)b * 64 + co) * 64 + h) * 64 + w] = y;
    }
}

// ---------------------------------------------------------------------------
// 1x1 conv + BN + PReLU, fp32.
// ---------------------------------------------------------------------------
__global__ __launch_bounds__(256) void conv1x1_bn(
    const float* __restrict__ X, const float* __restrict__ W,
    const float* __restrict__ bias,
    const float* __restrict__ bns, const float* __restrict__ bnb,
    const float* __restrict__ bnm, const float* __restrict__ bnv,
    const float* __restrict__ prelu, float* __restrict__ out)
{
    const int b = blockIdx.y, nt = blockIdx.x, tid = threadIdx.x;
    __shared__ float Xs[64][64];   // [i][n]
    __shared__ float Ws[64][64];   // [c][i]
    __shared__ float ep0[64], ep1[64], ep2[64];
    __shared__ float alpha;
    for (int f = tid; f < 4096; f += 256) {
        int i = f >> 6, n = f & 63;
        Xs[i][n] = X[((long)b * 64 + i) * 4096 + nt * 64 + n];
        Ws[f >> 6][f & 63] = W[f];
    }
    if (tid < 64) {
        float inv = bns[tid] * rsqrtf(fmaxf(bnv[tid], 0.f) + 1e-5f);
        ep0[tid] = inv; ep1[tid] = bnb[tid] - bnm[tid] * inv; ep2[tid] = bias[tid];
    }
    if (tid == 0) alpha = prelu[0];
    __syncthreads();
    const int n = tid & 63, g = tid >> 6;
    float acc[16];
    #pragma unroll
    for (int j = 0; j < 16; j++) acc[j] = ep2[g + 4 * j];
    for (int i = 0; i < 64; i++) {
        float xv = Xs[i][n];
        #pragma unroll
        for (int j = 0; j < 16; j++) acc[j] += Ws[g + 4 * j][i] * xv;
    }
    #pragma unroll
    for (int j = 0; j < 16; j++) {
        int c = g + 4 * j;
        float y = acc[j] * ep0[c] + ep1[c];
        y = y > 0.f ? y : alpha * y;
        out[((long)b * 64 + c) * 4096 + nt * 64 + n] = y;
    }
}

// ---------------------------------------------------------------------------
// Split-K Gram: grid (64 kchunks, B). atomicAdd combine; out pre-zeroed.
// ---------------------------------------------------------------------------
__global__ __launch_bounds__(256) void gram_partial(
    const float* __restrict__ X, float* __restrict__ out)
{
    const int ch = blockIdx.x, b = blockIdx.y, tid = threadIdx.x;
    __shared__ float Xs[64][65];
    for (int f = tid; f < 4096; f += 256) {
        int ci = f >> 6, kk = f & 63;
        Xs[ci][kk] = X[((long)b * 64 + ci) * 4096 + ch * 64 + kk];
    }
    __syncthreads();
    const int d = tid & 63, g = tid >> 6;   // c = g + 4*j, j in [0,16)
    float acc[16] = {};
    for (int kk = 0; kk < 64; kk++) {
        float xd = Xs[d][kk];
        #pragma unroll
        for (int j = 0; j < 16; j++) acc[j] += Xs[g + 4 * j][kk] * xd;
    }
    #pragma unroll
    for (int j = 0; j < 16; j++)
        atomicAdd(&out[((long)b * 64 + (g + 4 * j)) * 64 + d], acc[j]);
}

// ---------------------------------------------------------------------------
// SE mean: gy[b][c] = mean_hw(G[b][c]).  Grid (64, B), one block per channel.
// ---------------------------------------------------------------------------
__global__ __launch_bounds__(256) void se_mean(
    const float* __restrict__ G, float* __restrict__ gy)
{
    const int c = blockIdx.x, b = blockIdx.y, tid = threadIdx.x;
    const int lane = tid & 63, wid = tid >> 6;
    const float* p = G + ((long)b * 64 + c) * 4096;
    float s = 0.f;
    #pragma unroll
    for (int t = 0; t < 4; t++) {
        f32x4 v = *(const f32x4*)(p + (t * 256 + tid) * 4);
        s += v[0] + v[1] + v[2] + v[3];
    }
    #pragma unroll
    for (int o = 32; o; o >>= 1) s += __shfl_xor(s, o, 64);
    __shared__ float ws[4];
    if (!lane) ws[wid] = s;
    __syncthreads();
    if (tid == 0) gy[b * 64 + c] = (ws[0] + ws[1] + ws[2] + ws[3]) * (1.f / 4096.f);
}

// ---------------------------------------------------------------------------
// SE gate: gy2[b][c] = sigmoid(fc2 . relu(fc1 . gy))   (tiny)
// ---------------------------------------------------------------------------
__global__ __launch_bounds__(64) void se_gate(
    const float* __restrict__ gy_in, const float* __restrict__ fc1,
    const float* __restrict__ fc2, float* __restrict__ gy2)
{
    const int b = blockIdx.x, tid = threadIdx.x;
    __shared__ float gy[64], r1[32];
    gy[tid] = gy_in[b * 64 + tid];
    __syncthreads();
    if (tid < 32) {
        float s = 0.f;
        for (int c = 0; c < 64; c++) s += fc1[tid * 64 + c] * gy[c];
        r1[tid] = fmaxf(s, 0.f);
    }
    __syncthreads();
    float s = 0.f;
    for (int r = 0; r < 32; r++) s += fc2[tid * 32 + r] * r1[r];
    gy2[b * 64 + tid] = 1.f / (1.f + __expf(-sane(s)));
}

// ---------------------------------------------------------------------------
// CAM small algebra (64x64 per batch). 64 threads, one row per thread.
// ---------------------------------------------------------------------------
__global__ __launch_bounds__(64) void cam_small(
    const float* __restrict__ gramx, const float* __restrict__ gramg,
    const float* __restrict__ gy2, float* __restrict__ gattc)
{
    const int b = blockIdx.x, tid = threadIdx.x;
    __shared__ float Ac[64][65], Acg[64][65];
    __shared__ float gys[64];
    gys[tid] = gy2[b * 64 + tid];
    __syncthreads();
    {
        const float* r = gramx + ((long)b * 64 + tid) * 64;
        float mx = -1e30f;
        for (int d = 0; d < 64; d++) mx = fmaxf(mx, sane(r[d]));
        float s = 0.f;
        for (int d = 0; d < 64; d++) s += __expf(sane(r[d]) - mx);
        float inv = 1.f / s;
        for (int d = 0; d < 64; d++) Ac[tid][d] = __expf(sane(r[d]) - mx) * inv;
    }
    {
        const float* r = gramg + ((long)b * 64 + tid) * 64;
        float gc = gys[tid];
        float mx = -1e30f;
        for (int d = 0; d < 64; d++) mx = fmaxf(mx, sane(gc * gys[d] * r[d]));
        float s = 0.f;
        for (int d = 0; d < 64; d++) s += __expf(sane(gc * gys[d] * r[d]) - mx);
        float inv = 1.f / s;
        for (int d = 0; d < 64; d++) Acg[tid][d] = __expf(sane(gc * gys[d] * r[d]) - mx) * inv;
    }
    __syncthreads();
    float ge[64];
    float mx1 = -1e30f, mn = 1e30f;
    for (int d = 0; d < 64; d++) {
        float s = 0.f;
        for (int k = 0; k < 64; k++) s += Ac[tid][k] * Acg[k][d];
        ge[d] = s;
        mx1 = fmaxf(mx1, s); mn = fminf(mn, s);
    }
    float M2 = mx1 - mn;   // max of (mx1 - ge)
    float s = 0.f;
    for (int d = 0; d < 64; d++) s += __expf((mx1 - ge[d]) - M2);
    float inv = 1.f / s;
    for (int d = 0; d < 64; d++)
        gattc[((long)b * 64 + tid) * 64 + d] = __expf((mx1 - ge[d]) - M2) * inv;
}

// ---------------------------------------------------------------------------
// cam = gamma_c * (gatt_c @ pam2) + pam2   (fp32)
// ---------------------------------------------------------------------------
__global__ __launch_bounds__(256) void cam_apply(
    const float* __restrict__ pam2, const float* __restrict__ gattc,
    const float* __restrict__ gammaPtr, float* __restrict__ cam)
{
    const int b = blockIdx.y, nt = blockIdx.x, tid = threadIdx.x;
    __shared__ float Xs[64][64];   // [d][n]
    __shared__ float Gt[64][64];   // [c][d]
    for (int f = tid; f < 4096; f += 256) {
        int d = f >> 6, n = f & 63;
        Xs[d][n] = pam2[((long)b * 64 + d) * 4096 + nt * 64 + n];
        Gt[f >> 6][f & 63] = gattc[((long)b * 64 + (f >> 6)) * 64 + (f & 63)];
    }
    __syncthreads();
    const float gamma = gammaPtr[0];
    const int n = tid & 63, g = tid >> 6;
    float acc[16] = {};
    for (int d = 0; d < 64; d++) {
        float xv = Xs[d][n];
        #pragma unroll
        for (int j = 0; j < 16; j++) acc[j] += Gt[g + 4 * j][d] * xv;
    }
    #pragma unroll
    for (int j = 0; j < 16; j++) {
        int c = g + 4 * j;
        cam[((long)b * 64 + c) * 4096 + nt * 64 + n] = gamma * acc[j] + Xs[c][n];
    }
}

// ---------------------------------------------------------------------------
// host
// ---------------------------------------------------------------------------
extern "C" void kernel_launch(void* const* d_in, const int* in_sizes, int n_in,
                              void* d_out, int out_size, void* d_ws, size_t ws_size,
                              hipStream_t stream)
{
    static const int exp_sizes[51] = {
        524288, 524288,
        4096, 64, 4096, 64, 4096, 64, 4096, 64, 4096, 64,
        1, 2048, 2048, 1,
        36864, 64, 64, 64, 64, 64, 1,
        4096, 64, 64, 64, 64, 64, 1,
        36864, 64, 64, 64, 64, 64, 1,
        4096, 64, 64, 64, 64, 64, 1,
        4096, 64, 64, 64, 64, 64, 1
    };
    bool map_ok = (n_in == 51) && (out_size == 524288);
    if (map_ok) for (int i = 0; i < 51; i++) if (in_sizes[i] != exp_sizes[i]) { map_ok = false; break; }

    const int diag_grid = (out_size + 255) / 256;
    if (!map_ok) {
        diag_fill<<<diag_grid, 256, 0, stream>>>((float*)d_out, out_size, 400.0f);
        return;
    }
    const size_t NEED_FULL = 121000000;   // verified available
    if (ws_size < NEED_FULL) {
        float code = (ws_size >= 88000000) ? 100.0f : (ws_size >= 55000000 ? 200.0f : 300.0f);
        diag_fill<<<diag_grid, 256, 0, stream>>>((float*)d_out, out_size, code);
        return;
    }

    auto IN = [&](int i) { return (const float*)d_in[i]; };
    const float* X = IN(0);
    const float* G = IN(1);

    char* wp_ = (char*)d_ws;
    auto alloc = [&](size_t bytes) -> void* {
        void* p = (void*)wp_;
        wp_ += (bytes + 255) & ~(size_t)255;
        return p;
    };
    unsigned short* qT   = (unsigned short*)alloc(2L * 4096 * 64 * 2);
    unsigned short* kT   = (unsigned short*)alloc(2L * 4096 * 64 * 2);
    unsigned short* qgT  = (unsigned short*)alloc(2L * 4096 * 64 * 2);
    unsigned short* kgT  = (unsigned short*)alloc(2L * 4096 * 64 * 2);
    unsigned short* vC   = (unsigned short*)alloc(2L * 64 * 4096 * 2);
    float* part  = (float*)alloc(4L * 64 * 4096 * 4);
    float* pam   = (float*)alloc(2L * 64 * 4096 * 4);
    float* tbuf  = (float*)alloc(2L * 64 * 4096 * 4);
    float* pam2  = (float*)alloc(2L * 64 * 4096 * 4);
    float* cam   = (float*)alloc(2L * 64 * 4096 * 4);
    float* gramx = (float*)alloc(2L * 64 * 64 * 4);
    float* gramg = (float*)alloc(2L * 64 * 64 * 4);
    float* gy    = (float*)alloc(2L * 64 * 4);
    float* gy2   = (float*)alloc(2L * 64 * 4);
    float* gattc = (float*)alloc(2L * 64 * 64 * 4);
    float* pmx   = (float*)alloc(32L * 4096 * 4);
    float* psum  = (float*)alloc(32L * 4096 * 4);
    float* gM    = (float*)alloc(4096L * 4);
    float* gInv  = (float*)alloc(4096L * 4);
    unsigned short* att  = (unsigned short*)alloc(4096L * 4096 * 2);   // per-batch reuse
    unsigned short* attg = (unsigned short*)alloc(4096L * 4096 * 2);
    unsigned short* pbuf = (unsigned short*)alloc(4096L * 4096 * 2);
    float* cam2 = tbuf;   // tbuf free after cconv1; reuse for cam2

    // ---- projections (fp32 -> bf16 operands) ----
    proj_nc<<<dim3(64, 2), 256, 0, stream>>>(X, IN(2),  IN(3),  qT);
    proj_nc<<<dim3(64, 2), 256, 0, stream>>>(X, IN(4),  IN(5),  kT);
    proj_nc<<<dim3(64, 2), 256, 0, stream>>>(G, IN(8),  IN(9),  qgT);
    proj_nc<<<dim3(64, 2), 256, 0, stream>>>(G, IN(10), IN(11), kgT);
    proj_cn<<<dim3(64, 2), 256, 0, stream>>>(X, IN(6),  IN(7),  vC);

    // ---- guided position attention, per batch (reuse big buffers) ----
    for (int b = 0; b < 2; b++) {
        const unsigned short* qTb  = qT  + (long)b * 4096 * 64;
        const unsigned short* kTb  = kT  + (long)b * 4096 * 64;
        const unsigned short* qgTb = qgT + (long)b * 4096 * 64;
        const unsigned short* kgTb = kgT + (long)b * 4096 * 64;
        gemm_nt<<<dim3(32, 32, 1), 256, 0, stream>>>(qTb,  kTb,  att,  4096, 4096, 64, 1);
        gemm_nt<<<dim3(32, 32, 1), 256, 0, stream>>>(kgTb, qgTb, attg, 4096, 4096, 64, 1);
        row_softmax<<<4096, 256, 0, stream>>>(att);             // att[n][k] bf16
        colsm_partial<<<dim3(8, 32), 256, 0, stream>>>(attg, pmx, psum);
        colsm_combine<<<16, 256, 0, stream>>>(pmx, psum, gM, gInv);
        colsm_norm<<<dim3(8, 32), 256, 0, stream>>>(attg, gM, gInv);
        gemm_nt<<<dim3(32, 32, 1), 256, 0, stream>>>(att, attg, pbuf, 4096, 4096, 4096, 1);
        row_softmax<<<4096, 256, 0, stream>>>(pbuf);
        gemm_nt<<<dim3(32, 1, 4), 256, 0, stream>>>(vC + (long)b * 64 * 4096, pbuf, part,
                                                    64, 4096, 4096, 3);
        combine_pam<<<1024, 256, 0, stream>>>(part, X + (long)b * 64 * 4096, IN(12),
                                              pam + (long)b * 64 * 4096);
    }

    // ---- pconv head ----
    conv3x3_bn<<<dim3(64, 2), 256, 0, stream>>>(pam, IN(16), IN(17), IN(18), IN(19), IN(20), IN(21), IN(22), tbuf);
    conv1x1_bn<<<dim3(64, 2), 256, 0, stream>>>(tbuf, IN(23), IN(24), IN(25), IN(26), IN(27), IN(28), IN(29), pam2);

    // ---- guided channel attention ----
    diag_fill<<<32, 256, 0, stream>>>(gramx, 8192, 0.0f);
    diag_fill<<<32, 256, 0, stream>>>(gramg, 8192, 0.0f);
    gram_partial<<<dim3(64, 2), 256, 0, stream>>>(pam2, gramx);
    gram_partial<<<dim3(64, 2), 256, 0, stream>>>(G,    gramg);
    se_mean<<<dim3(64, 2), 256, 0, stream>>>(G, gy);
    se_gate<<<2, 64, 0, stream>>>(gy, IN(13), IN(14), gy2);
    cam_small<<<2, 64, 0, stream>>>(gramx, gramg, gy2, gattc);
    cam_apply<<<dim3(64, 2), 256, 0, stream>>>(pam2, gattc, IN(15), cam);

    // ---- cconv + fconv heads ----
    conv3x3_bn<<<dim3(64, 2), 256, 0, stream>>>(cam, IN(30), IN(31), IN(32), IN(33), IN(34), IN(35), IN(36), pam);  // reuse pam as tmp
    conv1x1_bn<<<dim3(64, 2), 256, 0, stream>>>(pam, IN(37), IN(38), IN(39), IN(40), IN(41), IN(42), IN(43), cam2);
    conv1x1_bn<<<dim3(64, 2), 256, 0, stream>>>(cam2, IN(44), IN(45), IN(46), IN(47), IN(48), IN(49), IN(50), (float*)d_out);
}

// Round 8
// 1159.314 us; speedup vs baseline: 2.6546x; 1.0026x over previous
//
#include <hip/hip_runtime.h>

// ---------------------------------------------------------------------------
// DGNLB fused pipeline.  ALL inputs/outputs are FP32 (reference is jnp.float32).
// B=2, C=64, H=W=64, N=4096.  Attention GEMMs run on bf16 MFMA.
// R8: XOR-swizzled LDS layout in gemm_nt (kills the 8-way ds_read_b128 bank
//     conflict; 2-way is free per m136) while keeping global_load_lds staging
//     (swizzle applied on the per-lane GLOBAL source, LDS dest stays lane*16).
// ---------------------------------------------------------------------------

typedef float f32x4 __attribute__((ext_vector_type(4)));
typedef __bf16 bf16x8 __attribute__((ext_vector_type(8)));
typedef int int4v __attribute__((ext_vector_type(4)));
typedef unsigned short ushort8 __attribute__((ext_vector_type(8)));

#define DI __device__ __forceinline__

DI float bf2f(unsigned short u) { union { unsigned int i; float f; } x; x.i = ((unsigned int)u) << 16; return x.f; }
DI unsigned short f2bf(float f) { union { float f; unsigned int i; } x; x.f = f; unsigned int r = x.i + 0x7fff + ((x.i >> 16) & 1); return (unsigned short)(r >> 16); }
DI float sane(float x) { return (x > -1e8f) ? ((x < 1e8f) ? x : 1e8f) : -1e8f; }

// async global->LDS, 16B per lane. LDS dest must be wave-uniform base + lane*16.
DI void async16(const unsigned short* g, unsigned short* l) {
    __builtin_amdgcn_global_load_lds(
        (const __attribute__((address_space(1))) void*)g,
        (__attribute__((address_space(3))) void*)l, 16, 0, 0);
}

__global__ __launch_bounds__(256) void diag_fill(float* __restrict__ out, int n, float val)
{
    int i = blockIdx.x * 256 + threadIdx.x;
    if (i < n) out[i] = val;
}

// ---------------------------------------------------------------------------
// NT GEMM: C[M][N] = A[M][K] * B[N][K]^T, bf16 operands, fp32 accum (MFMA).
// 128x128 tile, 4 waves 2x2, each wave 4x4 of 16x16x32 MFMAs, BK=32.
// LDS layout XOR-swizzled: chunk c (8 elems) of row r lives at slot c^(r&3).
// Staging inverts the swizzle on the global source address (LDS dest must
// stay linear in lane for global_load_lds).
// mode 1: write bf16      mode 3: split-K partial fp32 (slice per blockIdx.z)
// ---------------------------------------------------------------------------
__global__ __launch_bounds__(256) void gemm_nt(
    const unsigned short* __restrict__ A,
    const unsigned short* __restrict__ B,
    void* __restrict__ C,
    int M, int N, int K, int mode)
{
    __shared__ __align__(16) unsigned short As[128 * 32];
    __shared__ __align__(16) unsigned short Bs[128 * 32];
    const int tid  = threadIdx.x;
    const int bm   = blockIdx.y, bn = blockIdx.x;
    const int lane = tid & 63, wid = tid >> 6;
    const int wm   = (wid >> 1) * 64, wn = (wid & 1) * 64;
    const int l16  = lane & 15, quad = lane >> 4;

    f32x4 acc[4][4] = {};

    const int Kc   = K / (int)gridDim.z;
    const int kbeg = (int)blockIdx.z * Kc;
    const int kend = kbeg + Kc;

    // swizzled chunk for fragment reads: slot = quad ^ (row&3), row&3 == l16&3
    const int sw = (quad ^ (l16 & 3)) * 8;

    for (int k0 = kbeg; k0 < kend; k0 += 32) {
        __syncthreads();
        #pragma unroll
        for (int c = 0; c < 2; c++) {
            int ch = tid + c * 256;               // 512 chunks of 16B per tile
            int row = ch >> 2, cpos = ch & 3;
            int ko = (cpos ^ (row & 3)) * 8;      // inverse swizzle on source
            int ar = bm * 128 + row; if (ar > M - 1) ar = M - 1;   // clamp for M=64
            int br = bn * 128 + row;
            async16(&A[(long)ar * K + k0 + ko], &As[row * 32 + cpos * 8]);
            async16(&B[(long)br * K + k0 + ko], &Bs[row * 32 + cpos * 8]);
        }
        __syncthreads();
        bf16x8 af[4], bfr[4];
        #pragma unroll
        for (int i = 0; i < 4; i++) af[i]  = *(const bf16x8*)&As[(wm + i * 16 + l16) * 32 + sw];
        #pragma unroll
        for (int j = 0; j < 4; j++) bfr[j] = *(const bf16x8*)&Bs[(wn + j * 16 + l16) * 32 + sw];
        #pragma unroll
        for (int i = 0; i < 4; i++)
            #pragma unroll
            for (int j = 0; j < 4; j++)
                acc[i][j] = __builtin_amdgcn_mfma_f32_16x16x32_bf16(af[i], bfr[j], acc[i][j], 0, 0, 0);
    }

    #pragma unroll
    for (int i = 0; i < 4; i++) {
        int rb = bm * 128 + wm + i * 16 + quad * 4;   // C/D: col=lane&15, row=quad*4+reg
        #pragma unroll
        for (int j = 0; j < 4; j++) {
            int col = bn * 128 + wn + j * 16 + l16;
            #pragma unroll
            for (int r = 0; r < 4; r++) {
                int row = rb + r;
                if (row < M) {
                    long idx = (long)row * N + col;
                    float vv = acc[i][j][r];
                    if (mode == 1) ((unsigned short*)C)[idx] = f2bf(vv);
                    else           ((float*)C)[(long)blockIdx.z * M * N + idx] = vv;
                }
            }
        }
    }
}

// ---------------------------------------------------------------------------
// Row softmax over 4096 contiguous bf16 cols, in place (bf16 out).
// ---------------------------------------------------------------------------
__global__ __launch_bounds__(256) void row_softmax(unsigned short* __restrict__ buf)
{
    long row = blockIdx.x;
    unsigned short* p = buf + row * 4096L;
    const int tid = threadIdx.x, lane = tid & 63, wid = tid >> 6;
    float v[16]; float mx = -1e30f;
    #pragma unroll
    for (int t = 0; t < 16; t++) {
        float x = sane(bf2f(p[t * 256 + tid]));
        v[t] = x; mx = fmaxf(mx, x);
    }
    #pragma unroll
    for (int o = 32; o; o >>= 1) mx = fmaxf(mx, __shfl_xor(mx, o, 64));
    __shared__ float rmax[4], rsum[4];
    if (!lane) rmax[wid] = mx;
    __syncthreads();
    mx = fmaxf(fmaxf(rmax[0], rmax[1]), fmaxf(rmax[2], rmax[3]));
    float s = 0.f;
    #pragma unroll
    for (int t = 0; t < 16; t++) { v[t] = __expf(v[t] - mx); s += v[t]; }
    #pragma unroll
    for (int o = 32; o; o >>= 1) s += __shfl_xor(s, o, 64);
    if (!lane) rsum[wid] = s;
    __syncthreads();
    s = rsum[0] + rsum[1] + rsum[2] + rsum[3];
    float inv = 1.f / s;
    #pragma unroll
    for (int t = 0; t < 16; t++) p[t * 256 + tid] = f2bf(v[t] * inv);
}

// ---------------------------------------------------------------------------
// Column softmax (4096x4096 bf16), 3 phases (R5 winner).
// ---------------------------------------------------------------------------
__global__ __launch_bounds__(256) void colsm_partial(
    const unsigned short* __restrict__ buf,
    float* __restrict__ pmx, float* __restrict__ psum)
{
    const int tid = threadIdx.x;
    const int colgrp = tid & 63, rg = tid >> 6;
    const int cbase = blockIdx.x * 512 + colgrp * 8;
    const int r0 = blockIdx.y * 128 + rg * 32;
    const unsigned short* p = buf + (long)r0 * 4096 + cbase;
    float mx[8], s[8];
    #pragma unroll
    for (int j = 0; j < 8; j++) { mx[j] = -1e30f; s[j] = 0.f; }
    for (int r = 0; r < 32; r++) {
        ushort8 v = *(const ushort8*)(p + (long)r * 4096);
        #pragma unroll
        for (int j = 0; j < 8; j++) {
            float x = sane(bf2f(v[j]));
            float nm = fmaxf(mx[j], x);
            s[j] = s[j] * __expf(mx[j] - nm) + __expf(x - nm);
            mx[j] = nm;
        }
    }
    __shared__ float smx[4][512], ssm[4][512];
    #pragma unroll
    for (int j = 0; j < 8; j++) { smx[rg][colgrp * 8 + j] = mx[j]; ssm[rg][colgrp * 8 + j] = s[j]; }
    __syncthreads();
    for (int c = tid; c < 512; c += 256) {
        float M = fmaxf(fmaxf(smx[0][c], smx[1][c]), fmaxf(smx[2][c], smx[3][c]));
        float S = 0.f;
        #pragma unroll
        for (int i = 0; i < 4; i++) S += ssm[i][c] * __expf(smx[i][c] - M);
        int col = blockIdx.x * 512 + c;
        pmx[blockIdx.y * 4096 + col] = M;
        psum[blockIdx.y * 4096 + col] = S;
    }
}

__global__ __launch_bounds__(256) void colsm_combine(
    const float* __restrict__ pmx, const float* __restrict__ psum,
    float* __restrict__ gM, float* __restrict__ gInv)
{
    int col = blockIdx.x * 256 + threadIdx.x;   // grid 16
    float M = -1e30f;
    for (int ch = 0; ch < 32; ch++) M = fmaxf(M, pmx[ch * 4096 + col]);
    float S = 0.f;
    for (int ch = 0; ch < 32; ch++) S += psum[ch * 4096 + col] * __expf(pmx[ch * 4096 + col] - M);
    gM[col] = M;
    gInv[col] = 1.f / S;
}

__global__ __launch_bounds__(256) void colsm_norm(
    unsigned short* __restrict__ buf,
    const float* __restrict__ gM, const float* __restrict__ gInv)
{
    const int tid = threadIdx.x;
    const int colgrp = tid & 63, rg = tid >> 6;
    const int cbase = blockIdx.x * 512 + colgrp * 8;
    const int r0 = blockIdx.y * 128 + rg * 32;
    unsigned short* p = buf + (long)r0 * 4096 + cbase;
    float M[8], inv[8];
    #pragma unroll
    for (int j = 0; j < 8; j++) { M[j] = gM[cbase + j]; inv[j] = gInv[cbase + j]; }
    for (int r = 0; r < 32; r++) {
        ushort8 v = *(const ushort8*)(p + (long)r * 4096);
        ushort8 o;
        #pragma unroll
        for (int j = 0; j < 8; j++) o[j] = f2bf(__expf(sane(bf2f(v[j])) - M[j]) * inv[j]);
        *(ushort8*)(p + (long)r * 4096) = o;
    }
}

// ---------------------------------------------------------------------------
// 1x1 conv projections (fp32 in [B][64][4096], W fp32 [c][i], +bias) -> bf16.
// ---------------------------------------------------------------------------
__global__ __launch_bounds__(256) void proj_nc(
    const float* __restrict__ X, const float* __restrict__ W,
    const float* __restrict__ bias, unsigned short* __restrict__ out)
{
    const int b = blockIdx.y, nt = blockIdx.x, tid = threadIdx.x;
    __shared__ float Xs[64][64];   // [i][n]
    __shared__ float Ws[64][65];   // [i][c]
    __shared__ float Bb[64];
    for (int f = tid; f < 4096; f += 256) {
        int i = f >> 6, n = f & 63;
        Xs[i][n] = X[((long)b * 64 + i) * 4096 + nt * 64 + n];
        Ws[f & 63][f >> 6] = W[f];   // W[c*64+i] -> Ws[i][c]
    }
    if (tid < 64) Bb[tid] = bias[tid];
    __syncthreads();
    const int c = tid & 63, g = tid >> 6;
    float acc[16];
    #pragma unroll
    for (int j = 0; j < 16; j++) acc[j] = Bb[c];
    for (int i = 0; i < 64; i++) {
        float wv = Ws[i][c];
        #pragma unroll
        for (int j = 0; j < 16; j++) acc[j] += wv * Xs[i][g + 4 * j];
    }
    unsigned short* ob = out + ((long)b * 4096 + nt * 64) * 64;
    #pragma unroll
    for (int j = 0; j < 16; j++) ob[(g + 4 * j) * 64 + c] = f2bf(acc[j]);
}

__global__ __launch_bounds__(256) void proj_cn(
    const float* __restrict__ X, const float* __restrict__ W,
    const float* __restrict__ bias, unsigned short* __restrict__ out)
{
    const int b = blockIdx.y, nt = blockIdx.x, tid = threadIdx.x;
    __shared__ float Xs[64][64];   // [i][n]
    __shared__ float Ws[64][64];   // [c][i]
    __shared__ float Bb[64];
    for (int f = tid; f < 4096; f += 256) {
        int i = f >> 6, n = f & 63;
        Xs[i][n] = X[((long)b * 64 + i) * 4096 + nt * 64 + n];
        Ws[f >> 6][f & 63] = W[f];
    }
    if (tid < 64) Bb[tid] = bias[tid];
    __syncthreads();
    const int n = tid & 63, g = tid >> 6;
    float acc[16];
    #pragma unroll
    for (int j = 0; j < 16; j++) acc[j] = Bb[g + 4 * j];
    for (int i = 0; i < 64; i++) {
        float xv = Xs[i][n];
        #pragma unroll
        for (int j = 0; j < 16; j++) acc[j] += Ws[g + 4 * j][i] * xv;
    }
    unsigned short* ob = out + ((long)b * 64) * 4096 + nt * 64;
    #pragma unroll
    for (int j = 0; j < 16; j++) ob[(long)(g + 4 * j) * 4096 + n] = f2bf(acc[j]);
}

// ---------------------------------------------------------------------------
// combine split-K partials: pam = gamma*(sum_k part_k) + x.
// ---------------------------------------------------------------------------
__global__ __launch_bounds__(256) void combine_pam(
    const float* __restrict__ part, const float* __restrict__ x,
    const float* __restrict__ gammaPtr, float* __restrict__ pam)
{
    int i = blockIdx.x * 256 + threadIdx.x;   // 262144 total
    float s = part[i] + part[262144 + i] + part[2 * 262144 + i] + part[3 * 262144 + i];
    pam[i] = gammaPtr[0] * s + x[i];
}

// ---------------------------------------------------------------------------
// 3x3 conv (SAME) + BN + PReLU, fp32.
// ---------------------------------------------------------------------------
__global__ __launch_bounds__(256) void conv3x3_bn(
    const float* __restrict__ X, const float* __restrict__ W9,
    const float* __restrict__ bias,
    const float* __restrict__ bns, const float* __restrict__ bnb,
    const float* __restrict__ bnm, const float* __restrict__ bnv,
    const float* __restrict__ prelu, float* __restrict__ out)
{
    const int b = blockIdx.y, h = blockIdx.x, tid = threadIdx.x;
    __shared__ float Ls[3][64][66];
    __shared__ float ep0[64], ep1[64], ep2[64];
    __shared__ float alpha;
    for (int f = tid; f < 3 * 64 * 64; f += 256) {
        int ky = f >> 12, rem = f & 4095, ci = rem >> 6, w = rem & 63;
        int hh = h + ky - 1;
        Ls[ky][ci][w + 1] = (hh >= 0 && hh < 64) ? X[(((long)b * 64 + ci) * 64 + hh) * 64 + w] : 0.f;
    }
    for (int f = tid; f < 192; f += 256) {
        int ky = f >> 6, ci = f & 63;
        Ls[ky][ci][0] = 0.f; Ls[ky][ci][65] = 0.f;
    }
    if (tid < 64) {
        float inv = bns[tid] * rsqrtf(fmaxf(bnv[tid], 0.f) + 1e-5f);
        ep0[tid] = inv; ep1[tid] = bnb[tid] - bnm[tid] * inv; ep2[tid] = bias[tid];
    }
    if (tid == 0) alpha = prelu[0];
    __syncthreads();
    const int w = tid & 63, g = tid >> 6;   // co = g*16 + j
    float acc[16];
    #pragma unroll
    for (int j = 0; j < 16; j++) acc[j] = ep2[g * 16 + j];
    for (int ci = 0; ci < 64; ci++) {
        float v0 = Ls[0][ci][w], v1 = Ls[0][ci][w + 1], v2 = Ls[0][ci][w + 2];
        float v3 = Ls[1][ci][w], v4 = Ls[1][ci][w + 1], v5 = Ls[1][ci][w + 2];
        float v6 = Ls[2][ci][w], v7 = Ls[2][ci][w + 1], v8 = Ls[2][ci][w + 2];
        #pragma unroll
        for (int j = 0; j < 16; j++) {
            const float* wp = &W9[((g * 16 + j) * 64 + ci) * 9];
            acc[j] += wp[0] * v0 + wp[1] * v1 + wp[2] * v2
                    + wp[3] * v3 + wp[4] * v4 + wp[5] * v5
                    + wp[6] * v6 + wp[7] * v7 + wp[8] * v8;
        }
    }
    #pragma unroll
    for (int j = 0; j < 16; j++) {
        int co = g * 16 + j;
        float y = acc[j] * ep0[co] + ep1[co];
        y = y > 0.f ? y : alpha * y;
        out[(((long)b * 64 + co) * 64 + h) * 64 + w] = y;
    }
}

// ---------------------------------------------------------------------------
// 1x1 conv + BN + PReLU, fp32.
// ---------------------------------------------------------------------------
__global__ __launch_bounds__(256) void conv1x1_bn(
    const float* __restrict__ X, const float* __restrict__ W,
    const float* __restrict__ bias,
    const float* __restrict__ bns, const float* __restrict__ bnb,
    const float* __restrict__ bnm, const float* __restrict__ bnv,
    const float* __restrict__ prelu, float* __restrict__ out)
{
    const int b = blockIdx.y, nt = blockIdx.x, tid = threadIdx.x;
    __shared__ float Xs[64][64];   // [i][n]
    __shared__ float Ws[64][64];   // [c][i]
    __shared__ float ep0[64], ep1[64], ep2[64];
    __shared__ float alpha;
    for (int f = tid; f < 4096; f += 256) {
        int i = f >> 6, n = f & 63;
        Xs[i][n] = X[((long)b * 64 + i) * 4096 + nt * 64 + n];
        Ws[f >> 6][f & 63] = W[f];
    }
    if (tid < 64) {
        float inv = bns[tid] * rsqrtf(fmaxf(bnv[tid], 0.f) + 1e-5f);
        ep0[tid] = inv; ep1[tid] = bnb[tid] - bnm[tid] * inv; ep2[tid] = bias[tid];
    }
    if (tid == 0) alpha = prelu[0];
    __syncthreads();
    const int n = tid & 63, g = tid >> 6;
    float acc[16];
    #pragma unroll
    for (int j = 0; j < 16; j++) acc[j] = ep2[g + 4 * j];
    for (int i = 0; i < 64; i++) {
        float xv = Xs[i][n];
        #pragma unroll
        for (int j = 0; j < 16; j++) acc[j] += Ws[g + 4 * j][i] * xv;
    }
    #pragma unroll
    for (int j = 0; j < 16; j++) {
        int c = g + 4 * j;
        float y = acc[j] * ep0[c] + ep1[c];
        y = y > 0.f ? y : alpha * y;
        out[((long)b * 64 + c) * 4096 + nt * 64 + n] = y;
    }
}

// ---------------------------------------------------------------------------
// Split-K Gram: grid (64 kchunks, B). atomicAdd combine; out pre-zeroed.
// ---------------------------------------------------------------------------
__global__ __launch_bounds__(256) void gram_partial(
    const float* __restrict__ X, float* __restrict__ out)
{
    const int ch = blockIdx.x, b = blockIdx.y, tid = threadIdx.x;
    __shared__ float Xs[64][65];
    for (int f = tid; f < 4096; f += 256) {
        int ci = f >> 6, kk = f & 63;
        Xs[ci][kk] = X[((long)b * 64 + ci) * 4096 + ch * 64 + kk];
    }
    __syncthreads();
    const int d = tid & 63, g = tid >> 6;   // c = g + 4*j, j in [0,16)
    float acc[16] = {};
    for (int kk = 0; kk < 64; kk++) {
        float xd = Xs[d][kk];
        #pragma unroll
        for (int j = 0; j < 16; j++) acc[j] += Xs[g + 4 * j][kk] * xd;
    }
    #pragma unroll
    for (int j = 0; j < 16; j++)
        atomicAdd(&out[((long)b * 64 + (g + 4 * j)) * 64 + d], acc[j]);
}

// ---------------------------------------------------------------------------
// SE mean: gy[b][c] = mean_hw(G[b][c]).  Grid (64, B), one block per channel.
// ---------------------------------------------------------------------------
__global__ __launch_bounds__(256) void se_mean(
    const float* __restrict__ G, float* __restrict__ gy)
{
    const int c = blockIdx.x, b = blockIdx.y, tid = threadIdx.x;
    const int lane = tid & 63, wid = tid >> 6;
    const float* p = G + ((long)b * 64 + c) * 4096;
    float s = 0.f;
    #pragma unroll
    for (int t = 0; t < 4; t++) {
        f32x4 v = *(const f32x4*)(p + (t * 256 + tid) * 4);
        s += v[0] + v[1] + v[2] + v[3];
    }
    #pragma unroll
    for (int o = 32; o; o >>= 1) s += __shfl_xor(s, o, 64);
    __shared__ float ws[4];
    if (!lane) ws[wid] = s;
    __syncthreads();
    if (tid == 0) gy[b * 64 + c] = (ws[0] + ws[1] + ws[2] + ws[3]) * (1.f / 4096.f);
}

// ---------------------------------------------------------------------------
// SE gate: gy2[b][c] = sigmoid(fc2 . relu(fc1 . gy))   (tiny)
// ---------------------------------------------------------------------------
__global__ __launch_bounds__(64) void se_gate(
    const float* __restrict__ gy_in, const float* __restrict__ fc1,
    const float* __restrict__ fc2, float* __restrict__ gy2)
{
    const int b = blockIdx.x, tid = threadIdx.x;
    __shared__ float gy[64], r1[32];
    gy[tid] = gy_in[b * 64 + tid];
    __syncthreads();
    if (tid < 32) {
        float s = 0.f;
        for (int c = 0; c < 64; c++) s += fc1[tid * 64 + c] * gy[c];
        r1[tid] = fmaxf(s, 0.f);
    }
    __syncthreads();
    float s = 0.f;
    for (int r = 0; r < 32; r++) s += fc2[tid * 32 + r] * r1[r];
    gy2[b * 64 + tid] = 1.f / (1.f + __expf(-sane(s)));
}

// ---------------------------------------------------------------------------
// CAM small algebra (64x64 per batch). 64 threads, one row per thread.
// ---------------------------------------------------------------------------
__global__ __launch_bounds__(64) void cam_small(
    const float* __restrict__ gramx, const float* __restrict__ gramg,
    const float* __restrict__ gy2, float* __restrict__ gattc)
{
    const int b = blockIdx.x, tid = threadIdx.x;
    __shared__ float Ac[64][65], Acg[64][65];
    __shared__ float gys[64];
    gys[tid] = gy2[b * 64 + tid];
    __syncthreads();
    {
        const float* r = gramx + ((long)b * 64 + tid) * 64;
        float mx = -1e30f;
        for (int d = 0; d < 64; d++) mx = fmaxf(mx, sane(r[d]));
        float s = 0.f;
        for (int d = 0; d < 64; d++) s += __expf(sane(r[d]) - mx);
        float inv = 1.f / s;
        for (int d = 0; d < 64; d++) Ac[tid][d] = __expf(sane(r[d]) - mx) * inv;
    }
    {
        const float* r = gramg + ((long)b * 64 + tid) * 64;
        float gc = gys[tid];
        float mx = -1e30f;
        for (int d = 0; d < 64; d++) mx = fmaxf(mx, sane(gc * gys[d] * r[d]));
        float s = 0.f;
        for (int d = 0; d < 64; d++) s += __expf(sane(gc * gys[d] * r[d]) - mx);
        float inv = 1.f / s;
        for (int d = 0; d < 64; d++) Acg[tid][d] = __expf(sane(gc * gys[d] * r[d]) - mx) * inv;
    }
    __syncthreads();
    float ge[64];
    float mx1 = -1e30f, mn = 1e30f;
    for (int d = 0; d < 64; d++) {
        float s = 0.f;
        for (int k = 0; k < 64; k++) s += Ac[tid][k] * Acg[k][d];
        ge[d] = s;
        mx1 = fmaxf(mx1, s); mn = fminf(mn, s);
    }
    float M2 = mx1 - mn;   // max of (mx1 - ge)
    float s = 0.f;
    for (int d = 0; d < 64; d++) s += __expf((mx1 - ge[d]) - M2);
    float inv = 1.f / s;
    for (int d = 0; d < 64; d++)
        gattc[((long)b * 64 + tid) * 64 + d] = __expf((mx1 - ge[d]) - M2) * inv;
}

// ---------------------------------------------------------------------------
// cam = gamma_c * (gatt_c @ pam2) + pam2   (fp32)
// ---------------------------------------------------------------------------
__global__ __launch_bounds__(256) void cam_apply(
    const float* __restrict__ pam2, const float* __restrict__ gattc,
    const float* __restrict__ gammaPtr, float* __restrict__ cam)
{
    const int b = blockIdx.y, nt = blockIdx.x, tid = threadIdx.x;
    __shared__ float Xs[64][64];   // [d][n]
    __shared__ float Gt[64][64];   // [c][d]
    for (int f = tid; f < 4096; f += 256) {
        int d = f >> 6, n = f & 63;
        Xs[d][n] = pam2[((long)b * 64 + d) * 4096 + nt * 64 + n];
        Gt[f >> 6][f & 63] = gattc[((long)b * 64 + (f >> 6)) * 64 + (f & 63)];
    }
    __syncthreads();
    const float gamma = gammaPtr[0];
    const int n = tid & 63, g = tid >> 6;
    float acc[16] = {};
    for (int d = 0; d < 64; d++) {
        float xv = Xs[d][n];
        #pragma unroll
        for (int j = 0; j < 16; j++) acc[j] += Gt[g + 4 * j][d] * xv;
    }
    #pragma unroll
    for (int j = 0; j < 16; j++) {
        int c = g + 4 * j;
        cam[((long)b * 64 + c) * 4096 + nt * 64 + n] = gamma * acc[j] + Xs[c][n];
    }
}

// ---------------------------------------------------------------------------
// host
// ---------------------------------------------------------------------------
extern "C" void kernel_launch(void* const* d_in, const int* in_sizes, int n_in,
                              void* d_out, int out_size, void* d_ws, size_t ws_size,
                              hipStream_t stream)
{
    static const int exp_sizes[51] = {
        524288, 524288,
        4096, 64, 4096, 64, 4096, 64, 4096, 64, 4096, 64,
        1, 2048, 2048, 1,
        36864, 64, 64, 64, 64, 64, 1,
        4096, 64, 64, 64, 64, 64, 1,
        36864, 64, 64, 64, 64, 64, 1,
        4096, 64, 64, 64, 64, 64, 1,
        4096, 64, 64, 64, 64, 64, 1
    };
    bool map_ok = (n_in == 51) && (out_size == 524288);
    if (map_ok) for (int i = 0; i < 51; i++) if (in_sizes[i] != exp_sizes[i]) { map_ok = false; break; }

    const int diag_grid = (out_size + 255) / 256;
    if (!map_ok) {
        diag_fill<<<diag_grid, 256, 0, stream>>>((float*)d_out, out_size, 400.0f);
        return;
    }
    const size_t NEED_FULL = 121000000;   // verified available
    if (ws_size < NEED_FULL) {
        float code = (ws_size >= 88000000) ? 100.0f : (ws_size >= 55000000 ? 200.0f : 300.0f);
        diag_fill<<<diag_grid, 256, 0, stream>>>((float*)d_out, out_size, code);
        return;
    }

    auto IN = [&](int i) { return (const float*)d_in[i]; };
    const float* X = IN(0);
    const float* G = IN(1);

    char* wp_ = (char*)d_ws;
    auto alloc = [&](size_t bytes) -> void* {
        void* p = (void*)wp_;
        wp_ += (bytes + 255) & ~(size_t)255;
        return p;
    };
    unsigned short* qT   = (unsigned short*)alloc(2L * 4096 * 64 * 2);
    unsigned short* kT   = (unsigned short*)alloc(2L * 4096 * 64 * 2);
    unsigned short* qgT  = (unsigned short*)alloc(2L * 4096 * 64 * 2);
    unsigned short* kgT  = (unsigned short*)alloc(2L * 4096 * 64 * 2);
    unsigned short* vC   = (unsigned short*)alloc(2L * 64 * 4096 * 2);
    float* part  = (float*)alloc(4L * 64 * 4096 * 4);
    float* pam   = (float*)alloc(2L * 64 * 4096 * 4);
    float* tbuf  = (float*)alloc(2L * 64 * 4096 * 4);
    float* pam2  = (float*)alloc(2L * 64 * 4096 * 4);
    float* cam   = (float*)alloc(2L * 64 * 4096 * 4);
    float* gramx = (float*)alloc(2L * 64 * 64 * 4);
    float* gramg = (float*)alloc(2L * 64 * 64 * 4);
    float* gy    = (float*)alloc(2L * 64 * 4);
    float* gy2   = (float*)alloc(2L * 64 * 4);
    float* gattc = (float*)alloc(2L * 64 * 64 * 4);
    float* pmx   = (float*)alloc(32L * 4096 * 4);
    float* psum  = (float*)alloc(32L * 4096 * 4);
    float* gM    = (float*)alloc(4096L * 4);
    float* gInv  = (float*)alloc(4096L * 4);
    unsigned short* att  = (unsigned short*)alloc(4096L * 4096 * 2);   // per-batch reuse
    unsigned short* attg = (unsigned short*)alloc(4096L * 4096 * 2);
    unsigned short* pbuf = (unsigned short*)alloc(4096L * 4096 * 2);
    float* cam2 = tbuf;   // tbuf free after cconv1; reuse for cam2

    // ---- projections (fp32 -> bf16 operands) ----
    proj_nc<<<dim3(64, 2), 256, 0, stream>>>(X, IN(2),  IN(3),  qT);
    proj_nc<<<dim3(64, 2), 256, 0, stream>>>(X, IN(4),  IN(5),  kT);
    proj_nc<<<dim3(64, 2), 256, 0, stream>>>(G, IN(8),  IN(9),  qgT);
    proj_nc<<<dim3(64, 2), 256, 0, stream>>>(G, IN(10), IN(11), kgT);
    proj_cn<<<dim3(64, 2), 256, 0, stream>>>(X, IN(6),  IN(7),  vC);

    // ---- guided position attention, per batch (reuse big buffers) ----
    for (int b = 0; b < 2; b++) {
        const unsigned short* qTb  = qT  + (long)b * 4096 * 64;
        const unsigned short* kTb  = kT  + (long)b * 4096 * 64;
        const unsigned short* qgTb = qgT + (long)b * 4096 * 64;
        const unsigned short* kgTb = kgT + (long)b * 4096 * 64;
        gemm_nt<<<dim3(32, 32, 1), 256, 0, stream>>>(qTb,  kTb,  att,  4096, 4096, 64, 1);
        gemm_nt<<<dim3(32, 32, 1), 256, 0, stream>>>(kgTb, qgTb, attg, 4096, 4096, 64, 1);
        row_softmax<<<4096, 256, 0, stream>>>(att);             // att[n][k] bf16
        colsm_partial<<<dim3(8, 32), 256, 0, stream>>>(attg, pmx, psum);
        colsm_combine<<<16, 256, 0, stream>>>(pmx, psum, gM, gInv);
        colsm_norm<<<dim3(8, 32), 256, 0, stream>>>(attg, gM, gInv);
        gemm_nt<<<dim3(32, 32, 1), 256, 0, stream>>>(att, attg, pbuf, 4096, 4096, 4096, 1);
        row_softmax<<<4096, 256, 0, stream>>>(pbuf);
        gemm_nt<<<dim3(32, 1, 4), 256, 0, stream>>>(vC + (long)b * 64 * 4096, pbuf, part,
                                                    64, 4096, 4096, 3);
        combine_pam<<<1024, 256, 0, stream>>>(part, X + (long)b * 64 * 4096, IN(12),
                                              pam + (long)b * 64 * 4096);
    }

    // ---- pconv head ----
    conv3x3_bn<<<dim3(64, 2), 256, 0, stream>>>(pam, IN(16), IN(17), IN(18), IN(19), IN(20), IN(21), IN(22), tbuf);
    conv1x1_bn<<<dim3(64, 2), 256, 0, stream>>>(tbuf, IN(23), IN(24), IN(25), IN(26), IN(27), IN(28), IN(29), pam2);

    // ---- guided channel attention ----
    diag_fill<<<32, 256, 0, stream>>>(gramx, 8192, 0.0f);
    diag_fill<<<32, 256, 0, stream>>>(gramg, 8192, 0.0f);
    gram_partial<<<dim3(64, 2), 256, 0, stream>>>(pam2, gramx);
    gram_partial<<<dim3(64, 2), 256, 0, stream>>>(G,    gramg);
    se_mean<<<dim3(64, 2), 256, 0, stream>>>(G, gy);
    se_gate<<<2, 64, 0, stream>>>(gy, IN(13), IN(14), gy2);
    cam_small<<<2, 64, 0, stream>>>(gramx, gramg, gy2, gattc);
    cam_apply<<<dim3(64, 2), 256, 0, stream>>>(pam2, gattc, IN(15), cam);

    // ---- cconv + fconv heads ----
    conv3x3_bn<<<dim3(64, 2), 256, 0, stream>>>(cam, IN(30), IN(31), IN(32), IN(33), IN(34), IN(35), IN(36), pam);  // reuse pam as tmp
    conv1x1_bn<<<dim3(64, 2), 256, 0, stream>>>(pam, IN(37), IN(38), IN(39), IN(40), IN(41), IN(42), IN(43), cam2);
    conv1x1_bn<<<dim3(64, 2), 256, 0, stream>>>(cam2, IN(44), IN(45), IN(46), IN(47), IN(48), IN(49), IN(50), (float*)d_out);
}

// Round 9
// 1031.594 us; speedup vs baseline: 2.9832x; 1.1238x over previous
//
#include <hip/hip_runtime.h>

// ---------------------------------------------------------------------------
// DGNLB fused pipeline.  ALL inputs/outputs are FP32 (reference is jnp.float32).
// B=2, C=64, H=W=64, N=4096.  Attention GEMMs run on bf16 MFMA.
// R9: gemm_nt occupancy push (__launch_bounds__(256,3)) + incremental staging
//     pointers (kill per-iter 64-bit addr recompute).  R8 swizzle kept.
// ---------------------------------------------------------------------------

typedef float f32x4 __attribute__((ext_vector_type(4)));
typedef __bf16 bf16x8 __attribute__((ext_vector_type(8)));
typedef int int4v __attribute__((ext_vector_type(4)));
typedef unsigned short ushort8 __attribute__((ext_vector_type(8)));

#define DI __device__ __forceinline__

DI float bf2f(unsigned short u) { union { unsigned int i; float f; } x; x.i = ((unsigned int)u) << 16; return x.f; }
DI unsigned short f2bf(float f) { union { float f; unsigned int i; } x; x.f = f; unsigned int r = x.i + 0x7fff + ((x.i >> 16) & 1); return (unsigned short)(r >> 16); }
DI float sane(float x) { return (x > -1e8f) ? ((x < 1e8f) ? x : 1e8f) : -1e8f; }

// async global->LDS, 16B per lane. LDS dest must be wave-uniform base + lane*16.
DI void async16(const unsigned short* g, unsigned short* l) {
    __builtin_amdgcn_global_load_lds(
        (const __attribute__((address_space(1))) void*)g,
        (__attribute__((address_space(3))) void*)l, 16, 0, 0);
}

__global__ __launch_bounds__(256) void diag_fill(float* __restrict__ out, int n, float val)
{
    int i = blockIdx.x * 256 + threadIdx.x;
    if (i < n) out[i] = val;
}

// ---------------------------------------------------------------------------
// NT GEMM: C[M][N] = A[M][K] * B[N][K]^T, bf16 operands, fp32 accum (MFMA).
// 128x128 tile, 4 waves 2x2, each wave 4x4 of 16x16x32 MFMAs, BK=32.
// LDS layout XOR-swizzled (chunk c of row r at slot c^(r&3)).
// Staging via 4 incremental per-thread global pointers (+32 elems/iter).
// mode 1: write bf16      mode 3: split-K partial fp32 (slice per blockIdx.z)
// ---------------------------------------------------------------------------
__global__ __launch_bounds__(256, 3) void gemm_nt(
    const unsigned short* __restrict__ A,
    const unsigned short* __restrict__ B,
    void* __restrict__ C,
    int M, int N, int K, int mode)
{
    __shared__ __align__(16) unsigned short As[128 * 32];
    __shared__ __align__(16) unsigned short Bs[128 * 32];
    const int tid  = threadIdx.x;
    const int bm   = blockIdx.y, bn = blockIdx.x;
    const int lane = tid & 63, wid = tid >> 6;
    const int wm   = (wid >> 1) * 64, wn = (wid & 1) * 64;
    const int l16  = lane & 15, quad = lane >> 4;

    f32x4 acc[4][4] = {};

    const int Kc   = K / (int)gridDim.z;
    const int kbeg = (int)blockIdx.z * Kc;
    const int nIter = Kc / 32;

    // ---- staging sources: 4 incremental pointers per thread ----
    const int row0 = tid >> 2,        cp0 = tid & 3;
    const int row1 = (tid + 256) >> 2, cp1 = (tid + 256) & 3;
    int ar0 = bm * 128 + row0; if (ar0 > M - 1) ar0 = M - 1;
    int ar1 = bm * 128 + row1; if (ar1 > M - 1) ar1 = M - 1;
    const unsigned short* pa0 = &A[(long)ar0 * K + kbeg + ((cp0 ^ (row0 & 3)) * 8)];
    const unsigned short* pa1 = &A[(long)ar1 * K + kbeg + ((cp1 ^ (row1 & 3)) * 8)];
    const unsigned short* pb0 = &B[(long)(bn * 128 + row0) * K + kbeg + ((cp0 ^ (row0 & 3)) * 8)];
    const unsigned short* pb1 = &B[(long)(bn * 128 + row1) * K + kbeg + ((cp1 ^ (row1 & 3)) * 8)];
    unsigned short* la0 = &As[row0 * 32 + cp0 * 8];
    unsigned short* la1 = &As[row1 * 32 + cp1 * 8];
    unsigned short* lb0 = &Bs[row0 * 32 + cp0 * 8];
    unsigned short* lb1 = &Bs[row1 * 32 + cp1 * 8];

    // swizzled chunk for fragment reads: slot = quad ^ (row&3), row&3 == l16&3
    const int sw = (quad ^ (l16 & 3)) * 8;

    for (int it = 0; it < nIter; it++) {
        __syncthreads();
        async16(pa0, la0);
        async16(pa1, la1);
        async16(pb0, lb0);
        async16(pb1, lb1);
        pa0 += 32; pa1 += 32; pb0 += 32; pb1 += 32;
        __syncthreads();
        bf16x8 af[4], bfr[4];
        #pragma unroll
        for (int i = 0; i < 4; i++) af[i]  = *(const bf16x8*)&As[(wm + i * 16 + l16) * 32 + sw];
        #pragma unroll
        for (int j = 0; j < 4; j++) bfr[j] = *(const bf16x8*)&Bs[(wn + j * 16 + l16) * 32 + sw];
        #pragma unroll
        for (int i = 0; i < 4; i++)
            #pragma unroll
            for (int j = 0; j < 4; j++)
                acc[i][j] = __builtin_amdgcn_mfma_f32_16x16x32_bf16(af[i], bfr[j], acc[i][j], 0, 0, 0);
    }

    #pragma unroll
    for (int i = 0; i < 4; i++) {
        int rb = bm * 128 + wm + i * 16 + quad * 4;   // C/D: col=lane&15, row=quad*4+reg
        #pragma unroll
        for (int j = 0; j < 4; j++) {
            int col = bn * 128 + wn + j * 16 + l16;
            #pragma unroll
            for (int r = 0; r < 4; r++) {
                int row = rb + r;
                if (row < M) {
                    long idx = (long)row * N + col;
                    float vv = acc[i][j][r];
                    if (mode == 1) ((unsigned short*)C)[idx] = f2bf(vv);
                    else           ((float*)C)[(long)blockIdx.z * M * N + idx] = vv;
                }
            }
        }
    }
}

// ---------------------------------------------------------------------------
// Row softmax over 4096 contiguous bf16 cols, in place (bf16 out).
// ---------------------------------------------------------------------------
__global__ __launch_bounds__(256) void row_softmax(unsigned short* __restrict__ buf)
{
    long row = blockIdx.x;
    unsigned short* p = buf + row * 4096L;
    const int tid = threadIdx.x, lane = tid & 63, wid = tid >> 6;
    float v[16]; float mx = -1e30f;
    #pragma unroll
    for (int t = 0; t < 16; t++) {
        float x = sane(bf2f(p[t * 256 + tid]));
        v[t] = x; mx = fmaxf(mx, x);
    }
    #pragma unroll
    for (int o = 32; o; o >>= 1) mx = fmaxf(mx, __shfl_xor(mx, o, 64));
    __shared__ float rmax[4], rsum[4];
    if (!lane) rmax[wid] = mx;
    __syncthreads();
    mx = fmaxf(fmaxf(rmax[0], rmax[1]), fmaxf(rmax[2], rmax[3]));
    float s = 0.f;
    #pragma unroll
    for (int t = 0; t < 16; t++) { v[t] = __expf(v[t] - mx); s += v[t]; }
    #pragma unroll
    for (int o = 32; o; o >>= 1) s += __shfl_xor(s, o, 64);
    if (!lane) rsum[wid] = s;
    __syncthreads();
    s = rsum[0] + rsum[1] + rsum[2] + rsum[3];
    float inv = 1.f / s;
    #pragma unroll
    for (int t = 0; t < 16; t++) p[t * 256 + tid] = f2bf(v[t] * inv);
}

// ---------------------------------------------------------------------------
// Column softmax (4096x4096 bf16), 3 phases (R5 winner).
// ---------------------------------------------------------------------------
__global__ __launch_bounds__(256) void colsm_partial(
    const unsigned short* __restrict__ buf,
    float* __restrict__ pmx, float* __restrict__ psum)
{
    const int tid = threadIdx.x;
    const int colgrp = tid & 63, rg = tid >> 6;
    const int cbase = blockIdx.x * 512 + colgrp * 8;
    const int r0 = blockIdx.y * 128 + rg * 32;
    const unsigned short* p = buf + (long)r0 * 4096 + cbase;
    float mx[8], s[8];
    #pragma unroll
    for (int j = 0; j < 8; j++) { mx[j] = -1e30f; s[j] = 0.f; }
    for (int r = 0; r < 32; r++) {
        ushort8 v = *(const ushort8*)(p + (long)r * 4096);
        #pragma unroll
        for (int j = 0; j < 8; j++) {
            float x = sane(bf2f(v[j]));
            float nm = fmaxf(mx[j], x);
            s[j] = s[j] * __expf(mx[j] - nm) + __expf(x - nm);
            mx[j] = nm;
        }
    }
    __shared__ float smx[4][512], ssm[4][512];
    #pragma unroll
    for (int j = 0; j < 8; j++) { smx[rg][colgrp * 8 + j] = mx[j]; ssm[rg][colgrp * 8 + j] = s[j]; }
    __syncthreads();
    for (int c = tid; c < 512; c += 256) {
        float M = fmaxf(fmaxf(smx[0][c], smx[1][c]), fmaxf(smx[2][c], smx[3][c]));
        float S = 0.f;
        #pragma unroll
        for (int i = 0; i < 4; i++) S += ssm[i][c] * __expf(smx[i][c] - M);
        int col = blockIdx.x * 512 + c;
        pmx[blockIdx.y * 4096 + col] = M;
        psum[blockIdx.y * 4096 + col] = S;
    }
}

__global__ __launch_bounds__(256) void colsm_combine(
    const float* __restrict__ pmx, const float* __restrict__ psum,
    float* __restrict__ gM, float* __restrict__ gInv)
{
    int col = blockIdx.x * 256 + threadIdx.x;   // grid 16
    float M = -1e30f;
    for (int ch = 0; ch < 32; ch++) M = fmaxf(M, pmx[ch * 4096 + col]);
    float S = 0.f;
    for (int ch = 0; ch < 32; ch++) S += psum[ch * 4096 + col] * __expf(pmx[ch * 4096 + col] - M);
    gM[col] = M;
    gInv[col] = 1.f / S;
}

__global__ __launch_bounds__(256) void colsm_norm(
    unsigned short* __restrict__ buf,
    const float* __restrict__ gM, const float* __restrict__ gInv)
{
    const int tid = threadIdx.x;
    const int colgrp = tid & 63, rg = tid >> 6;
    const int cbase = blockIdx.x * 512 + colgrp * 8;
    const int r0 = blockIdx.y * 128 + rg * 32;
    unsigned short* p = buf + (long)r0 * 4096 + cbase;
    float M[8], inv[8];
    #pragma unroll
    for (int j = 0; j < 8; j++) { M[j] = gM[cbase + j]; inv[j] = gInv[cbase + j]; }
    for (int r = 0; r < 32; r++) {
        ushort8 v = *(const ushort8*)(p + (long)r * 4096);
        ushort8 o;
        #pragma unroll
        for (int j = 0; j < 8; j++) o[j] = f2bf(__expf(sane(bf2f(v[j])) - M[j]) * inv[j]);
        *(ushort8*)(p + (long)r * 4096) = o;
    }
}

// ---------------------------------------------------------------------------
// 1x1 conv projections (fp32 in [B][64][4096], W fp32 [c][i], +bias) -> bf16.
// ---------------------------------------------------------------------------
__global__ __launch_bounds__(256) void proj_nc(
    const float* __restrict__ X, const float* __restrict__ W,
    const float* __restrict__ bias, unsigned short* __restrict__ out)
{
    const int b = blockIdx.y, nt = blockIdx.x, tid = threadIdx.x;
    __shared__ float Xs[64][64];   // [i][n]
    __shared__ float Ws[64][65];   // [i][c]
    __shared__ float Bb[64];
    for (int f = tid; f < 4096; f += 256) {
        int i = f >> 6, n = f & 63;
        Xs[i][n] = X[((long)b * 64 + i) * 4096 + nt * 64 + n];
        Ws[f & 63][f >> 6] = W[f];   // W[c*64+i] -> Ws[i][c]
    }
    if (tid < 64) Bb[tid] = bias[tid];
    __syncthreads();
    const int c = tid & 63, g = tid >> 6;
    float acc[16];
    #pragma unroll
    for (int j = 0; j < 16; j++) acc[j] = Bb[c];
    for (int i = 0; i < 64; i++) {
        float wv = Ws[i][c];
        #pragma unroll
        for (int j = 0; j < 16; j++) acc[j] += wv * Xs[i][g + 4 * j];
    }
    unsigned short* ob = out + ((long)b * 4096 + nt * 64) * 64;
    #pragma unroll
    for (int j = 0; j < 16; j++) ob[(g + 4 * j) * 64 + c] = f2bf(acc[j]);
}

__global__ __launch_bounds__(256) void proj_cn(
    const float* __restrict__ X, const float* __restrict__ W,
    const float* __restrict__ bias, unsigned short* __restrict__ out)
{
    const int b = blockIdx.y, nt = blockIdx.x, tid = threadIdx.x;
    __shared__ float Xs[64][64];   // [i][n]
    __shared__ float Ws[64][64];   // [c][i]
    __shared__ float Bb[64];
    for (int f = tid; f < 4096; f += 256) {
        int i = f >> 6, n = f & 63;
        Xs[i][n] = X[((long)b * 64 + i) * 4096 + nt * 64 + n];
        Ws[f >> 6][f & 63] = W[f];
    }
    if (tid < 64) Bb[tid] = bias[tid];
    __syncthreads();
    const int n = tid & 63, g = tid >> 6;
    float acc[16];
    #pragma unroll
    for (int j = 0; j < 16; j++) acc[j] = Bb[g + 4 * j];
    for (int i = 0; i < 64; i++) {
        float xv = Xs[i][n];
        #pragma unroll
        for (int j = 0; j < 16; j++) acc[j] += Ws[g + 4 * j][i] * xv;
    }
    unsigned short* ob = out + ((long)b * 64) * 4096 + nt * 64;
    #pragma unroll
    for (int j = 0; j < 16; j++) ob[(long)(g + 4 * j) * 4096 + n] = f2bf(acc[j]);
}

// ---------------------------------------------------------------------------
// combine split-K partials: pam = gamma*(sum_k part_k) + x.
// ---------------------------------------------------------------------------
__global__ __launch_bounds__(256) void combine_pam(
    const float* __restrict__ part, const float* __restrict__ x,
    const float* __restrict__ gammaPtr, float* __restrict__ pam)
{
    int i = blockIdx.x * 256 + threadIdx.x;   // 262144 total
    float s = part[i] + part[262144 + i] + part[2 * 262144 + i] + part[3 * 262144 + i];
    pam[i] = gammaPtr[0] * s + x[i];
}

// ---------------------------------------------------------------------------
// 3x3 conv (SAME) + BN + PReLU, fp32.
// ---------------------------------------------------------------------------
__global__ __launch_bounds__(256) void conv3x3_bn(
    const float* __restrict__ X, const float* __restrict__ W9,
    const float* __restrict__ bias,
    const float* __restrict__ bns, const float* __restrict__ bnb,
    const float* __restrict__ bnm, const float* __restrict__ bnv,
    const float* __restrict__ prelu, float* __restrict__ out)
{
    const int b = blockIdx.y, h = blockIdx.x, tid = threadIdx.x;
    __shared__ float Ls[3][64][66];
    __shared__ float ep0[64], ep1[64], ep2[64];
    __shared__ float alpha;
    for (int f = tid; f < 3 * 64 * 64; f += 256) {
        int ky = f >> 12, rem = f & 4095, ci = rem >> 6, w = rem & 63;
        int hh = h + ky - 1;
        Ls[ky][ci][w + 1] = (hh >= 0 && hh < 64) ? X[(((long)b * 64 + ci) * 64 + hh) * 64 + w] : 0.f;
    }
    for (int f = tid; f < 192; f += 256) {
        int ky = f >> 6, ci = f & 63;
        Ls[ky][ci][0] = 0.f; Ls[ky][ci][65] = 0.f;
    }
    if (tid < 64) {
        float inv = bns[tid] * rsqrtf(fmaxf(bnv[tid], 0.f) + 1e-5f);
        ep0[tid] = inv; ep1[tid] = bnb[tid] - bnm[tid] * inv; ep2[tid] = bias[tid];
    }
    if (tid == 0) alpha = prelu[0];
    __syncthreads();
    const int w = tid & 63, g = tid >> 6;   // co = g*16 + j
    float acc[16];
    #pragma unroll
    for (int j = 0; j < 16; j++) acc[j] = ep2[g * 16 + j];
    for (int ci = 0; ci < 64; ci++) {
        float v0 = Ls[0][ci][w], v1 = Ls[0][ci][w + 1], v2 = Ls[0][ci][w + 2];
        float v3 = Ls[1][ci][w], v4 = Ls[1][ci][w + 1], v5 = Ls[1][ci][w + 2];
        float v6 = Ls[2][ci][w], v7 = Ls[2][ci][w + 1], v8 = Ls[2][ci][w + 2];
        #pragma unroll
        for (int j = 0; j < 16; j++) {
            const float* wp = &W9[((g * 16 + j) * 64 + ci) * 9];
            acc[j] += wp[0] * v0 + wp[1] * v1 + wp[2] * v2
                    + wp[3] * v3 + wp[4] * v4 + wp[5] * v5
                    + wp[6] * v6 + wp[7] * v7 + wp[8] * v8;
        }
    }
    #pragma unroll
    for (int j = 0; j < 16; j++) {
        int co = g * 16 + j;
        float y = acc[j] * ep0[co] + ep1[co];
        y = y > 0.f ? y : alpha * y;
        out[(((long)b * 64 + co) * 64 + h) * 64 + w] = y;
    }
}

// ---------------------------------------------------------------------------
// 1x1 conv + BN + PReLU, fp32.
// ---------------------------------------------------------------------------
__global__ __launch_bounds__(256) void conv1x1_bn(
    const float* __restrict__ X, const float* __restrict__ W,
    const float* __restrict__ bias,
    const float* __restrict__ bns, const float* __restrict__ bnb,
    const float* __restrict__ bnm, const float* __restrict__ bnv,
    const float* __restrict__ prelu, float* __restrict__ out)
{
    const int b = blockIdx.y, nt = blockIdx.x, tid = threadIdx.x;
    __shared__ float Xs[64][64];   // [i][n]
    __shared__ float Ws[64][64];   // [c][i]
    __shared__ float ep0[64], ep1[64], ep2[64];
    __shared__ float alpha;
    for (int f = tid; f < 4096; f += 256) {
        int i = f >> 6, n = f & 63;
        Xs[i][n] = X[((long)b * 64 + i) * 4096 + nt * 64 + n];
        Ws[f >> 6][f & 63] = W[f];
    }
    if (tid < 64) {
        float inv = bns[tid] * rsqrtf(fmaxf(bnv[tid], 0.f) + 1e-5f);
        ep0[tid] = inv; ep1[tid] = bnb[tid] - bnm[tid] * inv; ep2[tid] = bias[tid];
    }
    if (tid == 0) alpha = prelu[0];
    __syncthreads();
    const int n = tid & 63, g = tid >> 6;
    float acc[16];
    #pragma unroll
    for (int j = 0; j < 16; j++) acc[j] = ep2[g + 4 * j];
    for (int i = 0; i < 64; i++) {
        float xv = Xs[i][n];
        #pragma unroll
        for (int j = 0; j < 16; j++) acc[j] += Ws[g + 4 * j][i] * xv;
    }
    #pragma unroll
    for (int j = 0; j < 16; j++) {
        int c = g + 4 * j;
        float y = acc[j] * ep0[c] + ep1[c];
        y = y > 0.f ? y : alpha * y;
        out[((long)b * 64 + c) * 4096 + nt * 64 + n] = y;
    }
}

// ---------------------------------------------------------------------------
// Split-K Gram: grid (64 kchunks, B). atomicAdd combine; out pre-zeroed.
// ---------------------------------------------------------------------------
__global__ __launch_bounds__(256) void gram_partial(
    const float* __restrict__ X, float* __restrict__ out)
{
    const int ch = blockIdx.x, b = blockIdx.y, tid = threadIdx.x;
    __shared__ float Xs[64][65];
    for (int f = tid; f < 4096; f += 256) {
        int ci = f >> 6, kk = f & 63;
        Xs[ci][kk] = X[((long)b * 64 + ci) * 4096 + ch * 64 + kk];
    }
    __syncthreads();
    const int d = tid & 63, g = tid >> 6;   // c = g + 4*j, j in [0,16)
    float acc[16] = {};
    for (int kk = 0; kk < 64; kk++) {
        float xd = Xs[d][kk];
        #pragma unroll
        for (int j = 0; j < 16; j++) acc[j] += Xs[g + 4 * j][kk] * xd;
    }
    #pragma unroll
    for (int j = 0; j < 16; j++)
        atomicAdd(&out[((long)b * 64 + (g + 4 * j)) * 64 + d], acc[j]);
}

// ---------------------------------------------------------------------------
// SE mean: gy[b][c] = mean_hw(G[b][c]).  Grid (64, B), one block per channel.
// ---------------------------------------------------------------------------
__global__ __launch_bounds__(256) void se_mean(
    const float* __restrict__ G, float* __restrict__ gy)
{
    const int c = blockIdx.x, b = blockIdx.y, tid = threadIdx.x;
    const int lane = tid & 63, wid = tid >> 6;
    const float* p = G + ((long)b * 64 + c) * 4096;
    float s = 0.f;
    #pragma unroll
    for (int t = 0; t < 4; t++) {
        f32x4 v = *(const f32x4*)(p + (t * 256 + tid) * 4);
        s += v[0] + v[1] + v[2] + v[3];
    }
    #pragma unroll
    for (int o = 32; o; o >>= 1) s += __shfl_xor(s, o, 64);
    __shared__ float ws[4];
    if (!lane) ws[wid] = s;
    __syncthreads();
    if (tid == 0) gy[b * 64 + c] = (ws[0] + ws[1] + ws[2] + ws[3]) * (1.f / 4096.f);
}

// ---------------------------------------------------------------------------
// SE gate: gy2[b][c] = sigmoid(fc2 . relu(fc1 . gy))   (tiny)
// ---------------------------------------------------------------------------
__global__ __launch_bounds__(64) void se_gate(
    const float* __restrict__ gy_in, const float* __restrict__ fc1,
    const float* __restrict__ fc2, float* __restrict__ gy2)
{
    const int b = blockIdx.x, tid = threadIdx.x;
    __shared__ float gy[64], r1[32];
    gy[tid] = gy_in[b * 64 + tid];
    __syncthreads();
    if (tid < 32) {
        float s = 0.f;
        for (int c = 0; c < 64; c++) s += fc1[tid * 64 + c] * gy[c];
        r1[tid] = fmaxf(s, 0.f);
    }
    __syncthreads();
    float s = 0.f;
    for (int r = 0; r < 32; r++) s += fc2[tid * 32 + r] * r1[r];
    gy2[b * 64 + tid] = 1.f / (1.f + __expf(-sane(s)));
}

// ---------------------------------------------------------------------------
// CAM small algebra (64x64 per batch). 64 threads, one row per thread.
// ---------------------------------------------------------------------------
__global__ __launch_bounds__(64) void cam_small(
    const float* __restrict__ gramx, const float* __restrict__ gramg,
    const float* __restrict__ gy2, float* __restrict__ gattc)
{
    const int b = blockIdx.x, tid = threadIdx.x;
    __shared__ float Ac[64][65], Acg[64][65];
    __shared__ float gys[64];
    gys[tid] = gy2[b * 64 + tid];
    __syncthreads();
    {
        const float* r = gramx + ((long)b * 64 + tid) * 64;
        float mx = -1e30f;
        for (int d = 0; d < 64; d++) mx = fmaxf(mx, sane(r[d]));
        float s = 0.f;
        for (int d = 0; d < 64; d++) s += __expf(sane(r[d]) - mx);
        float inv = 1.f / s;
        for (int d = 0; d < 64; d++) Ac[tid][d] = __expf(sane(r[d]) - mx) * inv;
    }
    {
        const float* r = gramg + ((long)b * 64 + tid) * 64;
        float gc = gys[tid];
        float mx = -1e30f;
        for (int d = 0; d < 64; d++) mx = fmaxf(mx, sane(gc * gys[d] * r[d]));
        float s = 0.f;
        for (int d = 0; d < 64; d++) s += __expf(sane(gc * gys[d] * r[d]) - mx);
        float inv = 1.f / s;
        for (int d = 0; d < 64; d++) Acg[tid][d] = __expf(sane(gc * gys[d] * r[d]) - mx) * inv;
    }
    __syncthreads();
    float ge[64];
    float mx1 = -1e30f, mn = 1e30f;
    for (int d = 0; d < 64; d++) {
        float s = 0.f;
        for (int k = 0; k < 64; k++) s += Ac[tid][k] * Acg[k][d];
        ge[d] = s;
        mx1 = fmaxf(mx1, s); mn = fminf(mn, s);
    }
    float M2 = mx1 - mn;   // max of (mx1 - ge)
    float s = 0.f;
    for (int d = 0; d < 64; d++) s += __expf((mx1 - ge[d]) - M2);
    float inv = 1.f / s;
    for (int d = 0; d < 64; d++)
        gattc[((long)b * 64 + tid) * 64 + d] = __expf((mx1 - ge[d]) - M2) * inv;
}

// ---------------------------------------------------------------------------
// cam = gamma_c * (gatt_c @ pam2) + pam2   (fp32)
// ---------------------------------------------------------------------------
__global__ __launch_bounds__(256) void cam_apply(
    const float* __restrict__ pam2, const float* __restrict__ gattc,
    const float* __restrict__ gammaPtr, float* __restrict__ cam)
{
    const int b = blockIdx.y, nt = blockIdx.x, tid = threadIdx.x;
    __shared__ float Xs[64][64];   // [d][n]
    __shared__ float Gt[64][64];   // [c][d]
    for (int f = tid; f < 4096; f += 256) {
        int d = f >> 6, n = f & 63;
        Xs[d][n] = pam2[((long)b * 64 + d) * 4096 + nt * 64 + n];
        Gt[f >> 6][f & 63] = gattc[((long)b * 64 + (f >> 6)) * 64 + (f & 63)];
    }
    __syncthreads();
    const float gamma = gammaPtr[0];
    const int n = tid & 63, g = tid >> 6;
    float acc[16] = {};
    for (int d = 0; d < 64; d++) {
        float xv = Xs[d][n];
        #pragma unroll
        for (int j = 0; j < 16; j++) acc[j] += Gt[g + 4 * j][d] * xv;
    }
    #pragma unroll
    for (int j = 0; j < 16; j++) {
        int c = g + 4 * j;
        cam[((long)b * 64 + c) * 4096 + nt * 64 + n] = gamma * acc[j] + Xs[c][n];
    }
}

// ---------------------------------------------------------------------------
// host
// ---------------------------------------------------------------------------
extern "C" void kernel_launch(void* const* d_in, const int* in_sizes, int n_in,
                              void* d_out, int out_size, void* d_ws, size_t ws_size,
                              hipStream_t stream)
{
    static const int exp_sizes[51] = {
        524288, 524288,
        4096, 64, 4096, 64, 4096, 64, 4096, 64, 4096, 64,
        1, 2048, 2048, 1,
        36864, 64, 64, 64, 64, 64, 1,
        4096, 64, 64, 64, 64, 64, 1,
        36864, 64, 64, 64, 64, 64, 1,
        4096, 64, 64, 64, 64, 64, 1,
        4096, 64, 64, 64, 64, 64, 1
    };
    bool map_ok = (n_in == 51) && (out_size == 524288);
    if (map_ok) for (int i = 0; i < 51; i++) if (in_sizes[i] != exp_sizes[i]) { map_ok = false; break; }

    const int diag_grid = (out_size + 255) / 256;
    if (!map_ok) {
        diag_fill<<<diag_grid, 256, 0, stream>>>((float*)d_out, out_size, 400.0f);
        return;
    }
    const size_t NEED_FULL = 121000000;   // verified available
    if (ws_size < NEED_FULL) {
        float code = (ws_size >= 88000000) ? 100.0f : (ws_size >= 55000000 ? 200.0f : 300.0f);
        diag_fill<<<diag_grid, 256, 0, stream>>>((float*)d_out, out_size, code);
        return;
    }

    auto IN = [&](int i) { return (const float*)d_in[i]; };
    const float* X = IN(0);
    const float* G = IN(1);

    char* wp_ = (char*)d_ws;
    auto alloc = [&](size_t bytes) -> void* {
        void* p = (void*)wp_;
        wp_ += (bytes + 255) & ~(size_t)255;
        return p;
    };
    unsigned short* qT   = (unsigned short*)alloc(2L * 4096 * 64 * 2);
    unsigned short* kT   = (unsigned short*)alloc(2L * 4096 * 64 * 2);
    unsigned short* qgT  = (unsigned short*)alloc(2L * 4096 * 64 * 2);
    unsigned short* kgT  = (unsigned short*)alloc(2L * 4096 * 64 * 2);
    unsigned short* vC   = (unsigned short*)alloc(2L * 64 * 4096 * 2);
    float* part  = (float*)alloc(4L * 64 * 4096 * 4);
    float* pam   = (float*)alloc(2L * 64 * 4096 * 4);
    float* tbuf  = (float*)alloc(2L * 64 * 4096 * 4);
    float* pam2  = (float*)alloc(2L * 64 * 4096 * 4);
    float* cam   = (float*)alloc(2L * 64 * 4096 * 4);
    float* gramx = (float*)alloc(2L * 64 * 64 * 4);
    float* gramg = (float*)alloc(2L * 64 * 64 * 4);
    float* gy    = (float*)alloc(2L * 64 * 4);
    float* gy2   = (float*)alloc(2L * 64 * 4);
    float* gattc = (float*)alloc(2L * 64 * 64 * 4);
    float* pmx   = (float*)alloc(32L * 4096 * 4);
    float* psum  = (float*)alloc(32L * 4096 * 4);
    float* gM    = (float*)alloc(4096L * 4);
    float* gInv  = (float*)alloc(4096L * 4);
    unsigned short* att  = (unsigned short*)alloc(4096L * 4096 * 2);   // per-batch reuse
    unsigned short* attg = (unsigned short*)alloc(4096L * 4096 * 2);
    unsigned short* pbuf = (unsigned short*)alloc(4096L * 4096 * 2);
    float* cam2 = tbuf;   // tbuf free after cconv1; reuse for cam2

    // ---- projections (fp32 -> bf16 operands) ----
    proj_nc<<<dim3(64, 2), 256, 0, stream>>>(X, IN(2),  IN(3),  qT);
    proj_nc<<<dim3(64, 2), 256, 0, stream>>>(X, IN(4),  IN(5),  kT);
    proj_nc<<<dim3(64, 2), 256, 0, stream>>>(G, IN(8),  IN(9),  qgT);
    proj_nc<<<dim3(64, 2), 256, 0, stream>>>(G, IN(10), IN(11), kgT);
    proj_cn<<<dim3(64, 2), 256, 0, stream>>>(X, IN(6),  IN(7),  vC);

    // ---- guided position attention, per batch (reuse big buffers) ----
    for (int b = 0; b < 2; b++) {
        const unsigned short* qTb  = qT  + (long)b * 4096 * 64;
        const unsigned short* kTb  = kT  + (long)b * 4096 * 64;
        const unsigned short* qgTb = qgT + (long)b * 4096 * 64;
        const unsigned short* kgTb = kgT + (long)b * 4096 * 64;
        gemm_nt<<<dim3(32, 32, 1), 256, 0, stream>>>(qTb,  kTb,  att,  4096, 4096, 64, 1);
        gemm_nt<<<dim3(32, 32, 1), 256, 0, stream>>>(kgTb, qgTb, attg, 4096, 4096, 64, 1);
        row_softmax<<<4096, 256, 0, stream>>>(att);             // att[n][k] bf16
        colsm_partial<<<dim3(8, 32), 256, 0, stream>>>(attg, pmx, psum);
        colsm_combine<<<16, 256, 0, stream>>>(pmx, psum, gM, gInv);
        colsm_norm<<<dim3(8, 32), 256, 0, stream>>>(attg, gM, gInv);
        gemm_nt<<<dim3(32, 32, 1), 256, 0, stream>>>(att, attg, pbuf, 4096, 4096, 4096, 1);
        row_softmax<<<4096, 256, 0, stream>>>(pbuf);
        gemm_nt<<<dim3(32, 1, 4), 256, 0, stream>>>(vC + (long)b * 64 * 4096, pbuf, part,
                                                    64, 4096, 4096, 3);
        combine_pam<<<1024, 256, 0, stream>>>(part, X + (long)b * 64 * 4096, IN(12),
                                              pam + (long)b * 64 * 4096);
    }

    // ---- pconv head ----
    conv3x3_bn<<<dim3(64, 2), 256, 0, stream>>>(pam, IN(16), IN(17), IN(18), IN(19), IN(20), IN(21), IN(22), tbuf);
    conv1x1_bn<<<dim3(64, 2), 256, 0, stream>>>(tbuf, IN(23), IN(24), IN(25), IN(26), IN(27), IN(28), IN(29), pam2);

    // ---- guided channel attention ----
    diag_fill<<<32, 256, 0, stream>>>(gramx, 8192, 0.0f);
    diag_fill<<<32, 256, 0, stream>>>(gramg, 8192, 0.0f);
    gram_partial<<<dim3(64, 2), 256, 0, stream>>>(pam2, gramx);
    gram_partial<<<dim3(64, 2), 256, 0, stream>>>(G,    gramg);
    se_mean<<<dim3(64, 2), 256, 0, stream>>>(G, gy);
    se_gate<<<2, 64, 0, stream>>>(gy, IN(13), IN(14), gy2);
    cam_small<<<2, 64, 0, stream>>>(gramx, gramg, gy2, gattc);
    cam_apply<<<dim3(64, 2), 256, 0, stream>>>(pam2, gattc, IN(15), cam);

    // ---- cconv + fconv heads ----
    conv3x3_bn<<<dim3(64, 2), 256, 0, stream>>>(cam, IN(30), IN(31), IN(32), IN(33), IN(34), IN(35), IN(36), pam);  // reuse pam as tmp
    conv1x1_bn<<<dim3(64, 2), 256, 0, stream>>>(pam, IN(37), IN(38), IN(39), IN(40), IN(41), IN(42), IN(43), cam2);
    conv1x1_bn<<<dim3(64, 2), 256, 0, stream>>>(cam2, IN(44), IN(45), IN(46), IN(47), IN(48), IN(49), IN(50), (float*)d_out);
}

// Round 10
// 881.403 us; speedup vs baseline: 3.4916x; 1.1704x over previous
//
#include <hip/hip_runtime.h>
#include <hip/hip_fp8.h>

// ---------------------------------------------------------------------------
// DGNLB fused pipeline.  ALL inputs/outputs are FP32 (reference is jnp.float32).
// B=2, C=64, H=W=64, N=4096.
// R10: P-GEMM operands (post-softmax att/attg) stored fp8 e4m3 scaled x256 ->
//      new gemm_p8 (BK=64, half the barriers, mfma fp8 16x16x32, descale in
//      epilogue).  Pre-softmax scores stay bf16.  conv3x3 co-split (z=4).
// ---------------------------------------------------------------------------

typedef float f32x4 __attribute__((ext_vector_type(4)));
typedef __bf16 bf16x8 __attribute__((ext_vector_type(8)));
typedef int int4v __attribute__((ext_vector_type(4)));
typedef unsigned short ushort8 __attribute__((ext_vector_type(8)));
typedef unsigned char uchar8 __attribute__((ext_vector_type(8)));

#define DI __device__ __forceinline__

DI float bf2f(unsigned short u) { union { unsigned int i; float f; } x; x.i = ((unsigned int)u) << 16; return x.f; }
DI unsigned short f2bf(float f) { union { float f; unsigned int i; } x; x.f = f; unsigned int r = x.i + 0x7fff + ((x.i >> 16) & 1); return (unsigned short)(r >> 16); }
DI unsigned char f2fp8(float f) { __hip_fp8_e4m3 h(f); return (unsigned char)h.__x; }
DI float sane(float x) { return (x > -1e8f) ? ((x < 1e8f) ? x : 1e8f) : -1e8f; }

// async global->LDS, 16B per lane. LDS dest must be wave-uniform base + lane*16.
DI void async16(const unsigned short* g, unsigned short* l) {
    __builtin_amdgcn_global_load_lds(
        (const __attribute__((address_space(1))) void*)g,
        (__attribute__((address_space(3))) void*)l, 16, 0, 0);
}
DI void async16b(const unsigned char* g, unsigned char* l) {
    __builtin_amdgcn_global_load_lds(
        (const __attribute__((address_space(1))) void*)g,
        (__attribute__((address_space(3))) void*)l, 16, 0, 0);
}

__global__ __launch_bounds__(256) void diag_fill(float* __restrict__ out, int n, float val)
{
    int i = blockIdx.x * 256 + threadIdx.x;
    if (i < n) out[i] = val;
}

// ---------------------------------------------------------------------------
// NT GEMM bf16: C[M][N] = A[M][K]*B[N][K]^T.  (score GEMMs, pam_o)
// mode 1: write bf16      mode 3: split-K partial fp32
// ---------------------------------------------------------------------------
__global__ __launch_bounds__(256, 3) void gemm_nt(
    const unsigned short* __restrict__ A,
    const unsigned short* __restrict__ B,
    void* __restrict__ C,
    int M, int N, int K, int mode)
{
    __shared__ __align__(16) unsigned short As[128 * 32];
    __shared__ __align__(16) unsigned short Bs[128 * 32];
    const int tid  = threadIdx.x;
    const int bm   = blockIdx.y, bn = blockIdx.x;
    const int lane = tid & 63, wid = tid >> 6;
    const int wm   = (wid >> 1) * 64, wn = (wid & 1) * 64;
    const int l16  = lane & 15, quad = lane >> 4;

    f32x4 acc[4][4] = {};

    const int Kc   = K / (int)gridDim.z;
    const int kbeg = (int)blockIdx.z * Kc;
    const int nIter = Kc / 32;

    const int row0 = tid >> 2,        cp0 = tid & 3;
    const int row1 = (tid + 256) >> 2, cp1 = (tid + 256) & 3;
    int ar0 = bm * 128 + row0; if (ar0 > M - 1) ar0 = M - 1;
    int ar1 = bm * 128 + row1; if (ar1 > M - 1) ar1 = M - 1;
    const unsigned short* pa0 = &A[(long)ar0 * K + kbeg + ((cp0 ^ (row0 & 3)) * 8)];
    const unsigned short* pa1 = &A[(long)ar1 * K + kbeg + ((cp1 ^ (row1 & 3)) * 8)];
    const unsigned short* pb0 = &B[(long)(bn * 128 + row0) * K + kbeg + ((cp0 ^ (row0 & 3)) * 8)];
    const unsigned short* pb1 = &B[(long)(bn * 128 + row1) * K + kbeg + ((cp1 ^ (row1 & 3)) * 8)];
    unsigned short* la0 = &As[row0 * 32 + cp0 * 8];
    unsigned short* la1 = &As[row1 * 32 + cp1 * 8];
    unsigned short* lb0 = &Bs[row0 * 32 + cp0 * 8];
    unsigned short* lb1 = &Bs[row1 * 32 + cp1 * 8];

    const int sw = (quad ^ (l16 & 3)) * 8;

    for (int it = 0; it < nIter; it++) {
        __syncthreads();
        async16(pa0, la0);
        async16(pa1, la1);
        async16(pb0, lb0);
        async16(pb1, lb1);
        pa0 += 32; pa1 += 32; pb0 += 32; pb1 += 32;
        __syncthreads();
        bf16x8 af[4], bfr[4];
        #pragma unroll
        for (int i = 0; i < 4; i++) af[i]  = *(const bf16x8*)&As[(wm + i * 16 + l16) * 32 + sw];
        #pragma unroll
        for (int j = 0; j < 4; j++) bfr[j] = *(const bf16x8*)&Bs[(wn + j * 16 + l16) * 32 + sw];
        #pragma unroll
        for (int i = 0; i < 4; i++)
            #pragma unroll
            for (int j = 0; j < 4; j++)
                acc[i][j] = __builtin_amdgcn_mfma_f32_16x16x32_bf16(af[i], bfr[j], acc[i][j], 0, 0, 0);
    }

    #pragma unroll
    for (int i = 0; i < 4; i++) {
        int rb = bm * 128 + wm + i * 16 + quad * 4;
        #pragma unroll
        for (int j = 0; j < 4; j++) {
            int col = bn * 128 + wn + j * 16 + l16;
            #pragma unroll
            for (int r = 0; r < 4; r++) {
                int row = rb + r;
                if (row < M) {
                    long idx = (long)row * N + col;
                    float vv = acc[i][j][r];
                    if (mode == 1) ((unsigned short*)C)[idx] = f2bf(vv);
                    else           ((float*)C)[(long)blockIdx.z * M * N + idx] = vv;
                }
            }
        }
    }
}

// ---------------------------------------------------------------------------
// fp8 NT GEMM: C[4096][4096](bf16) = (A8/256) * (B8/256)^T.  BK=64, 64 iters.
// A8,B8: u8 e4m3, K-contiguous.  16B-chunk XOR swizzle (chunk c of row r at
// slot c^(r&3)).  Descale 1/65536 in epilogue.
// ---------------------------------------------------------------------------
__global__ __launch_bounds__(256, 3) void gemm_p8(
    const unsigned char* __restrict__ A,
    const unsigned char* __restrict__ B,
    unsigned short* __restrict__ C, int N, int K)
{
    __shared__ __align__(16) unsigned char As[128 * 64];
    __shared__ __align__(16) unsigned char Bs[128 * 64];
    const int tid  = threadIdx.x;
    const int bm   = blockIdx.y, bn = blockIdx.x;
    const int lane = tid & 63, wid = tid >> 6;
    const int wm   = (wid >> 1) * 64, wn = (wid & 1) * 64;
    const int l16  = lane & 15, quad = lane >> 4;

    f32x4 acc[4][4] = {};

    const int row0 = tid >> 2,        cp0 = tid & 3;
    const int row1 = (tid + 256) >> 2, cp1 = (tid + 256) & 3;
    const unsigned char* pa0 = &A[(long)(bm * 128 + row0) * K + ((cp0 ^ (row0 & 3)) * 16)];
    const unsigned char* pa1 = &A[(long)(bm * 128 + row1) * K + ((cp1 ^ (row1 & 3)) * 16)];
    const unsigned char* pb0 = &B[(long)(bn * 128 + row0) * K + ((cp0 ^ (row0 & 3)) * 16)];
    const unsigned char* pb1 = &B[(long)(bn * 128 + row1) * K + ((cp1 ^ (row1 & 3)) * 16)];
    unsigned char* la0 = &As[row0 * 64 + cp0 * 16];
    unsigned char* la1 = &As[row1 * 64 + cp1 * 16];
    unsigned char* lb0 = &Bs[row0 * 64 + cp0 * 16];
    unsigned char* lb1 = &Bs[row1 * 64 + cp1 * 16];

    const int off8 = (quad & 1) * 8;
    const int qh   = quad >> 1;
    const int xr   = l16 & 3;

    const int nIter = K / 64;
    for (int it = 0; it < nIter; it++) {
        __syncthreads();
        async16b(pa0, la0);
        async16b(pa1, la1);
        async16b(pb0, lb0);
        async16b(pb1, lb1);
        pa0 += 64; pa1 += 64; pb0 += 64; pb1 += 64;
        __syncthreads();
        #pragma unroll
        for (int h = 0; h < 2; h++) {
            const int ch = ((2 * h + qh) ^ xr) * 16 + off8;
            long af[4], bfr[4];
            #pragma unroll
            for (int i = 0; i < 4; i++) af[i]  = *(const long*)&As[(wm + i * 16 + l16) * 64 + ch];
            #pragma unroll
            for (int j = 0; j < 4; j++) bfr[j] = *(const long*)&Bs[(wn + j * 16 + l16) * 64 + ch];
            #pragma unroll
            for (int i = 0; i < 4; i++)
                #pragma unroll
                for (int j = 0; j < 4; j++)
                    acc[i][j] = __builtin_amdgcn_mfma_f32_16x16x32_fp8_fp8(af[i], bfr[j], acc[i][j], 0, 0, 0);
        }
    }

    const float ds = 1.f / 65536.f;
    #pragma unroll
    for (int i = 0; i < 4; i++) {
        int rb = bm * 128 + wm + i * 16 + quad * 4;
        #pragma unroll
        for (int j = 0; j < 4; j++) {
            int col = bn * 128 + wn + j * 16 + l16;
            #pragma unroll
            for (int r = 0; r < 4; r++)
                C[(long)(rb + r) * N + col] = f2bf(acc[i][j][r] * ds);
        }
    }
}

// ---------------------------------------------------------------------------
// Row softmax bf16 in-place (for P before pam_o).
// ---------------------------------------------------------------------------
__global__ __launch_bounds__(256) void row_softmax(unsigned short* __restrict__ buf)
{
    long row = blockIdx.x;
    unsigned short* p = buf + row * 4096L;
    const int tid = threadIdx.x, lane = tid & 63, wid = tid >> 6;
    float v[16]; float mx = -1e30f;
    #pragma unroll
    for (int t = 0; t < 16; t++) {
        float x = sane(bf2f(p[t * 256 + tid]));
        v[t] = x; mx = fmaxf(mx, x);
    }
    #pragma unroll
    for (int o = 32; o; o >>= 1) mx = fmaxf(mx, __shfl_xor(mx, o, 64));
    __shared__ float rmax[4], rsum[4];
    if (!lane) rmax[wid] = mx;
    __syncthreads();
    mx = fmaxf(fmaxf(rmax[0], rmax[1]), fmaxf(rmax[2], rmax[3]));
    float s = 0.f;
    #pragma unroll
    for (int t = 0; t < 16; t++) { v[t] = __expf(v[t] - mx); s += v[t]; }
    #pragma unroll
    for (int o = 32; o; o >>= 1) s += __shfl_xor(s, o, 64);
    if (!lane) rsum[wid] = s;
    __syncthreads();
    s = rsum[0] + rsum[1] + rsum[2] + rsum[3];
    float inv = 1.f / s;
    #pragma unroll
    for (int t = 0; t < 16; t++) p[t * 256 + tid] = f2bf(v[t] * inv);
}

// ---------------------------------------------------------------------------
// Row softmax bf16 -> fp8 x256 (att path).
// ---------------------------------------------------------------------------
__global__ __launch_bounds__(256) void row_softmax_f8(
    const unsigned short* __restrict__ in, unsigned char* __restrict__ out)
{
    long row = blockIdx.x;
    const unsigned short* p = in + row * 4096L;
    unsigned char* q = out + row * 4096L;
    const int tid = threadIdx.x, lane = tid & 63, wid = tid >> 6;
    float v[16]; float mx = -1e30f;
    #pragma unroll
    for (int t = 0; t < 16; t++) {
        float x = sane(bf2f(p[t * 256 + tid]));
        v[t] = x; mx = fmaxf(mx, x);
    }
    #pragma unroll
    for (int o = 32; o; o >>= 1) mx = fmaxf(mx, __shfl_xor(mx, o, 64));
    __shared__ float rmax[4], rsum[4];
    if (!lane) rmax[wid] = mx;
    __syncthreads();
    mx = fmaxf(fmaxf(rmax[0], rmax[1]), fmaxf(rmax[2], rmax[3]));
    float s = 0.f;
    #pragma unroll
    for (int t = 0; t < 16; t++) { v[t] = __expf(v[t] - mx); s += v[t]; }
    #pragma unroll
    for (int o = 32; o; o >>= 1) s += __shfl_xor(s, o, 64);
    if (!lane) rsum[wid] = s;
    __syncthreads();
    s = rsum[0] + rsum[1] + rsum[2] + rsum[3];
    float inv = 256.f / s;
    #pragma unroll
    for (int t = 0; t < 16; t++) q[t * 256 + tid] = f2fp8(v[t] * inv);
}

// ---------------------------------------------------------------------------
// Column softmax (attS bf16 -> attgF8 fp8 x256), 3 phases.
// ---------------------------------------------------------------------------
__global__ __launch_bounds__(256) void colsm_partial(
    const unsigned short* __restrict__ buf,
    float* __restrict__ pmx, float* __restrict__ psum)
{
    const int tid = threadIdx.x;
    const int colgrp = tid & 63, rg = tid >> 6;
    const int cbase = blockIdx.x * 512 + colgrp * 8;
    const int r0 = blockIdx.y * 128 + rg * 32;
    const unsigned short* p = buf + (long)r0 * 4096 + cbase;
    float mx[8], s[8];
    #pragma unroll
    for (int j = 0; j < 8; j++) { mx[j] = -1e30f; s[j] = 0.f; }
    for (int r = 0; r < 32; r++) {
        ushort8 v = *(const ushort8*)(p + (long)r * 4096);
        #pragma unroll
        for (int j = 0; j < 8; j++) {
            float x = sane(bf2f(v[j]));
            float nm = fmaxf(mx[j], x);
            s[j] = s[j] * __expf(mx[j] - nm) + __expf(x - nm);
            mx[j] = nm;
        }
    }
    __shared__ float smx[4][512], ssm[4][512];
    #pragma unroll
    for (int j = 0; j < 8; j++) { smx[rg][colgrp * 8 + j] = mx[j]; ssm[rg][colgrp * 8 + j] = s[j]; }
    __syncthreads();
    for (int c = tid; c < 512; c += 256) {
        float M = fmaxf(fmaxf(smx[0][c], smx[1][c]), fmaxf(smx[2][c], smx[3][c]));
        float S = 0.f;
        #pragma unroll
        for (int i = 0; i < 4; i++) S += ssm[i][c] * __expf(smx[i][c] - M);
        int col = blockIdx.x * 512 + c;
        pmx[blockIdx.y * 4096 + col] = M;
        psum[blockIdx.y * 4096 + col] = S;
    }
}

__global__ __launch_bounds__(256) void colsm_combine(
    const float* __restrict__ pmx, const float* __restrict__ psum,
    float* __restrict__ gM, float* __restrict__ gInv)
{
    int col = blockIdx.x * 256 + threadIdx.x;   // grid 16
    float M = -1e30f;
    for (int ch = 0; ch < 32; ch++) M = fmaxf(M, pmx[ch * 4096 + col]);
    float S = 0.f;
    for (int ch = 0; ch < 32; ch++) S += psum[ch * 4096 + col] * __expf(pmx[ch * 4096 + col] - M);
    gM[col] = M;
    gInv[col] = 256.f / S;   // fold the fp8 scale in
}

__global__ __launch_bounds__(256) void colsm_norm_f8(
    const unsigned short* __restrict__ in, unsigned char* __restrict__ out,
    const float* __restrict__ gM, const float* __restrict__ gInv)
{
    const int tid = threadIdx.x;
    const int colgrp = tid & 63, rg = tid >> 6;
    const int cbase = blockIdx.x * 512 + colgrp * 8;
    const int r0 = blockIdx.y * 128 + rg * 32;
    const unsigned short* p = in + (long)r0 * 4096 + cbase;
    unsigned char* q = out + (long)r0 * 4096 + cbase;
    float M[8], inv[8];
    #pragma unroll
    for (int j = 0; j < 8; j++) { M[j] = gM[cbase + j]; inv[j] = gInv[cbase + j]; }
    for (int r = 0; r < 32; r++) {
        ushort8 v = *(const ushort8*)(p + (long)r * 4096);
        uchar8 o;
        #pragma unroll
        for (int j = 0; j < 8; j++) o[j] = f2fp8(__expf(sane(bf2f(v[j])) - M[j]) * inv[j]);
        *(uchar8*)(q + (long)r * 4096) = o;
    }
}

// ---------------------------------------------------------------------------
// 1x1 conv projections (fp32 -> bf16 operands).
// ---------------------------------------------------------------------------
__global__ __launch_bounds__(256) void proj_nc(
    const float* __restrict__ X, const float* __restrict__ W,
    const float* __restrict__ bias, unsigned short* __restrict__ out)
{
    const int b = blockIdx.y, nt = blockIdx.x, tid = threadIdx.x;
    __shared__ float Xs[64][64];
    __shared__ float Ws[64][65];
    __shared__ float Bb[64];
    for (int f = tid; f < 4096; f += 256) {
        int i = f >> 6, n = f & 63;
        Xs[i][n] = X[((long)b * 64 + i) * 4096 + nt * 64 + n];
        Ws[f & 63][f >> 6] = W[f];
    }
    if (tid < 64) Bb[tid] = bias[tid];
    __syncthreads();
    const int c = tid & 63, g = tid >> 6;
    float acc[16];
    #pragma unroll
    for (int j = 0; j < 16; j++) acc[j] = Bb[c];
    for (int i = 0; i < 64; i++) {
        float wv = Ws[i][c];
        #pragma unroll
        for (int j = 0; j < 16; j++) acc[j] += wv * Xs[i][g + 4 * j];
    }
    unsigned short* ob = out + ((long)b * 4096 + nt * 64) * 64;
    #pragma unroll
    for (int j = 0; j < 16; j++) ob[(g + 4 * j) * 64 + c] = f2bf(acc[j]);
}

__global__ __launch_bounds__(256) void proj_cn(
    const float* __restrict__ X, const float* __restrict__ W,
    const float* __restrict__ bias, unsigned short* __restrict__ out)
{
    const int b = blockIdx.y, nt = blockIdx.x, tid = threadIdx.x;
    __shared__ float Xs[64][64];
    __shared__ float Ws[64][64];
    __shared__ float Bb[64];
    for (int f = tid; f < 4096; f += 256) {
        int i = f >> 6, n = f & 63;
        Xs[i][n] = X[((long)b * 64 + i) * 4096 + nt * 64 + n];
        Ws[f >> 6][f & 63] = W[f];
    }
    if (tid < 64) Bb[tid] = bias[tid];
    __syncthreads();
    const int n = tid & 63, g = tid >> 6;
    float acc[16];
    #pragma unroll
    for (int j = 0; j < 16; j++) acc[j] = Bb[g + 4 * j];
    for (int i = 0; i < 64; i++) {
        float xv = Xs[i][n];
        #pragma unroll
        for (int j = 0; j < 16; j++) acc[j] += Ws[g + 4 * j][i] * xv;
    }
    unsigned short* ob = out + ((long)b * 64) * 4096 + nt * 64;
    #pragma unroll
    for (int j = 0; j < 16; j++) ob[(long)(g + 4 * j) * 4096 + n] = f2bf(acc[j]);
}

// ---------------------------------------------------------------------------
// combine split-K partials: pam = gamma*(sum_k part_k) + x.
// ---------------------------------------------------------------------------
__global__ __launch_bounds__(256) void combine_pam(
    const float* __restrict__ part, const float* __restrict__ x,
    const float* __restrict__ gammaPtr, float* __restrict__ pam)
{
    int i = blockIdx.x * 256 + threadIdx.x;
    float s = part[i] + part[262144 + i] + part[2 * 262144 + i] + part[3 * 262144 + i];
    pam[i] = gammaPtr[0] * s + x[i];
}

// ---------------------------------------------------------------------------
// 3x3 conv (SAME) + BN + PReLU, fp32.  Grid (64 h, B, 4 co-groups of 16).
// ---------------------------------------------------------------------------
__global__ __launch_bounds__(256) void conv3x3_bn(
    const float* __restrict__ X, const float* __restrict__ W9,
    const float* __restrict__ bias,
    const float* __restrict__ bns, const float* __restrict__ bnb,
    const float* __restrict__ bnm, const float* __restrict__ bnv,
    const float* __restrict__ prelu, float* __restrict__ out)
{
    const int b = blockIdx.y, h = blockIdx.x, co0 = blockIdx.z * 16, tid = threadIdx.x;
    __shared__ float Ls[3][64][66];
    __shared__ float ep0[64], ep1[64], ep2[64];
    __shared__ float alpha;
    for (int f = tid; f < 3 * 64 * 64; f += 256) {
        int ky = f >> 12, rem = f & 4095, ci = rem >> 6, w = rem & 63;
        int hh = h + ky - 1;
        Ls[ky][ci][w + 1] = (hh >= 0 && hh < 64) ? X[(((long)b * 64 + ci) * 64 + hh) * 64 + w] : 0.f;
    }
    for (int f = tid; f < 192; f += 256) {
        int ky = f >> 6, ci = f & 63;
        Ls[ky][ci][0] = 0.f; Ls[ky][ci][65] = 0.f;
    }
    if (tid < 64) {
        float inv = bns[tid] * rsqrtf(fmaxf(bnv[tid], 0.f) + 1e-5f);
        ep0[tid] = inv; ep1[tid] = bnb[tid] - bnm[tid] * inv; ep2[tid] = bias[tid];
    }
    if (tid == 0) alpha = prelu[0];
    __syncthreads();
    const int w = tid & 63, g = tid >> 6;   // co = co0 + g*4 + j
    float acc[4];
    #pragma unroll
    for (int j = 0; j < 4; j++) acc[j] = ep2[co0 + g * 4 + j];
    for (int ci = 0; ci < 64; ci++) {
        float v0 = Ls[0][ci][w], v1 = Ls[0][ci][w + 1], v2 = Ls[0][ci][w + 2];
        float v3 = Ls[1][ci][w], v4 = Ls[1][ci][w + 1], v5 = Ls[1][ci][w + 2];
        float v6 = Ls[2][ci][w], v7 = Ls[2][ci][w + 1], v8 = Ls[2][ci][w + 2];
        #pragma unroll
        for (int j = 0; j < 4; j++) {
            const float* wp = &W9[((co0 + g * 4 + j) * 64 + ci) * 9];
            acc[j] += wp[0] * v0 + wp[1] * v1 + wp[2] * v2
                    + wp[3] * v3 + wp[4] * v4 + wp[5] * v5
                    + wp[6] * v6 + wp[7] * v7 + wp[8] * v8;
        }
    }
    #pragma unroll
    for (int j = 0; j < 4; j++) {
        int co = co0 + g * 4 + j;
        float y = acc[j] * ep0[co] + ep1[co];
        y = y > 0.f ? y : alpha * y;
        out[(((long)b * 64 + co) * 64 + h) * 64 + w] = y;
    }
}

// ---------------------------------------------------------------------------
// 1x1 conv + BN + PReLU, fp32.
// ---------------------------------------------------------------------------
__global__ __launch_bounds__(256) void conv1x1_bn(
    const float* __restrict__ X, const float* __restrict__ W,
    const float* __restrict__ bias,
    const float* __restrict__ bns, const float* __restrict__ bnb,
    const float* __restrict__ bnm, const float* __restrict__ bnv,
    const float* __restrict__ prelu, float* __restrict__ out)
{
    const int b = blockIdx.y, nt = blockIdx.x, tid = threadIdx.x;
    __shared__ float Xs[64][64];
    __shared__ float Ws[64][64];
    __shared__ float ep0[64], ep1[64], ep2[64];
    __shared__ float alpha;
    for (int f = tid; f < 4096; f += 256) {
        int i = f >> 6, n = f & 63;
        Xs[i][n] = X[((long)b * 64 + i) * 4096 + nt * 64 + n];
        Ws[f >> 6][f & 63] = W[f];
    }
    if (tid < 64) {
        float inv = bns[tid] * rsqrtf(fmaxf(bnv[tid], 0.f) + 1e-5f);
        ep0[tid] = inv; ep1[tid] = bnb[tid] - bnm[tid] * inv; ep2[tid] = bias[tid];
    }
    if (tid == 0) alpha = prelu[0];
    __syncthreads();
    const int n = tid & 63, g = tid >> 6;
    float acc[16];
    #pragma unroll
    for (int j = 0; j < 16; j++) acc[j] = ep2[g + 4 * j];
    for (int i = 0; i < 64; i++) {
        float xv = Xs[i][n];
        #pragma unroll
        for (int j = 0; j < 16; j++) acc[j] += Ws[g + 4 * j][i] * xv;
    }
    #pragma unroll
    for (int j = 0; j < 16; j++) {
        int c = g + 4 * j;
        float y = acc[j] * ep0[c] + ep1[c];
        y = y > 0.f ? y : alpha * y;
        out[((long)b * 64 + c) * 4096 + nt * 64 + n] = y;
    }
}

// ---------------------------------------------------------------------------
// Split-K Gram: grid (64 kchunks, B). atomicAdd combine; out pre-zeroed.
// ---------------------------------------------------------------------------
__global__ __launch_bounds__(256) void gram_partial(
    const float* __restrict__ X, float* __restrict__ out)
{
    const int ch = blockIdx.x, b = blockIdx.y, tid = threadIdx.x;
    __shared__ float Xs[64][65];
    for (int f = tid; f < 4096; f += 256) {
        int ci = f >> 6, kk = f & 63;
        Xs[ci][kk] = X[((long)b * 64 + ci) * 4096 + ch * 64 + kk];
    }
    __syncthreads();
    const int d = tid & 63, g = tid >> 6;
    float acc[16] = {};
    for (int kk = 0; kk < 64; kk++) {
        float xd = Xs[d][kk];
        #pragma unroll
        for (int j = 0; j < 16; j++) acc[j] += Xs[g + 4 * j][kk] * xd;
    }
    #pragma unroll
    for (int j = 0; j < 16; j++)
        atomicAdd(&out[((long)b * 64 + (g + 4 * j)) * 64 + d], acc[j]);
}

// ---------------------------------------------------------------------------
// SE mean + gate.
// ---------------------------------------------------------------------------
__global__ __launch_bounds__(256) void se_mean(
    const float* __restrict__ G, float* __restrict__ gy)
{
    const int c = blockIdx.x, b = blockIdx.y, tid = threadIdx.x;
    const int lane = tid & 63, wid = tid >> 6;
    const float* p = G + ((long)b * 64 + c) * 4096;
    float s = 0.f;
    #pragma unroll
    for (int t = 0; t < 4; t++) {
        f32x4 v = *(const f32x4*)(p + (t * 256 + tid) * 4);
        s += v[0] + v[1] + v[2] + v[3];
    }
    #pragma unroll
    for (int o = 32; o; o >>= 1) s += __shfl_xor(s, o, 64);
    __shared__ float ws[4];
    if (!lane) ws[wid] = s;
    __syncthreads();
    if (tid == 0) gy[b * 64 + c] = (ws[0] + ws[1] + ws[2] + ws[3]) * (1.f / 4096.f);
}

__global__ __launch_bounds__(64) void se_gate(
    const float* __restrict__ gy_in, const float* __restrict__ fc1,
    const float* __restrict__ fc2, float* __restrict__ gy2)
{
    const int b = blockIdx.x, tid = threadIdx.x;
    __shared__ float gy[64], r1[32];
    gy[tid] = gy_in[b * 64 + tid];
    __syncthreads();
    if (tid < 32) {
        float s = 0.f;
        for (int c = 0; c < 64; c++) s += fc1[tid * 64 + c] * gy[c];
        r1[tid] = fmaxf(s, 0.f);
    }
    __syncthreads();
    float s = 0.f;
    for (int r = 0; r < 32; r++) s += fc2[tid * 32 + r] * r1[r];
    gy2[b * 64 + tid] = 1.f / (1.f + __expf(-sane(s)));
}

// ---------------------------------------------------------------------------
// CAM small algebra (64x64 per batch).
// ---------------------------------------------------------------------------
__global__ __launch_bounds__(64) void cam_small(
    const float* __restrict__ gramx, const float* __restrict__ gramg,
    const float* __restrict__ gy2, float* __restrict__ gattc)
{
    const int b = blockIdx.x, tid = threadIdx.x;
    __shared__ float Ac[64][65], Acg[64][65];
    __shared__ float gys[64];
    gys[tid] = gy2[b * 64 + tid];
    __syncthreads();
    {
        const float* r = gramx + ((long)b * 64 + tid) * 64;
        float mx = -1e30f;
        for (int d = 0; d < 64; d++) mx = fmaxf(mx, sane(r[d]));
        float s = 0.f;
        for (int d = 0; d < 64; d++) s += __expf(sane(r[d]) - mx);
        float inv = 1.f / s;
        for (int d = 0; d < 64; d++) Ac[tid][d] = __expf(sane(r[d]) - mx) * inv;
    }
    {
        const float* r = gramg + ((long)b * 64 + tid) * 64;
        float gc = gys[tid];
        float mx = -1e30f;
        for (int d = 0; d < 64; d++) mx = fmaxf(mx, sane(gc * gys[d] * r[d]));
        float s = 0.f;
        for (int d = 0; d < 64; d++) s += __expf(sane(gc * gys[d] * r[d]) - mx);
        float inv = 1.f / s;
        for (int d = 0; d < 64; d++) Acg[tid][d] = __expf(sane(gc * gys[d] * r[d]) - mx) * inv;
    }
    __syncthreads();
    float ge[64];
    float mx1 = -1e30f, mn = 1e30f;
    for (int d = 0; d < 64; d++) {
        float s = 0.f;
        for (int k = 0; k < 64; k++) s += Ac[tid][k] * Acg[k][d];
        ge[d] = s;
        mx1 = fmaxf(mx1, s); mn = fminf(mn, s);
    }
    float M2 = mx1 - mn;
    float s = 0.f;
    for (int d = 0; d < 64; d++) s += __expf((mx1 - ge[d]) - M2);
    float inv = 1.f / s;
    for (int d = 0; d < 64; d++)
        gattc[((long)b * 64 + tid) * 64 + d] = __expf((mx1 - ge[d]) - M2) * inv;
}

// ---------------------------------------------------------------------------
// cam = gamma_c * (gatt_c @ pam2) + pam2   (fp32)
// ---------------------------------------------------------------------------
__global__ __launch_bounds__(256) void cam_apply(
    const float* __restrict__ pam2, const float* __restrict__ gattc,
    const float* __restrict__ gammaPtr, float* __restrict__ cam)
{
    const int b = blockIdx.y, nt = blockIdx.x, tid = threadIdx.x;
    __shared__ float Xs[64][64];
    __shared__ float Gt[64][64];
    for (int f = tid; f < 4096; f += 256) {
        int d = f >> 6, n = f & 63;
        Xs[d][n] = pam2[((long)b * 64 + d) * 4096 + nt * 64 + n];
        Gt[f >> 6][f & 63] = gattc[((long)b * 64 + (f >> 6)) * 64 + (f & 63)];
    }
    __syncthreads();
    const float gamma = gammaPtr[0];
    const int n = tid & 63, g = tid >> 6;
    float acc[16] = {};
    for (int d = 0; d < 64; d++) {
        float xv = Xs[d][n];
        #pragma unroll
        for (int j = 0; j < 16; j++) acc[j] += Gt[g + 4 * j][d] * xv;
    }
    #pragma unroll
    for (int j = 0; j < 16; j++) {
        int c = g + 4 * j;
        cam[((long)b * 64 + c) * 4096 + nt * 64 + n] = gamma * acc[j] + Xs[c][n];
    }
}

// ---------------------------------------------------------------------------
// host
// ---------------------------------------------------------------------------
extern "C" void kernel_launch(void* const* d_in, const int* in_sizes, int n_in,
                              void* d_out, int out_size, void* d_ws, size_t ws_size,
                              hipStream_t stream)
{
    static const int exp_sizes[51] = {
        524288, 524288,
        4096, 64, 4096, 64, 4096, 64, 4096, 64, 4096, 64,
        1, 2048, 2048, 1,
        36864, 64, 64, 64, 64, 64, 1,
        4096, 64, 64, 64, 64, 64, 1,
        36864, 64, 64, 64, 64, 64, 1,
        4096, 64, 64, 64, 64, 64, 1,
        4096, 64, 64, 64, 64, 64, 1
    };
    bool map_ok = (n_in == 51) && (out_size == 524288);
    if (map_ok) for (int i = 0; i < 51; i++) if (in_sizes[i] != exp_sizes[i]) { map_ok = false; break; }

    const int diag_grid = (out_size + 255) / 256;
    if (!map_ok) {
        diag_fill<<<diag_grid, 256, 0, stream>>>((float*)d_out, out_size, 400.0f);
        return;
    }
    const size_t NEED_FULL = 121000000;   // verified available; new layout ~114MB
    if (ws_size < NEED_FULL) {
        float code = (ws_size >= 88000000) ? 100.0f : (ws_size >= 55000000 ? 200.0f : 300.0f);
        diag_fill<<<diag_grid, 256, 0, stream>>>((float*)d_out, out_size, code);
        return;
    }

    auto IN = [&](int i) { return (const float*)d_in[i]; };
    const float* X = IN(0);
    const float* G = IN(1);

    char* wp_ = (char*)d_ws;
    auto alloc = [&](size_t bytes) -> void* {
        void* p = (void*)wp_;
        wp_ += (bytes + 255) & ~(size_t)255;
        return p;
    };
    unsigned short* qT   = (unsigned short*)alloc(2L * 4096 * 64 * 2);
    unsigned short* kT   = (unsigned short*)alloc(2L * 4096 * 64 * 2);
    unsigned short* qgT  = (unsigned short*)alloc(2L * 4096 * 64 * 2);
    unsigned short* kgT  = (unsigned short*)alloc(2L * 4096 * 64 * 2);
    unsigned short* vC   = (unsigned short*)alloc(2L * 64 * 4096 * 2);
    float* part  = (float*)alloc(4L * 64 * 4096 * 4);
    float* pam   = (float*)alloc(2L * 64 * 4096 * 4);
    float* tbuf  = (float*)alloc(2L * 64 * 4096 * 4);
    float* pam2  = (float*)alloc(2L * 64 * 4096 * 4);
    float* cam   = (float*)alloc(2L * 64 * 4096 * 4);
    float* gramx = (float*)alloc(2L * 64 * 64 * 4);
    float* gramg = (float*)alloc(2L * 64 * 64 * 4);
    float* gy    = (float*)alloc(2L * 64 * 4);
    float* gy2   = (float*)alloc(2L * 64 * 4);
    float* gattc = (float*)alloc(2L * 64 * 64 * 4);
    float* pmx   = (float*)alloc(32L * 4096 * 4);
    float* psum  = (float*)alloc(32L * 4096 * 4);
    float* gM    = (float*)alloc(4096L * 4);
    float* gInv  = (float*)alloc(4096L * 4);
    unsigned short* pbuf   = (unsigned short*)alloc(4096L * 4096 * 2);  // scores / P / gatt
    unsigned short* attS   = (unsigned short*)alloc(4096L * 4096 * 2);  // att_g scores (transposed)
    unsigned char*  attF8  = (unsigned char*)alloc(4096L * 4096);      // softmax(att) fp8 x256
    unsigned char*  attgF8 = (unsigned char*)alloc(4096L * 4096);      // colsoftmax(att_g)^T fp8 x256
    float* cam2 = tbuf;   // tbuf free after cconv1; reuse for cam2

    // ---- projections (fp32 -> bf16 operands) ----
    proj_nc<<<dim3(64, 2), 256, 0, stream>>>(X, IN(2),  IN(3),  qT);
    proj_nc<<<dim3(64, 2), 256, 0, stream>>>(X, IN(4),  IN(5),  kT);
    proj_nc<<<dim3(64, 2), 256, 0, stream>>>(G, IN(8),  IN(9),  qgT);
    proj_nc<<<dim3(64, 2), 256, 0, stream>>>(G, IN(10), IN(11), kgT);
    proj_cn<<<dim3(64, 2), 256, 0, stream>>>(X, IN(6),  IN(7),  vC);

    // ---- guided position attention, per batch (reuse big buffers) ----
    for (int b = 0; b < 2; b++) {
        const unsigned short* qTb  = qT  + (long)b * 4096 * 64;
        const unsigned short* kTb  = kT  + (long)b * 4096 * 64;
        const unsigned short* qgTb = qgT + (long)b * 4096 * 64;
        const unsigned short* kgTb = kgT + (long)b * 4096 * 64;
        // scores: S[n][m] -> pbuf ; Sg^T[m][k] -> attS   (bf16)
        gemm_nt<<<dim3(32, 32, 1), 256, 0, stream>>>(qTb,  kTb,  pbuf, 4096, 4096, 64, 1);
        gemm_nt<<<dim3(32, 32, 1), 256, 0, stream>>>(kgTb, qgTb, attS, 4096, 4096, 64, 1);
        // softmaxes -> fp8 x256
        row_softmax_f8<<<4096, 256, 0, stream>>>(pbuf, attF8);
        colsm_partial<<<dim3(8, 32), 256, 0, stream>>>(attS, pmx, psum);
        colsm_combine<<<16, 256, 0, stream>>>(pmx, psum, gM, gInv);
        colsm_norm_f8<<<dim3(8, 32), 256, 0, stream>>>(attS, attgF8, gM, gInv);
        // P = att @ att_g  (fp8 x fp8, descaled) -> pbuf bf16, then row softmax
        gemm_p8<<<dim3(32, 32), 256, 0, stream>>>(attF8, attgF8, pbuf, 4096, 4096);
        row_softmax<<<4096, 256, 0, stream>>>(pbuf);
        // pam_o = v @ gatt^T (split-K=4)
        gemm_nt<<<dim3(32, 1, 4), 256, 0, stream>>>(vC + (long)b * 64 * 4096, pbuf, part,
                                                    64, 4096, 4096, 3);
        combine_pam<<<1024, 256, 0, stream>>>(part, X + (long)b * 64 * 4096, IN(12),
                                              pam + (long)b * 64 * 4096);
    }

    // ---- pconv head ----
    conv3x3_bn<<<dim3(64, 2, 4), 256, 0, stream>>>(pam, IN(16), IN(17), IN(18), IN(19), IN(20), IN(21), IN(22), tbuf);
    conv1x1_bn<<<dim3(64, 2), 256, 0, stream>>>(tbuf, IN(23), IN(24), IN(25), IN(26), IN(27), IN(28), IN(29), pam2);

    // ---- guided channel attention ----
    diag_fill<<<32, 256, 0, stream>>>(gramx, 8192, 0.0f);
    diag_fill<<<32, 256, 0, stream>>>(gramg, 8192, 0.0f);
    gram_partial<<<dim3(64, 2), 256, 0, stream>>>(pam2, gramx);
    gram_partial<<<dim3(64, 2), 256, 0, stream>>>(G,    gramg);
    se_mean<<<dim3(64, 2), 256, 0, stream>>>(G, gy);
    se_gate<<<2, 64, 0, stream>>>(gy, IN(13), IN(14), gy2);
    cam_small<<<2, 64, 0, stream>>>(gramx, gramg, gy2, gattc);
    cam_apply<<<dim3(64, 2), 256, 0, stream>>>(pam2, gattc, IN(15), cam);

    // ---- cconv + fconv heads ----
    conv3x3_bn<<<dim3(64, 2, 4), 256, 0, stream>>>(cam, IN(30), IN(31), IN(32), IN(33), IN(34), IN(35), IN(36), pam);
    conv1x1_bn<<<dim3(64, 2), 256, 0, stream>>>(pam, IN(37), IN(38), IN(39), IN(40), IN(41), IN(42), IN(43), cam2);
    conv1x1_bn<<<dim3(64, 2), 256, 0, stream>>>(cam2, IN(44), IN(45), IN(46), IN(47), IN(48), IN(49), IN(50), (float*)d_out);
}

// Round 11
// 875.445 us; speedup vs baseline: 3.5153x; 1.0068x over previous
//
#include <hip/hip_runtime.h>
#include <hip/hip_fp8.h>

// ---------------------------------------------------------------------------
// DGNLB fused pipeline.  ALL inputs/outputs are FP32 (reference is jnp.float32).
// B=2, C=64, H=W=64, N=4096.
// R11: gemm_score (K=64, barrier-free, direct-global fragments) replaces the
//      LDS-staged score GEMMs; pam_o split-K 4->8 (256 blocks); gram fills
//      merged.  gemm_p8 / gemm_nt unchanged from R10 winner.
// ---------------------------------------------------------------------------

typedef float f32x4 __attribute__((ext_vector_type(4)));
typedef __bf16 bf16x8 __attribute__((ext_vector_type(8)));
typedef int int4v __attribute__((ext_vector_type(4)));
typedef unsigned short ushort8 __attribute__((ext_vector_type(8)));
typedef unsigned char uchar8 __attribute__((ext_vector_type(8)));

#define DI __device__ __forceinline__

DI float bf2f(unsigned short u) { union { unsigned int i; float f; } x; x.i = ((unsigned int)u) << 16; return x.f; }
DI unsigned short f2bf(float f) { union { float f; unsigned int i; } x; x.f = f; unsigned int r = x.i + 0x7fff + ((x.i >> 16) & 1); return (unsigned short)(r >> 16); }
DI unsigned char f2fp8(float f) { __hip_fp8_e4m3 h(f); return (unsigned char)h.__x; }
DI float sane(float x) { return (x > -1e8f) ? ((x < 1e8f) ? x : 1e8f) : -1e8f; }

// async global->LDS, 16B per lane. LDS dest must be wave-uniform base + lane*16.
DI void async16(const unsigned short* g, unsigned short* l) {
    __builtin_amdgcn_global_load_lds(
        (const __attribute__((address_space(1))) void*)g,
        (__attribute__((address_space(3))) void*)l, 16, 0, 0);
}
DI void async16b(const unsigned char* g, unsigned char* l) {
    __builtin_amdgcn_global_load_lds(
        (const __attribute__((address_space(1))) void*)g,
        (__attribute__((address_space(3))) void*)l, 16, 0, 0);
}

__global__ __launch_bounds__(256) void diag_fill(float* __restrict__ out, int n, float val)
{
    int i = blockIdx.x * 256 + threadIdx.x;
    if (i < n) out[i] = val;
}

// ---------------------------------------------------------------------------
// Score GEMM (K=64 only): C[4096][4096](bf16) = A[4096][64] * B[4096][64]^T.
// No LDS, no barriers: fragments loaded directly from global (operands are
// 0.5MB, L2-resident).  128x128 tile, 4 waves 2x2, 32 MFMAs.
// ---------------------------------------------------------------------------
__global__ __launch_bounds__(256) void gemm_score(
    const unsigned short* __restrict__ A,
    const unsigned short* __restrict__ B,
    unsigned short* __restrict__ C, int N)
{
    const int tid  = threadIdx.x;
    const int bm   = blockIdx.y, bn = blockIdx.x;
    const int lane = tid & 63, wid = tid >> 6;
    const int wm   = (wid >> 1) * 64, wn = (wid & 1) * 64;
    const int l16  = lane & 15, quad = lane >> 4;

    f32x4 acc[4][4] = {};
    bf16x8 af[2][4], bfr[2][4];
    #pragma unroll
    for (int w = 0; w < 2; w++) {
        #pragma unroll
        for (int i = 0; i < 4; i++)
            af[w][i]  = *(const bf16x8*)&A[(long)(bm * 128 + wm + i * 16 + l16) * 64 + w * 32 + quad * 8];
        #pragma unroll
        for (int j = 0; j < 4; j++)
            bfr[w][j] = *(const bf16x8*)&B[(long)(bn * 128 + wn + j * 16 + l16) * 64 + w * 32 + quad * 8];
    }
    #pragma unroll
    for (int w = 0; w < 2; w++)
        #pragma unroll
        for (int i = 0; i < 4; i++)
            #pragma unroll
            for (int j = 0; j < 4; j++)
                acc[i][j] = __builtin_amdgcn_mfma_f32_16x16x32_bf16(af[w][i], bfr[w][j], acc[i][j], 0, 0, 0);

    #pragma unroll
    for (int i = 0; i < 4; i++) {
        int rb = bm * 128 + wm + i * 16 + quad * 4;   // C/D: col=lane&15, row=quad*4+reg
        #pragma unroll
        for (int j = 0; j < 4; j++) {
            int col = bn * 128 + wn + j * 16 + l16;
            #pragma unroll
            for (int r = 0; r < 4; r++)
                C[(long)(rb + r) * N + col] = f2bf(acc[i][j][r]);
        }
    }
}

// ---------------------------------------------------------------------------
// NT GEMM bf16 (pam_o): C = A[M][K]*B[N][K]^T, split-K partials fp32 (mode 3
// semantics only now).  128x128 tile, BK=32, XOR-swizzled LDS, async staging.
// ---------------------------------------------------------------------------
__global__ __launch_bounds__(256, 3) void gemm_nt(
    const unsigned short* __restrict__ A,
    const unsigned short* __restrict__ B,
    float* __restrict__ C,
    int M, int N, int K)
{
    __shared__ __align__(16) unsigned short As[128 * 32];
    __shared__ __align__(16) unsigned short Bs[128 * 32];
    const int tid  = threadIdx.x;
    const int bm   = blockIdx.y, bn = blockIdx.x;
    const int lane = tid & 63, wid = tid >> 6;
    const int wm   = (wid >> 1) * 64, wn = (wid & 1) * 64;
    const int l16  = lane & 15, quad = lane >> 4;

    f32x4 acc[4][4] = {};

    const int Kc   = K / (int)gridDim.z;
    const int kbeg = (int)blockIdx.z * Kc;
    const int nIter = Kc / 32;

    const int row0 = tid >> 2,        cp0 = tid & 3;
    const int row1 = (tid + 256) >> 2, cp1 = (tid + 256) & 3;
    int ar0 = bm * 128 + row0; if (ar0 > M - 1) ar0 = M - 1;
    int ar1 = bm * 128 + row1; if (ar1 > M - 1) ar1 = M - 1;
    const unsigned short* pa0 = &A[(long)ar0 * K + kbeg + ((cp0 ^ (row0 & 3)) * 8)];
    const unsigned short* pa1 = &A[(long)ar1 * K + kbeg + ((cp1 ^ (row1 & 3)) * 8)];
    const unsigned short* pb0 = &B[(long)(bn * 128 + row0) * K + kbeg + ((cp0 ^ (row0 & 3)) * 8)];
    const unsigned short* pb1 = &B[(long)(bn * 128 + row1) * K + kbeg + ((cp1 ^ (row1 & 3)) * 8)];
    unsigned short* la0 = &As[row0 * 32 + cp0 * 8];
    unsigned short* la1 = &As[row1 * 32 + cp1 * 8];
    unsigned short* lb0 = &Bs[row0 * 32 + cp0 * 8];
    unsigned short* lb1 = &Bs[row1 * 32 + cp1 * 8];

    const int sw = (quad ^ (l16 & 3)) * 8;

    for (int it = 0; it < nIter; it++) {
        __syncthreads();
        async16(pa0, la0);
        async16(pa1, la1);
        async16(pb0, lb0);
        async16(pb1, lb1);
        pa0 += 32; pa1 += 32; pb0 += 32; pb1 += 32;
        __syncthreads();
        bf16x8 af[4], bfr[4];
        #pragma unroll
        for (int i = 0; i < 4; i++) af[i]  = *(const bf16x8*)&As[(wm + i * 16 + l16) * 32 + sw];
        #pragma unroll
        for (int j = 0; j < 4; j++) bfr[j] = *(const bf16x8*)&Bs[(wn + j * 16 + l16) * 32 + sw];
        #pragma unroll
        for (int i = 0; i < 4; i++)
            #pragma unroll
            for (int j = 0; j < 4; j++)
                acc[i][j] = __builtin_amdgcn_mfma_f32_16x16x32_bf16(af[i], bfr[j], acc[i][j], 0, 0, 0);
    }

    #pragma unroll
    for (int i = 0; i < 4; i++) {
        int rb = bm * 128 + wm + i * 16 + quad * 4;
        #pragma unroll
        for (int j = 0; j < 4; j++) {
            int col = bn * 128 + wn + j * 16 + l16;
            #pragma unroll
            for (int r = 0; r < 4; r++) {
                int row = rb + r;
                if (row < M)
                    C[(long)blockIdx.z * M * N + (long)row * N + col] = acc[i][j][r];
            }
        }
    }
}

// ---------------------------------------------------------------------------
// fp8 NT GEMM: C[4096][4096](bf16) = (A8/256)*(B8/256)^T.  BK=64, 64 iters.
// ---------------------------------------------------------------------------
__global__ __launch_bounds__(256, 3) void gemm_p8(
    const unsigned char* __restrict__ A,
    const unsigned char* __restrict__ B,
    unsigned short* __restrict__ C, int N, int K)
{
    __shared__ __align__(16) unsigned char As[128 * 64];
    __shared__ __align__(16) unsigned char Bs[128 * 64];
    const int tid  = threadIdx.x;
    const int bm   = blockIdx.y, bn = blockIdx.x;
    const int lane = tid & 63, wid = tid >> 6;
    const int wm   = (wid >> 1) * 64, wn = (wid & 1) * 64;
    const int l16  = lane & 15, quad = lane >> 4;

    f32x4 acc[4][4] = {};

    const int row0 = tid >> 2,        cp0 = tid & 3;
    const int row1 = (tid + 256) >> 2, cp1 = (tid + 256) & 3;
    const unsigned char* pa0 = &A[(long)(bm * 128 + row0) * K + ((cp0 ^ (row0 & 3)) * 16)];
    const unsigned char* pa1 = &A[(long)(bm * 128 + row1) * K + ((cp1 ^ (row1 & 3)) * 16)];
    const unsigned char* pb0 = &B[(long)(bn * 128 + row0) * K + ((cp0 ^ (row0 & 3)) * 16)];
    const unsigned char* pb1 = &B[(long)(bn * 128 + row1) * K + ((cp1 ^ (row1 & 3)) * 16)];
    unsigned char* la0 = &As[row0 * 64 + cp0 * 16];
    unsigned char* la1 = &As[row1 * 64 + cp1 * 16];
    unsigned char* lb0 = &Bs[row0 * 64 + cp0 * 16];
    unsigned char* lb1 = &Bs[row1 * 64 + cp1 * 16];

    const int off8 = (quad & 1) * 8;
    const int qh   = quad >> 1;
    const int xr   = l16 & 3;

    const int nIter = K / 64;
    for (int it = 0; it < nIter; it++) {
        __syncthreads();
        async16b(pa0, la0);
        async16b(pa1, la1);
        async16b(pb0, lb0);
        async16b(pb1, lb1);
        pa0 += 64; pa1 += 64; pb0 += 64; pb1 += 64;
        __syncthreads();
        #pragma unroll
        for (int h = 0; h < 2; h++) {
            const int ch = ((2 * h + qh) ^ xr) * 16 + off8;
            long af[4], bfr[4];
            #pragma unroll
            for (int i = 0; i < 4; i++) af[i]  = *(const long*)&As[(wm + i * 16 + l16) * 64 + ch];
            #pragma unroll
            for (int j = 0; j < 4; j++) bfr[j] = *(const long*)&Bs[(wn + j * 16 + l16) * 64 + ch];
            #pragma unroll
            for (int i = 0; i < 4; i++)
                #pragma unroll
                for (int j = 0; j < 4; j++)
                    acc[i][j] = __builtin_amdgcn_mfma_f32_16x16x32_fp8_fp8(af[i], bfr[j], acc[i][j], 0, 0, 0);
        }
    }

    const float ds = 1.f / 65536.f;
    #pragma unroll
    for (int i = 0; i < 4; i++) {
        int rb = bm * 128 + wm + i * 16 + quad * 4;
        #pragma unroll
        for (int j = 0; j < 4; j++) {
            int col = bn * 128 + wn + j * 16 + l16;
            #pragma unroll
            for (int r = 0; r < 4; r++)
                C[(long)(rb + r) * N + col] = f2bf(acc[i][j][r] * ds);
        }
    }
}

// ---------------------------------------------------------------------------
// Row softmax bf16 in-place (for P before pam_o).
// ---------------------------------------------------------------------------
__global__ __launch_bounds__(256) void row_softmax(unsigned short* __restrict__ buf)
{
    long row = blockIdx.x;
    unsigned short* p = buf + row * 4096L;
    const int tid = threadIdx.x, lane = tid & 63, wid = tid >> 6;
    float v[16]; float mx = -1e30f;
    #pragma unroll
    for (int t = 0; t < 16; t++) {
        float x = sane(bf2f(p[t * 256 + tid]));
        v[t] = x; mx = fmaxf(mx, x);
    }
    #pragma unroll
    for (int o = 32; o; o >>= 1) mx = fmaxf(mx, __shfl_xor(mx, o, 64));
    __shared__ float rmax[4], rsum[4];
    if (!lane) rmax[wid] = mx;
    __syncthreads();
    mx = fmaxf(fmaxf(rmax[0], rmax[1]), fmaxf(rmax[2], rmax[3]));
    float s = 0.f;
    #pragma unroll
    for (int t = 0; t < 16; t++) { v[t] = __expf(v[t] - mx); s += v[t]; }
    #pragma unroll
    for (int o = 32; o; o >>= 1) s += __shfl_xor(s, o, 64);
    if (!lane) rsum[wid] = s;
    __syncthreads();
    s = rsum[0] + rsum[1] + rsum[2] + rsum[3];
    float inv = 1.f / s;
    #pragma unroll
    for (int t = 0; t < 16; t++) p[t * 256 + tid] = f2bf(v[t] * inv);
}

// ---------------------------------------------------------------------------
// Row softmax bf16 -> fp8 x256 (att path).
// ---------------------------------------------------------------------------
__global__ __launch_bounds__(256) void row_softmax_f8(
    const unsigned short* __restrict__ in, unsigned char* __restrict__ out)
{
    long row = blockIdx.x;
    const unsigned short* p = in + row * 4096L;
    unsigned char* q = out + row * 4096L;
    const int tid = threadIdx.x, lane = tid & 63, wid = tid >> 6;
    float v[16]; float mx = -1e30f;
    #pragma unroll
    for (int t = 0; t < 16; t++) {
        float x = sane(bf2f(p[t * 256 + tid]));
        v[t] = x; mx = fmaxf(mx, x);
    }
    #pragma unroll
    for (int o = 32; o; o >>= 1) mx = fmaxf(mx, __shfl_xor(mx, o, 64));
    __shared__ float rmax[4], rsum[4];
    if (!lane) rmax[wid] = mx;
    __syncthreads();
    mx = fmaxf(fmaxf(rmax[0], rmax[1]), fmaxf(rmax[2], rmax[3]));
    float s = 0.f;
    #pragma unroll
    for (int t = 0; t < 16; t++) { v[t] = __expf(v[t] - mx); s += v[t]; }
    #pragma unroll
    for (int o = 32; o; o >>= 1) s += __shfl_xor(s, o, 64);
    if (!lane) rsum[wid] = s;
    __syncthreads();
    s = rsum[0] + rsum[1] + rsum[2] + rsum[3];
    float inv = 256.f / s;
    #pragma unroll
    for (int t = 0; t < 16; t++) q[t * 256 + tid] = f2fp8(v[t] * inv);
}

// ---------------------------------------------------------------------------
// Column softmax (attS bf16 -> attgF8 fp8 x256), 3 phases.
// ---------------------------------------------------------------------------
__global__ __launch_bounds__(256) void colsm_partial(
    const unsigned short* __restrict__ buf,
    float* __restrict__ pmx, float* __restrict__ psum)
{
    const int tid = threadIdx.x;
    const int colgrp = tid & 63, rg = tid >> 6;
    const int cbase = blockIdx.x * 512 + colgrp * 8;
    const int r0 = blockIdx.y * 128 + rg * 32;
    const unsigned short* p = buf + (long)r0 * 4096 + cbase;
    float mx[8], s[8];
    #pragma unroll
    for (int j = 0; j < 8; j++) { mx[j] = -1e30f; s[j] = 0.f; }
    for (int r = 0; r < 32; r++) {
        ushort8 v = *(const ushort8*)(p + (long)r * 4096);
        #pragma unroll
        for (int j = 0; j < 8; j++) {
            float x = sane(bf2f(v[j]));
            float nm = fmaxf(mx[j], x);
            s[j] = s[j] * __expf(mx[j] - nm) + __expf(x - nm);
            mx[j] = nm;
        }
    }
    __shared__ float smx[4][512], ssm[4][512];
    #pragma unroll
    for (int j = 0; j < 8; j++) { smx[rg][colgrp * 8 + j] = mx[j]; ssm[rg][colgrp * 8 + j] = s[j]; }
    __syncthreads();
    for (int c = tid; c < 512; c += 256) {
        float M = fmaxf(fmaxf(smx[0][c], smx[1][c]), fmaxf(smx[2][c], smx[3][c]));
        float S = 0.f;
        #pragma unroll
        for (int i = 0; i < 4; i++) S += ssm[i][c] * __expf(smx[i][c] - M);
        int col = blockIdx.x * 512 + c;
        pmx[blockIdx.y * 4096 + col] = M;
        psum[blockIdx.y * 4096 + col] = S;
    }
}

__global__ __launch_bounds__(256) void colsm_combine(
    const float* __restrict__ pmx, const float* __restrict__ psum,
    float* __restrict__ gM, float* __restrict__ gInv)
{
    int col = blockIdx.x * 256 + threadIdx.x;   // grid 16
    float M = -1e30f;
    for (int ch = 0; ch < 32; ch++) M = fmaxf(M, pmx[ch * 4096 + col]);
    float S = 0.f;
    for (int ch = 0; ch < 32; ch++) S += psum[ch * 4096 + col] * __expf(pmx[ch * 4096 + col] - M);
    gM[col] = M;
    gInv[col] = 256.f / S;   // fp8 scale folded in
}

__global__ __launch_bounds__(256) void colsm_norm_f8(
    const unsigned short* __restrict__ in, unsigned char* __restrict__ out,
    const float* __restrict__ gM, const float* __restrict__ gInv)
{
    const int tid = threadIdx.x;
    const int colgrp = tid & 63, rg = tid >> 6;
    const int cbase = blockIdx.x * 512 + colgrp * 8;
    const int r0 = blockIdx.y * 128 + rg * 32;
    const unsigned short* p = in + (long)r0 * 4096 + cbase;
    unsigned char* q = out + (long)r0 * 4096 + cbase;
    float M[8], inv[8];
    #pragma unroll
    for (int j = 0; j < 8; j++) { M[j] = gM[cbase + j]; inv[j] = gInv[cbase + j]; }
    for (int r = 0; r < 32; r++) {
        ushort8 v = *(const ushort8*)(p + (long)r * 4096);
        uchar8 o;
        #pragma unroll
        for (int j = 0; j < 8; j++) o[j] = f2fp8(__expf(sane(bf2f(v[j])) - M[j]) * inv[j]);
        *(uchar8*)(q + (long)r * 4096) = o;
    }
}

// ---------------------------------------------------------------------------
// 1x1 conv projections (fp32 -> bf16 operands).
// ---------------------------------------------------------------------------
__global__ __launch_bounds__(256) void proj_nc(
    const float* __restrict__ X, const float* __restrict__ W,
    const float* __restrict__ bias, unsigned short* __restrict__ out)
{
    const int b = blockIdx.y, nt = blockIdx.x, tid = threadIdx.x;
    __shared__ float Xs[64][64];
    __shared__ float Ws[64][65];
    __shared__ float Bb[64];
    for (int f = tid; f < 4096; f += 256) {
        int i = f >> 6, n = f & 63;
        Xs[i][n] = X[((long)b * 64 + i) * 4096 + nt * 64 + n];
        Ws[f & 63][f >> 6] = W[f];
    }
    if (tid < 64) Bb[tid] = bias[tid];
    __syncthreads();
    const int c = tid & 63, g = tid >> 6;
    float acc[16];
    #pragma unroll
    for (int j = 0; j < 16; j++) acc[j] = Bb[c];
    for (int i = 0; i < 64; i++) {
        float wv = Ws[i][c];
        #pragma unroll
        for (int j = 0; j < 16; j++) acc[j] += wv * Xs[i][g + 4 * j];
    }
    unsigned short* ob = out + ((long)b * 4096 + nt * 64) * 64;
    #pragma unroll
    for (int j = 0; j < 16; j++) ob[(g + 4 * j) * 64 + c] = f2bf(acc[j]);
}

__global__ __launch_bounds__(256) void proj_cn(
    const float* __restrict__ X, const float* __restrict__ W,
    const float* __restrict__ bias, unsigned short* __restrict__ out)
{
    const int b = blockIdx.y, nt = blockIdx.x, tid = threadIdx.x;
    __shared__ float Xs[64][64];
    __shared__ float Ws[64][64];
    __shared__ float Bb[64];
    for (int f = tid; f < 4096; f += 256) {
        int i = f >> 6, n = f & 63;
        Xs[i][n] = X[((long)b * 64 + i) * 4096 + nt * 64 + n];
        Ws[f >> 6][f & 63] = W[f];
    }
    if (tid < 64) Bb[tid] = bias[tid];
    __syncthreads();
    const int n = tid & 63, g = tid >> 6;
    float acc[16];
    #pragma unroll
    for (int j = 0; j < 16; j++) acc[j] = Bb[g + 4 * j];
    for (int i = 0; i < 64; i++) {
        float xv = Xs[i][n];
        #pragma unroll
        for (int j = 0; j < 16; j++) acc[j] += Ws[g + 4 * j][i] * xv;
    }
    unsigned short* ob = out + ((long)b * 64) * 4096 + nt * 64;
    #pragma unroll
    for (int j = 0; j < 16; j++) ob[(long)(g + 4 * j) * 4096 + n] = f2bf(acc[j]);
}

// ---------------------------------------------------------------------------
// combine split-K partials: pam = gamma*(sum_k part_k) + x.
// ---------------------------------------------------------------------------
__global__ __launch_bounds__(256) void combine_pam(
    const float* __restrict__ part, const float* __restrict__ x,
    const float* __restrict__ gammaPtr, float* __restrict__ pam, int nsplit)
{
    int i = blockIdx.x * 256 + threadIdx.x;
    float s = 0.f;
    for (int k = 0; k < nsplit; k++) s += part[(long)k * 262144 + i];
    pam[i] = gammaPtr[0] * s + x[i];
}

// ---------------------------------------------------------------------------
// 3x3 conv (SAME) + BN + PReLU, fp32.  Grid (64 h, B, 4 co-groups of 16).
// ---------------------------------------------------------------------------
__global__ __launch_bounds__(256) void conv3x3_bn(
    const float* __restrict__ X, const float* __restrict__ W9,
    const float* __restrict__ bias,
    const float* __restrict__ bns, const float* __restrict__ bnb,
    const float* __restrict__ bnm, const float* __restrict__ bnv,
    const float* __restrict__ prelu, float* __restrict__ out)
{
    const int b = blockIdx.y, h = blockIdx.x, co0 = blockIdx.z * 16, tid = threadIdx.x;
    __shared__ float Ls[3][64][66];
    __shared__ float ep0[64], ep1[64], ep2[64];
    __shared__ float alpha;
    for (int f = tid; f < 3 * 64 * 64; f += 256) {
        int ky = f >> 12, rem = f & 4095, ci = rem >> 6, w = rem & 63;
        int hh = h + ky - 1;
        Ls[ky][ci][w + 1] = (hh >= 0 && hh < 64) ? X[(((long)b * 64 + ci) * 64 + hh) * 64 + w] : 0.f;
    }
    for (int f = tid; f < 192; f += 256) {
        int ky = f >> 6, ci = f & 63;
        Ls[ky][ci][0] = 0.f; Ls[ky][ci][65] = 0.f;
    }
    if (tid < 64) {
        float inv = bns[tid] * rsqrtf(fmaxf(bnv[tid], 0.f) + 1e-5f);
        ep0[tid] = inv; ep1[tid] = bnb[tid] - bnm[tid] * inv; ep2[tid] = bias[tid];
    }
    if (tid == 0) alpha = prelu[0];
    __syncthreads();
    const int w = tid & 63, g = tid >> 6;   // co = co0 + g*4 + j
    float acc[4];
    #pragma unroll
    for (int j = 0; j < 4; j++) acc[j] = ep2[co0 + g * 4 + j];
    for (int ci = 0; ci < 64; ci++) {
        float v0 = Ls[0][ci][w], v1 = Ls[0][ci][w + 1], v2 = Ls[0][ci][w + 2];
        float v3 = Ls[1][ci][w], v4 = Ls[1][ci][w + 1], v5 = Ls[1][ci][w + 2];
        float v6 = Ls[2][ci][w], v7 = Ls[2][ci][w + 1], v8 = Ls[2][ci][w + 2];
        #pragma unroll
        for (int j = 0; j < 4; j++) {
            const float* wp = &W9[((co0 + g * 4 + j) * 64 + ci) * 9];
            acc[j] += wp[0] * v0 + wp[1] * v1 + wp[2] * v2
                    + wp[3] * v3 + wp[4] * v4 + wp[5] * v5
                    + wp[6] * v6 + wp[7] * v7 + wp[8] * v8;
        }
    }
    #pragma unroll
    for (int j = 0; j < 4; j++) {
        int co = co0 + g * 4 + j;
        float y = acc[j] * ep0[co] + ep1[co];
        y = y > 0.f ? y : alpha * y;
        out[(((long)b * 64 + co) * 64 + h) * 64 + w] = y;
    }
}

// ---------------------------------------------------------------------------
// 1x1 conv + BN + PReLU, fp32.
// ---------------------------------------------------------------------------
__global__ __launch_bounds__(256) void conv1x1_bn(
    const float* __restrict__ X, const float* __restrict__ W,
    const float* __restrict__ bias,
    const float* __restrict__ bns, const float* __restrict__ bnb,
    const float* __restrict__ bnm, const float* __restrict__ bnv,
    const float* __restrict__ prelu, float* __restrict__ out)
{
    const int b = blockIdx.y, nt = blockIdx.x, tid = threadIdx.x;
    __shared__ float Xs[64][64];
    __shared__ float Ws[64][64];
    __shared__ float ep0[64], ep1[64], ep2[64];
    __shared__ float alpha;
    for (int f = tid; f < 4096; f += 256) {
        int i = f >> 6, n = f & 63;
        Xs[i][n] = X[((long)b * 64 + i) * 4096 + nt * 64 + n];
        Ws[f >> 6][f & 63] = W[f];
    }
    if (tid < 64) {
        float inv = bns[tid] * rsqrtf(fmaxf(bnv[tid], 0.f) + 1e-5f);
        ep0[tid] = inv; ep1[tid] = bnb[tid] - bnm[tid] * inv; ep2[tid] = bias[tid];
    }
    if (tid == 0) alpha = prelu[0];
    __syncthreads();
    const int n = tid & 63, g = tid >> 6;
    float acc[16];
    #pragma unroll
    for (int j = 0; j < 16; j++) acc[j] = ep2[g + 4 * j];
    for (int i = 0; i < 64; i++) {
        float xv = Xs[i][n];
        #pragma unroll
        for (int j = 0; j < 16; j++) acc[j] += Ws[g + 4 * j][i] * xv;
    }
    #pragma unroll
    for (int j = 0; j < 16; j++) {
        int c = g + 4 * j;
        float y = acc[j] * ep0[c] + ep1[c];
        y = y > 0.f ? y : alpha * y;
        out[((long)b * 64 + c) * 4096 + nt * 64 + n] = y;
    }
}

// ---------------------------------------------------------------------------
// Split-K Gram: grid (64 kchunks, B). atomicAdd combine; out pre-zeroed.
// ---------------------------------------------------------------------------
__global__ __launch_bounds__(256) void gram_partial(
    const float* __restrict__ X, float* __restrict__ out)
{
    const int ch = blockIdx.x, b = blockIdx.y, tid = threadIdx.x;
    __shared__ float Xs[64][65];
    for (int f = tid; f < 4096; f += 256) {
        int ci = f >> 6, kk = f & 63;
        Xs[ci][kk] = X[((long)b * 64 + ci) * 4096 + ch * 64 + kk];
    }
    __syncthreads();
    const int d = tid & 63, g = tid >> 6;
    float acc[16] = {};
    for (int kk = 0; kk < 64; kk++) {
        float xd = Xs[d][kk];
        #pragma unroll
        for (int j = 0; j < 16; j++) acc[j] += Xs[g + 4 * j][kk] * xd;
    }
    #pragma unroll
    for (int j = 0; j < 16; j++)
        atomicAdd(&out[((long)b * 64 + (g + 4 * j)) * 64 + d], acc[j]);
}

// ---------------------------------------------------------------------------
// SE mean + gate.
// ---------------------------------------------------------------------------
__global__ __launch_bounds__(256) void se_mean(
    const float* __restrict__ G, float* __restrict__ gy)
{
    const int c = blockIdx.x, b = blockIdx.y, tid = threadIdx.x;
    const int lane = tid & 63, wid = tid >> 6;
    const float* p = G + ((long)b * 64 + c) * 4096;
    float s = 0.f;
    #pragma unroll
    for (int t = 0; t < 4; t++) {
        f32x4 v = *(const f32x4*)(p + (t * 256 + tid) * 4);
        s += v[0] + v[1] + v[2] + v[3];
    }
    #pragma unroll
    for (int o = 32; o; o >>= 1) s += __shfl_xor(s, o, 64);
    __shared__ float ws[4];
    if (!lane) ws[wid] = s;
    __syncthreads();
    if (tid == 0) gy[b * 64 + c] = (ws[0] + ws[1] + ws[2] + ws[3]) * (1.f / 4096.f);
}

__global__ __launch_bounds__(64) void se_gate(
    const float* __restrict__ gy_in, const float* __restrict__ fc1,
    const float* __restrict__ fc2, float* __restrict__ gy2)
{
    const int b = blockIdx.x, tid = threadIdx.x;
    __shared__ float gy[64], r1[32];
    gy[tid] = gy_in[b * 64 + tid];
    __syncthreads();
    if (tid < 32) {
        float s = 0.f;
        for (int c = 0; c < 64; c++) s += fc1[tid * 64 + c] * gy[c];
        r1[tid] = fmaxf(s, 0.f);
    }
    __syncthreads();
    float s = 0.f;
    for (int r = 0; r < 32; r++) s += fc2[tid * 32 + r] * r1[r];
    gy2[b * 64 + tid] = 1.f / (1.f + __expf(-sane(s)));
}

// ---------------------------------------------------------------------------
// CAM small algebra (64x64 per batch).
// ---------------------------------------------------------------------------
__global__ __launch_bounds__(64) void cam_small(
    const float* __restrict__ gramx, const float* __restrict__ gramg,
    const float* __restrict__ gy2, float* __restrict__ gattc)
{
    const int b = blockIdx.x, tid = threadIdx.x;
    __shared__ float Ac[64][65], Acg[64][65];
    __shared__ float gys[64];
    gys[tid] = gy2[b * 64 + tid];
    __syncthreads();
    {
        const float* r = gramx + ((long)b * 64 + tid) * 64;
        float mx = -1e30f;
        for (int d = 0; d < 64; d++) mx = fmaxf(mx, sane(r[d]));
        float s = 0.f;
        for (int d = 0; d < 64; d++) s += __expf(sane(r[d]) - mx);
        float inv = 1.f / s;
        for (int d = 0; d < 64; d++) Ac[tid][d] = __expf(sane(r[d]) - mx) * inv;
    }
    {
        const float* r = gramg + ((long)b * 64 + tid) * 64;
        float gc = gys[tid];
        float mx = -1e30f;
        for (int d = 0; d < 64; d++) mx = fmaxf(mx, sane(gc * gys[d] * r[d]));
        float s = 0.f;
        for (int d = 0; d < 64; d++) s += __expf(sane(gc * gys[d] * r[d]) - mx);
        float inv = 1.f / s;
        for (int d = 0; d < 64; d++) Acg[tid][d] = __expf(sane(gc * gys[d] * r[d]) - mx) * inv;
    }
    __syncthreads();
    float ge[64];
    float mx1 = -1e30f, mn = 1e30f;
    for (int d = 0; d < 64; d++) {
        float s = 0.f;
        for (int k = 0; k < 64; k++) s += Ac[tid][k] * Acg[k][d];
        ge[d] = s;
        mx1 = fmaxf(mx1, s); mn = fminf(mn, s);
    }
    float M2 = mx1 - mn;
    float s = 0.f;
    for (int d = 0; d < 64; d++) s += __expf((mx1 - ge[d]) - M2);
    float inv = 1.f / s;
    for (int d = 0; d < 64; d++)
        gattc[((long)b * 64 + tid) * 64 + d] = __expf((mx1 - ge[d]) - M2) * inv;
}

// ---------------------------------------------------------------------------
// cam = gamma_c * (gatt_c @ pam2) + pam2   (fp32)
// ---------------------------------------------------------------------------
__global__ __launch_bounds__(256) void cam_apply(
    const float* __restrict__ pam2, const float* __restrict__ gattc,
    const float* __restrict__ gammaPtr, float* __restrict__ cam)
{
    const int b = blockIdx.y, nt = blockIdx.x, tid = threadIdx.x;
    __shared__ float Xs[64][64];
    __shared__ float Gt[64][64];
    for (int f = tid; f < 4096; f += 256) {
        int d = f >> 6, n = f & 63;
        Xs[d][n] = pam2[((long)b * 64 + d) * 4096 + nt * 64 + n];
        Gt[f >> 6][f & 63] = gattc[((long)b * 64 + (f >> 6)) * 64 + (f & 63)];
    }
    __syncthreads();
    const float gamma = gammaPtr[0];
    const int n = tid & 63, g = tid >> 6;
    float acc[16] = {};
    for (int d = 0; d < 64; d++) {
        float xv = Xs[d][n];
        #pragma unroll
        for (int j = 0; j < 16; j++) acc[j] += Gt[g + 4 * j][d] * xv;
    }
    #pragma unroll
    for (int j = 0; j < 16; j++) {
        int c = g + 4 * j;
        cam[((long)b * 64 + c) * 4096 + nt * 64 + n] = gamma * acc[j] + Xs[c][n];
    }
}

// ---------------------------------------------------------------------------
// host
// ---------------------------------------------------------------------------
extern "C" void kernel_launch(void* const* d_in, const int* in_sizes, int n_in,
                              void* d_out, int out_size, void* d_ws, size_t ws_size,
                              hipStream_t stream)
{
    static const int exp_sizes[51] = {
        524288, 524288,
        4096, 64, 4096, 64, 4096, 64, 4096, 64, 4096, 64,
        1, 2048, 2048, 1,
        36864, 64, 64, 64, 64, 64, 1,
        4096, 64, 64, 64, 64, 64, 1,
        36864, 64, 64, 64, 64, 64, 1,
        4096, 64, 64, 64, 64, 64, 1,
        4096, 64, 64, 64, 64, 64, 1
    };
    bool map_ok = (n_in == 51) && (out_size == 524288);
    if (map_ok) for (int i = 0; i < 51; i++) if (in_sizes[i] != exp_sizes[i]) { map_ok = false; break; }

    const int diag_grid = (out_size + 255) / 256;
    if (!map_ok) {
        diag_fill<<<diag_grid, 256, 0, stream>>>((float*)d_out, out_size, 400.0f);
        return;
    }
    const size_t NEED_FULL = 121000000;   // layout ~118MB with 8-way part
    if (ws_size < NEED_FULL) {
        float code = (ws_size >= 88000000) ? 100.0f : (ws_size >= 55000000 ? 200.0f : 300.0f);
        diag_fill<<<diag_grid, 256, 0, stream>>>((float*)d_out, out_size, code);
        return;
    }

    auto IN = [&](int i) { return (const float*)d_in[i]; };
    const float* X = IN(0);
    const float* G = IN(1);

    char* wp_ = (char*)d_ws;
    auto alloc = [&](size_t bytes) -> void* {
        void* p = (void*)wp_;
        wp_ += (bytes + 255) & ~(size_t)255;
        return p;
    };
    unsigned short* qT   = (unsigned short*)alloc(2L * 4096 * 64 * 2);
    unsigned short* kT   = (unsigned short*)alloc(2L * 4096 * 64 * 2);
    unsigned short* qgT  = (unsigned short*)alloc(2L * 4096 * 64 * 2);
    unsigned short* kgT  = (unsigned short*)alloc(2L * 4096 * 64 * 2);
    unsigned short* vC   = (unsigned short*)alloc(2L * 64 * 4096 * 2);
    float* part  = (float*)alloc(8L * 64 * 4096 * 4);     // split-K 8 partials
    float* pam   = (float*)alloc(2L * 64 * 4096 * 4);
    float* tbuf  = (float*)alloc(2L * 64 * 4096 * 4);
    float* pam2  = (float*)alloc(2L * 64 * 4096 * 4);
    float* cam   = (float*)alloc(2L * 64 * 4096 * 4);
    float* gramx = (float*)alloc(2L * 64 * 64 * 4);
    float* gramg = (float*)alloc(2L * 64 * 64 * 4);       // contiguous with gramx
    float* gy    = (float*)alloc(2L * 64 * 4);
    float* gy2   = (float*)alloc(2L * 64 * 4);
    float* gattc = (float*)alloc(2L * 64 * 64 * 4);
    float* pmx   = (float*)alloc(32L * 4096 * 4);
    float* psum  = (float*)alloc(32L * 4096 * 4);
    float* gM    = (float*)alloc(4096L * 4);
    float* gInv  = (float*)alloc(4096L * 4);
    unsigned short* pbuf   = (unsigned short*)alloc(4096L * 4096 * 2);  // scores / P / gatt
    unsigned short* attS   = (unsigned short*)alloc(4096L * 4096 * 2);  // att_g scores (transposed)
    unsigned char*  attF8  = (unsigned char*)alloc(4096L * 4096);      // softmax(att) fp8 x256
    unsigned char*  attgF8 = (unsigned char*)alloc(4096L * 4096);      // colsoftmax(att_g)^T fp8 x256
    float* cam2 = tbuf;   // tbuf free after cconv1; reuse for cam2

    // ---- projections (fp32 -> bf16 operands) ----
    proj_nc<<<dim3(64, 2), 256, 0, stream>>>(X, IN(2),  IN(3),  qT);
    proj_nc<<<dim3(64, 2), 256, 0, stream>>>(X, IN(4),  IN(5),  kT);
    proj_nc<<<dim3(64, 2), 256, 0, stream>>>(G, IN(8),  IN(9),  qgT);
    proj_nc<<<dim3(64, 2), 256, 0, stream>>>(G, IN(10), IN(11), kgT);
    proj_cn<<<dim3(64, 2), 256, 0, stream>>>(X, IN(6),  IN(7),  vC);

    // ---- guided position attention, per batch (reuse big buffers) ----
    for (int b = 0; b < 2; b++) {
        const unsigned short* qTb  = qT  + (long)b * 4096 * 64;
        const unsigned short* kTb  = kT  + (long)b * 4096 * 64;
        const unsigned short* qgTb = qgT + (long)b * 4096 * 64;
        const unsigned short* kgTb = kgT + (long)b * 4096 * 64;
        // scores: S[n][m] -> pbuf ; Sg^T[m][k] -> attS   (bf16, barrier-free)
        gemm_score<<<dim3(32, 32), 256, 0, stream>>>(qTb,  kTb,  pbuf, 4096);
        gemm_score<<<dim3(32, 32), 256, 0, stream>>>(kgTb, qgTb, attS, 4096);
        // softmaxes -> fp8 x256
        row_softmax_f8<<<4096, 256, 0, stream>>>(pbuf, attF8);
        colsm_partial<<<dim3(8, 32), 256, 0, stream>>>(attS, pmx, psum);
        colsm_combine<<<16, 256, 0, stream>>>(pmx, psum, gM, gInv);
        colsm_norm_f8<<<dim3(8, 32), 256, 0, stream>>>(attS, attgF8, gM, gInv);
        // P = att @ att_g  (fp8 x fp8, descaled) -> pbuf bf16, then row softmax
        gemm_p8<<<dim3(32, 32), 256, 0, stream>>>(attF8, attgF8, pbuf, 4096, 4096);
        row_softmax<<<4096, 256, 0, stream>>>(pbuf);
        // pam_o = v @ gatt^T (split-K=8, 256 blocks)
        gemm_nt<<<dim3(32, 1, 8), 256, 0, stream>>>(vC + (long)b * 64 * 4096, pbuf, part,
                                                    64, 4096, 4096);
        combine_pam<<<1024, 256, 0, stream>>>(part, X + (long)b * 64 * 4096, IN(12),
                                              pam + (long)b * 64 * 4096, 8);
    }

    // ---- pconv head ----
    conv3x3_bn<<<dim3(64, 2, 4), 256, 0, stream>>>(pam, IN(16), IN(17), IN(18), IN(19), IN(20), IN(21), IN(22), tbuf);
    conv1x1_bn<<<dim3(64, 2), 256, 0, stream>>>(tbuf, IN(23), IN(24), IN(25), IN(26), IN(27), IN(28), IN(29), pam2);

    // ---- guided channel attention ----
    diag_fill<<<64, 256, 0, stream>>>(gramx, 16384, 0.0f);   // gramx+gramg contiguous
    gram_partial<<<dim3(64, 2), 256, 0, stream>>>(pam2, gramx);
    gram_partial<<<dim3(64, 2), 256, 0, stream>>>(G,    gramg);
    se_mean<<<dim3(64, 2), 256, 0, stream>>>(G, gy);
    se_gate<<<2, 64, 0, stream>>>(gy, IN(13), IN(14), gy2);
    cam_small<<<2, 64, 0, stream>>>(gramx, gramg, gy2, gattc);
    cam_apply<<<dim3(64, 2), 256, 0, stream>>>(pam2, gattc, IN(15), cam);

    // ---- cconv + fconv heads ----
    conv3x3_bn<<<dim3(64, 2, 4), 256, 0, stream>>>(cam, IN(30), IN(31), IN(32), IN(33), IN(34), IN(35), IN(36), pam);
    conv1x1_bn<<<dim3(64, 2), 256, 0, stream>>>(pam, IN(37), IN(38), IN(39), IN(40), IN(41), IN(42), IN(43), cam2);
    conv1x1_bn<<<dim3(64, 2), 256, 0, stream>>>(cam2, IN(44), IN(45), IN(46), IN(47), IN(48), IN(49), IN(50), (float*)d_out);
}

// Round 12
// 761.234 us; speedup vs baseline: 4.0428x; 1.1500x over previous
//
#include <hip/hip_runtime.h>
#include <hip/hip_fp8.h>

// ---------------------------------------------------------------------------
// DGNLB fused pipeline.  ALL inputs/outputs are FP32 (reference is jnp.float32).
// B=2, C=64, H=W=64, N=4096.
// R12: gemm_p8 -> MX-scaled fp8 K=128 (mfma_scale_f32_16x16x128_f8f6f4,
//      BK=128, 32 iters, scales=1.0).  Everything else frozen from R11.
// ---------------------------------------------------------------------------

typedef float f32x4 __attribute__((ext_vector_type(4)));
typedef __bf16 bf16x8 __attribute__((ext_vector_type(8)));
typedef int int4v __attribute__((ext_vector_type(4)));
typedef int int8v __attribute__((ext_vector_type(8)));
typedef unsigned short ushort8 __attribute__((ext_vector_type(8)));
typedef unsigned char uchar8 __attribute__((ext_vector_type(8)));

#define DI __device__ __forceinline__

DI float bf2f(unsigned short u) { union { unsigned int i; float f; } x; x.i = ((unsigned int)u) << 16; return x.f; }
DI unsigned short f2bf(float f) { union { float f; unsigned int i; } x; x.f = f; unsigned int r = x.i + 0x7fff + ((x.i >> 16) & 1); return (unsigned short)(r >> 16); }
DI unsigned char f2fp8(float f) { __hip_fp8_e4m3 h(f); return (unsigned char)h.__x; }
DI float sane(float x) { return (x > -1e8f) ? ((x < 1e8f) ? x : 1e8f) : -1e8f; }

// async global->LDS, 16B per lane. LDS dest must be wave-uniform base + lane*16.
DI void async16(const unsigned short* g, unsigned short* l) {
    __builtin_amdgcn_global_load_lds(
        (const __attribute__((address_space(1))) void*)g,
        (__attribute__((address_space(3))) void*)l, 16, 0, 0);
}
DI void async16b(const unsigned char* g, unsigned char* l) {
    __builtin_amdgcn_global_load_lds(
        (const __attribute__((address_space(1))) void*)g,
        (__attribute__((address_space(3))) void*)l, 16, 0, 0);
}

__global__ __launch_bounds__(256) void diag_fill(float* __restrict__ out, int n, float val)
{
    int i = blockIdx.x * 256 + threadIdx.x;
    if (i < n) out[i] = val;
}

// ---------------------------------------------------------------------------
// Score GEMM (K=64 only): C[4096][4096](bf16) = A[4096][64] * B[4096][64]^T.
// No LDS, no barriers (operands L2-resident).
// ---------------------------------------------------------------------------
__global__ __launch_bounds__(256) void gemm_score(
    const unsigned short* __restrict__ A,
    const unsigned short* __restrict__ B,
    unsigned short* __restrict__ C, int N)
{
    const int tid  = threadIdx.x;
    const int bm   = blockIdx.y, bn = blockIdx.x;
    const int lane = tid & 63, wid = tid >> 6;
    const int wm   = (wid >> 1) * 64, wn = (wid & 1) * 64;
    const int l16  = lane & 15, quad = lane >> 4;

    f32x4 acc[4][4] = {};
    bf16x8 af[2][4], bfr[2][4];
    #pragma unroll
    for (int w = 0; w < 2; w++) {
        #pragma unroll
        for (int i = 0; i < 4; i++)
            af[w][i]  = *(const bf16x8*)&A[(long)(bm * 128 + wm + i * 16 + l16) * 64 + w * 32 + quad * 8];
        #pragma unroll
        for (int j = 0; j < 4; j++)
            bfr[w][j] = *(const bf16x8*)&B[(long)(bn * 128 + wn + j * 16 + l16) * 64 + w * 32 + quad * 8];
    }
    #pragma unroll
    for (int w = 0; w < 2; w++)
        #pragma unroll
        for (int i = 0; i < 4; i++)
            #pragma unroll
            for (int j = 0; j < 4; j++)
                acc[i][j] = __builtin_amdgcn_mfma_f32_16x16x32_bf16(af[w][i], bfr[w][j], acc[i][j], 0, 0, 0);

    #pragma unroll
    for (int i = 0; i < 4; i++) {
        int rb = bm * 128 + wm + i * 16 + quad * 4;
        #pragma unroll
        for (int j = 0; j < 4; j++) {
            int col = bn * 128 + wn + j * 16 + l16;
            #pragma unroll
            for (int r = 0; r < 4; r++)
                C[(long)(rb + r) * N + col] = f2bf(acc[i][j][r]);
        }
    }
}

// ---------------------------------------------------------------------------
// NT GEMM bf16 (pam_o): split-K partials fp32.  128x128 tile, BK=32.
// ---------------------------------------------------------------------------
__global__ __launch_bounds__(256, 3) void gemm_nt(
    const unsigned short* __restrict__ A,
    const unsigned short* __restrict__ B,
    float* __restrict__ C,
    int M, int N, int K)
{
    __shared__ __align__(16) unsigned short As[128 * 32];
    __shared__ __align__(16) unsigned short Bs[128 * 32];
    const int tid  = threadIdx.x;
    const int bm   = blockIdx.y, bn = blockIdx.x;
    const int lane = tid & 63, wid = tid >> 6;
    const int wm   = (wid >> 1) * 64, wn = (wid & 1) * 64;
    const int l16  = lane & 15, quad = lane >> 4;

    f32x4 acc[4][4] = {};

    const int Kc   = K / (int)gridDim.z;
    const int kbeg = (int)blockIdx.z * Kc;
    const int nIter = Kc / 32;

    const int row0 = tid >> 2,        cp0 = tid & 3;
    const int row1 = (tid + 256) >> 2, cp1 = (tid + 256) & 3;
    int ar0 = bm * 128 + row0; if (ar0 > M - 1) ar0 = M - 1;
    int ar1 = bm * 128 + row1; if (ar1 > M - 1) ar1 = M - 1;
    const unsigned short* pa0 = &A[(long)ar0 * K + kbeg + ((cp0 ^ (row0 & 3)) * 8)];
    const unsigned short* pa1 = &A[(long)ar1 * K + kbeg + ((cp1 ^ (row1 & 3)) * 8)];
    const unsigned short* pb0 = &B[(long)(bn * 128 + row0) * K + kbeg + ((cp0 ^ (row0 & 3)) * 8)];
    const unsigned short* pb1 = &B[(long)(bn * 128 + row1) * K + kbeg + ((cp1 ^ (row1 & 3)) * 8)];
    unsigned short* la0 = &As[row0 * 32 + cp0 * 8];
    unsigned short* la1 = &As[row1 * 32 + cp1 * 8];
    unsigned short* lb0 = &Bs[row0 * 32 + cp0 * 8];
    unsigned short* lb1 = &Bs[row1 * 32 + cp1 * 8];

    const int sw = (quad ^ (l16 & 3)) * 8;

    for (int it = 0; it < nIter; it++) {
        __syncthreads();
        async16(pa0, la0);
        async16(pa1, la1);
        async16(pb0, lb0);
        async16(pb1, lb1);
        pa0 += 32; pa1 += 32; pb0 += 32; pb1 += 32;
        __syncthreads();
        bf16x8 af[4], bfr[4];
        #pragma unroll
        for (int i = 0; i < 4; i++) af[i]  = *(const bf16x8*)&As[(wm + i * 16 + l16) * 32 + sw];
        #pragma unroll
        for (int j = 0; j < 4; j++) bfr[j] = *(const bf16x8*)&Bs[(wn + j * 16 + l16) * 32 + sw];
        #pragma unroll
        for (int i = 0; i < 4; i++)
            #pragma unroll
            for (int j = 0; j < 4; j++)
                acc[i][j] = __builtin_amdgcn_mfma_f32_16x16x32_bf16(af[i], bfr[j], acc[i][j], 0, 0, 0);
    }

    #pragma unroll
    for (int i = 0; i < 4; i++) {
        int rb = bm * 128 + wm + i * 16 + quad * 4;
        #pragma unroll
        for (int j = 0; j < 4; j++) {
            int col = bn * 128 + wn + j * 16 + l16;
            #pragma unroll
            for (int r = 0; r < 4; r++) {
                int row = rb + r;
                if (row < M)
                    C[(long)blockIdx.z * M * N + (long)row * N + col] = acc[i][j][r];
            }
        }
    }
}

// ---------------------------------------------------------------------------
// MX fp8 NT GEMM: C[4096][4096](bf16) = (A8/256)*(B8/256)^T.
// mfma_scale_f32_16x16x128_f8f6f4 (fp8 e4m3, scales=1.0).  BK=128, 32 iters.
// LDS: 16B chunk cp of row r stored at slot cp^(r&7); reader lane (l16,quad)
// reads slots (2q)^(l16&7) and (2q+1)^(l16&7)  -> 2 lanes/bank-group (free).
// ---------------------------------------------------------------------------
__global__ __launch_bounds__(256, 3) void gemm_p8(
    const unsigned char* __restrict__ A,
    const unsigned char* __restrict__ B,
    unsigned short* __restrict__ C, int N, int K)
{
    __shared__ __align__(16) unsigned char As[128 * 128];
    __shared__ __align__(16) unsigned char Bs[128 * 128];
    const int tid  = threadIdx.x;
    const int bm   = blockIdx.y, bn = blockIdx.x;
    const int lane = tid & 63, wid = tid >> 6;
    const int wm   = (wid >> 1) * 64, wn = (wid & 1) * 64;
    const int l16  = lane & 15, quad = lane >> 4;

    f32x4 acc[4][4] = {};

    // staging: 4 x 16B chunks per matrix per thread per iter
    const unsigned char* pa[4];
    const unsigned char* pb[4];
    unsigned char* la[4];
    unsigned char* lb[4];
    #pragma unroll
    for (int m = 0; m < 4; m++) {
        int ch = tid + m * 256;          // 0..1023
        int row = ch >> 3, sp = ch & 7;
        int cp = sp ^ (row & 7);
        pa[m] = &A[(long)(bm * 128 + row) * K + cp * 16];
        pb[m] = &B[(long)(bn * 128 + row) * K + cp * 16];
        la[m] = &As[row * 128 + sp * 16];
        lb[m] = &Bs[row * 128 + sp * 16];
    }

    const int s0 = ((2 * quad) ^ (l16 & 7)) * 16;
    const int s1 = ((2 * quad + 1) ^ (l16 & 7)) * 16;

    const int nIter = K / 128;
    for (int it = 0; it < nIter; it++) {
        __syncthreads();
        #pragma unroll
        for (int m = 0; m < 4; m++) {
            async16b(pa[m], la[m]);
            async16b(pb[m], lb[m]);
            pa[m] += 128; pb[m] += 128;
        }
        __syncthreads();
        int8v bfr[4];
        #pragma unroll
        for (int j = 0; j < 4; j++) {
            const unsigned char* base = &Bs[(wn + j * 16 + l16) * 128];
            int4v v0 = *(const int4v*)(base + s0);
            int4v v1 = *(const int4v*)(base + s1);
            bfr[j][0] = v0[0]; bfr[j][1] = v0[1]; bfr[j][2] = v0[2]; bfr[j][3] = v0[3];
            bfr[j][4] = v1[0]; bfr[j][5] = v1[1]; bfr[j][6] = v1[2]; bfr[j][7] = v1[3];
        }
        #pragma unroll
        for (int i = 0; i < 4; i++) {
            const unsigned char* base = &As[(wm + i * 16 + l16) * 128];
            int4v v0 = *(const int4v*)(base + s0);
            int4v v1 = *(const int4v*)(base + s1);
            int8v af;
            af[0] = v0[0]; af[1] = v0[1]; af[2] = v0[2]; af[3] = v0[3];
            af[4] = v1[0]; af[5] = v1[1]; af[6] = v1[2]; af[7] = v1[3];
            #pragma unroll
            for (int j = 0; j < 4; j++)
                acc[i][j] = __builtin_amdgcn_mfma_scale_f32_16x16x128_f8f6f4(
                    af, bfr[j], acc[i][j],
                    0, 0,                    // cbsz=fp8(e4m3), blgp=fp8(e4m3)
                    0, 0x7f7f7f7f,           // scale A: opsel 0, e8m0 127 = 1.0
                    0, 0x7f7f7f7f);          // scale B
        }
    }

    const float ds = 1.f / 65536.f;
    #pragma unroll
    for (int i = 0; i < 4; i++) {
        int rb = bm * 128 + wm + i * 16 + quad * 4;
        #pragma unroll
        for (int j = 0; j < 4; j++) {
            int col = bn * 128 + wn + j * 16 + l16;
            #pragma unroll
            for (int r = 0; r < 4; r++)
                C[(long)(rb + r) * N + col] = f2bf(acc[i][j][r] * ds);
        }
    }
}

// ---------------------------------------------------------------------------
// Row softmax bf16 in-place (for P before pam_o).
// ---------------------------------------------------------------------------
__global__ __launch_bounds__(256) void row_softmax(unsigned short* __restrict__ buf)
{
    long row = blockIdx.x;
    unsigned short* p = buf + row * 4096L;
    const int tid = threadIdx.x, lane = tid & 63, wid = tid >> 6;
    float v[16]; float mx = -1e30f;
    #pragma unroll
    for (int t = 0; t < 16; t++) {
        float x = sane(bf2f(p[t * 256 + tid]));
        v[t] = x; mx = fmaxf(mx, x);
    }
    #pragma unroll
    for (int o = 32; o; o >>= 1) mx = fmaxf(mx, __shfl_xor(mx, o, 64));
    __shared__ float rmax[4], rsum[4];
    if (!lane) rmax[wid] = mx;
    __syncthreads();
    mx = fmaxf(fmaxf(rmax[0], rmax[1]), fmaxf(rmax[2], rmax[3]));
    float s = 0.f;
    #pragma unroll
    for (int t = 0; t < 16; t++) { v[t] = __expf(v[t] - mx); s += v[t]; }
    #pragma unroll
    for (int o = 32; o; o >>= 1) s += __shfl_xor(s, o, 64);
    if (!lane) rsum[wid] = s;
    __syncthreads();
    s = rsum[0] + rsum[1] + rsum[2] + rsum[3];
    float inv = 1.f / s;
    #pragma unroll
    for (int t = 0; t < 16; t++) p[t * 256 + tid] = f2bf(v[t] * inv);
}

// ---------------------------------------------------------------------------
// Row softmax bf16 -> fp8 x256 (att path).
// ---------------------------------------------------------------------------
__global__ __launch_bounds__(256) void row_softmax_f8(
    const unsigned short* __restrict__ in, unsigned char* __restrict__ out)
{
    long row = blockIdx.x;
    const unsigned short* p = in + row * 4096L;
    unsigned char* q = out + row * 4096L;
    const int tid = threadIdx.x, lane = tid & 63, wid = tid >> 6;
    float v[16]; float mx = -1e30f;
    #pragma unroll
    for (int t = 0; t < 16; t++) {
        float x = sane(bf2f(p[t * 256 + tid]));
        v[t] = x; mx = fmaxf(mx, x);
    }
    #pragma unroll
    for (int o = 32; o; o >>= 1) mx = fmaxf(mx, __shfl_xor(mx, o, 64));
    __shared__ float rmax[4], rsum[4];
    if (!lane) rmax[wid] = mx;
    __syncthreads();
    mx = fmaxf(fmaxf(rmax[0], rmax[1]), fmaxf(rmax[2], rmax[3]));
    float s = 0.f;
    #pragma unroll
    for (int t = 0; t < 16; t++) { v[t] = __expf(v[t] - mx); s += v[t]; }
    #pragma unroll
    for (int o = 32; o; o >>= 1) s += __shfl_xor(s, o, 64);
    if (!lane) rsum[wid] = s;
    __syncthreads();
    s = rsum[0] + rsum[1] + rsum[2] + rsum[3];
    float inv = 256.f / s;
    #pragma unroll
    for (int t = 0; t < 16; t++) q[t * 256 + tid] = f2fp8(v[t] * inv);
}

// ---------------------------------------------------------------------------
// Column softmax (attS bf16 -> attgF8 fp8 x256), 3 phases.
// ---------------------------------------------------------------------------
__global__ __launch_bounds__(256) void colsm_partial(
    const unsigned short* __restrict__ buf,
    float* __restrict__ pmx, float* __restrict__ psum)
{
    const int tid = threadIdx.x;
    const int colgrp = tid & 63, rg = tid >> 6;
    const int cbase = blockIdx.x * 512 + colgrp * 8;
    const int r0 = blockIdx.y * 128 + rg * 32;
    const unsigned short* p = buf + (long)r0 * 4096 + cbase;
    float mx[8], s[8];
    #pragma unroll
    for (int j = 0; j < 8; j++) { mx[j] = -1e30f; s[j] = 0.f; }
    for (int r = 0; r < 32; r++) {
        ushort8 v = *(const ushort8*)(p + (long)r * 4096);
        #pragma unroll
        for (int j = 0; j < 8; j++) {
            float x = sane(bf2f(v[j]));
            float nm = fmaxf(mx[j], x);
            s[j] = s[j] * __expf(mx[j] - nm) + __expf(x - nm);
            mx[j] = nm;
        }
    }
    __shared__ float smx[4][512], ssm[4][512];
    #pragma unroll
    for (int j = 0; j < 8; j++) { smx[rg][colgrp * 8 + j] = mx[j]; ssm[rg][colgrp * 8 + j] = s[j]; }
    __syncthreads();
    for (int c = tid; c < 512; c += 256) {
        float M = fmaxf(fmaxf(smx[0][c], smx[1][c]), fmaxf(smx[2][c], smx[3][c]));
        float S = 0.f;
        #pragma unroll
        for (int i = 0; i < 4; i++) S += ssm[i][c] * __expf(smx[i][c] - M);
        int col = blockIdx.x * 512 + c;
        pmx[blockIdx.y * 4096 + col] = M;
        psum[blockIdx.y * 4096 + col] = S;
    }
}

__global__ __launch_bounds__(256) void colsm_combine(
    const float* __restrict__ pmx, const float* __restrict__ psum,
    float* __restrict__ gM, float* __restrict__ gInv)
{
    int col = blockIdx.x * 256 + threadIdx.x;   // grid 16
    float M = -1e30f;
    for (int ch = 0; ch < 32; ch++) M = fmaxf(M, pmx[ch * 4096 + col]);
    float S = 0.f;
    for (int ch = 0; ch < 32; ch++) S += psum[ch * 4096 + col] * __expf(pmx[ch * 4096 + col] - M);
    gM[col] = M;
    gInv[col] = 256.f / S;   // fp8 scale folded in
}

__global__ __launch_bounds__(256) void colsm_norm_f8(
    const unsigned short* __restrict__ in, unsigned char* __restrict__ out,
    const float* __restrict__ gM, const float* __restrict__ gInv)
{
    const int tid = threadIdx.x;
    const int colgrp = tid & 63, rg = tid >> 6;
    const int cbase = blockIdx.x * 512 + colgrp * 8;
    const int r0 = blockIdx.y * 128 + rg * 32;
    const unsigned short* p = in + (long)r0 * 4096 + cbase;
    unsigned char* q = out + (long)r0 * 4096 + cbase;
    float M[8], inv[8];
    #pragma unroll
    for (int j = 0; j < 8; j++) { M[j] = gM[cbase + j]; inv[j] = gInv[cbase + j]; }
    for (int r = 0; r < 32; r++) {
        ushort8 v = *(const ushort8*)(p + (long)r * 4096);
        uchar8 o;
        #pragma unroll
        for (int j = 0; j < 8; j++) o[j] = f2fp8(__expf(sane(bf2f(v[j])) - M[j]) * inv[j]);
        *(uchar8*)(q + (long)r * 4096) = o;
    }
}

// ---------------------------------------------------------------------------
// 1x1 conv projections (fp32 -> bf16 operands).
// ---------------------------------------------------------------------------
__global__ __launch_bounds__(256) void proj_nc(
    const float* __restrict__ X, const float* __restrict__ W,
    const float* __restrict__ bias, unsigned short* __restrict__ out)
{
    const int b = blockIdx.y, nt = blockIdx.x, tid = threadIdx.x;
    __shared__ float Xs[64][64];
    __shared__ float Ws[64][65];
    __shared__ float Bb[64];
    for (int f = tid; f < 4096; f += 256) {
        int i = f >> 6, n = f & 63;
        Xs[i][n] = X[((long)b * 64 + i) * 4096 + nt * 64 + n];
        Ws[f & 63][f >> 6] = W[f];
    }
    if (tid < 64) Bb[tid] = bias[tid];
    __syncthreads();
    const int c = tid & 63, g = tid >> 6;
    float acc[16];
    #pragma unroll
    for (int j = 0; j < 16; j++) acc[j] = Bb[c];
    for (int i = 0; i < 64; i++) {
        float wv = Ws[i][c];
        #pragma unroll
        for (int j = 0; j < 16; j++) acc[j] += wv * Xs[i][g + 4 * j];
    }
    unsigned short* ob = out + ((long)b * 4096 + nt * 64) * 64;
    #pragma unroll
    for (int j = 0; j < 16; j++) ob[(g + 4 * j) * 64 + c] = f2bf(acc[j]);
}

__global__ __launch_bounds__(256) void proj_cn(
    const float* __restrict__ X, const float* __restrict__ W,
    const float* __restrict__ bias, unsigned short* __restrict__ out)
{
    const int b = blockIdx.y, nt = blockIdx.x, tid = threadIdx.x;
    __shared__ float Xs[64][64];
    __shared__ float Ws[64][64];
    __shared__ float Bb[64];
    for (int f = tid; f < 4096; f += 256) {
        int i = f >> 6, n = f & 63;
        Xs[i][n] = X[((long)b * 64 + i) * 4096 + nt * 64 + n];
        Ws[f >> 6][f & 63] = W[f];
    }
    if (tid < 64) Bb[tid] = bias[tid];
    __syncthreads();
    const int n = tid & 63, g = tid >> 6;
    float acc[16];
    #pragma unroll
    for (int j = 0; j < 16; j++) acc[j] = Bb[g + 4 * j];
    for (int i = 0; i < 64; i++) {
        float xv = Xs[i][n];
        #pragma unroll
        for (int j = 0; j < 16; j++) acc[j] += Ws[g + 4 * j][i] * xv;
    }
    unsigned short* ob = out + ((long)b * 64) * 4096 + nt * 64;
    #pragma unroll
    for (int j = 0; j < 16; j++) ob[(long)(g + 4 * j) * 4096 + n] = f2bf(acc[j]);
}

// ---------------------------------------------------------------------------
// combine split-K partials: pam = gamma*(sum_k part_k) + x.
// ---------------------------------------------------------------------------
__global__ __launch_bounds__(256) void combine_pam(
    const float* __restrict__ part, const float* __restrict__ x,
    const float* __restrict__ gammaPtr, float* __restrict__ pam, int nsplit)
{
    int i = blockIdx.x * 256 + threadIdx.x;
    float s = 0.f;
    for (int k = 0; k < nsplit; k++) s += part[(long)k * 262144 + i];
    pam[i] = gammaPtr[0] * s + x[i];
}

// ---------------------------------------------------------------------------
// 3x3 conv (SAME) + BN + PReLU, fp32.  Grid (64 h, B, 4 co-groups of 16).
// ---------------------------------------------------------------------------
__global__ __launch_bounds__(256) void conv3x3_bn(
    const float* __restrict__ X, const float* __restrict__ W9,
    const float* __restrict__ bias,
    const float* __restrict__ bns, const float* __restrict__ bnb,
    const float* __restrict__ bnm, const float* __restrict__ bnv,
    const float* __restrict__ prelu, float* __restrict__ out)
{
    const int b = blockIdx.y, h = blockIdx.x, co0 = blockIdx.z * 16, tid = threadIdx.x;
    __shared__ float Ls[3][64][66];
    __shared__ float ep0[64], ep1[64], ep2[64];
    __shared__ float alpha;
    for (int f = tid; f < 3 * 64 * 64; f += 256) {
        int ky = f >> 12, rem = f & 4095, ci = rem >> 6, w = rem & 63;
        int hh = h + ky - 1;
        Ls[ky][ci][w + 1] = (hh >= 0 && hh < 64) ? X[(((long)b * 64 + ci) * 64 + hh) * 64 + w] : 0.f;
    }
    for (int f = tid; f < 192; f += 256) {
        int ky = f >> 6, ci = f & 63;
        Ls[ky][ci][0] = 0.f; Ls[ky][ci][65] = 0.f;
    }
    if (tid < 64) {
        float inv = bns[tid] * rsqrtf(fmaxf(bnv[tid], 0.f) + 1e-5f);
        ep0[tid] = inv; ep1[tid] = bnb[tid] - bnm[tid] * inv; ep2[tid] = bias[tid];
    }
    if (tid == 0) alpha = prelu[0];
    __syncthreads();
    const int w = tid & 63, g = tid >> 6;   // co = co0 + g*4 + j
    float acc[4];
    #pragma unroll
    for (int j = 0; j < 4; j++) acc[j] = ep2[co0 + g * 4 + j];
    for (int ci = 0; ci < 64; ci++) {
        float v0 = Ls[0][ci][w], v1 = Ls[0][ci][w + 1], v2 = Ls[0][ci][w + 2];
        float v3 = Ls[1][ci][w], v4 = Ls[1][ci][w + 1], v5 = Ls[1][ci][w + 2];
        float v6 = Ls[2][ci][w], v7 = Ls[2][ci][w + 1], v8 = Ls[2][ci][w + 2];
        #pragma unroll
        for (int j = 0; j < 4; j++) {
            const float* wp = &W9[((co0 + g * 4 + j) * 64 + ci) * 9];
            acc[j] += wp[0] * v0 + wp[1] * v1 + wp[2] * v2
                    + wp[3] * v3 + wp[4] * v4 + wp[5] * v5
                    + wp[6] * v6 + wp[7] * v7 + wp[8] * v8;
        }
    }
    #pragma unroll
    for (int j = 0; j < 4; j++) {
        int co = co0 + g * 4 + j;
        float y = acc[j] * ep0[co] + ep1[co];
        y = y > 0.f ? y : alpha * y;
        out[(((long)b * 64 + co) * 64 + h) * 64 + w] = y;
    }
}

// ---------------------------------------------------------------------------
// 1x1 conv + BN + PReLU, fp32.
// ---------------------------------------------------------------------------
__global__ __launch_bounds__(256) void conv1x1_bn(
    const float* __restrict__ X, const float* __restrict__ W,
    const float* __restrict__ bias,
    const float* __restrict__ bns, const float* __restrict__ bnb,
    const float* __restrict__ bnm, const float* __restrict__ bnv,
    const float* __restrict__ prelu, float* __restrict__ out)
{
    const int b = blockIdx.y, nt = blockIdx.x, tid = threadIdx.x;
    __shared__ float Xs[64][64];
    __shared__ float Ws[64][64];
    __shared__ float ep0[64], ep1[64], ep2[64];
    __shared__ float alpha;
    for (int f = tid; f < 4096; f += 256) {
        int i = f >> 6, n = f & 63;
        Xs[i][n] = X[((long)b * 64 + i) * 4096 + nt * 64 + n];
        Ws[f >> 6][f & 63] = W[f];
    }
    if (tid < 64) {
        float inv = bns[tid] * rsqrtf(fmaxf(bnv[tid], 0.f) + 1e-5f);
        ep0[tid] = inv; ep1[tid] = bnb[tid] - bnm[tid] * inv; ep2[tid] = bias[tid];
    }
    if (tid == 0) alpha = prelu[0];
    __syncthreads();
    const int n = tid & 63, g = tid >> 6;
    float acc[16];
    #pragma unroll
    for (int j = 0; j < 16; j++) acc[j] = ep2[g + 4 * j];
    for (int i = 0; i < 64; i++) {
        float xv = Xs[i][n];
        #pragma unroll
        for (int j = 0; j < 16; j++) acc[j] += Ws[g + 4 * j][i] * xv;
    }
    #pragma unroll
    for (int j = 0; j < 16; j++) {
        int c = g + 4 * j;
        float y = acc[j] * ep0[c] + ep1[c];
        y = y > 0.f ? y : alpha * y;
        out[((long)b * 64 + c) * 4096 + nt * 64 + n] = y;
    }
}

// ---------------------------------------------------------------------------
// Split-K Gram: grid (64 kchunks, B). atomicAdd combine; out pre-zeroed.
// ---------------------------------------------------------------------------
__global__ __launch_bounds__(256) void gram_partial(
    const float* __restrict__ X, float* __restrict__ out)
{
    const int ch = blockIdx.x, b = blockIdx.y, tid = threadIdx.x;
    __shared__ float Xs[64][65];
    for (int f = tid; f < 4096; f += 256) {
        int ci = f >> 6, kk = f & 63;
        Xs[ci][kk] = X[((long)b * 64 + ci) * 4096 + ch * 64 + kk];
    }
    __syncthreads();
    const int d = tid & 63, g = tid >> 6;
    float acc[16] = {};
    for (int kk = 0; kk < 64; kk++) {
        float xd = Xs[d][kk];
        #pragma unroll
        for (int j = 0; j < 16; j++) acc[j] += Xs[g + 4 * j][kk] * xd;
    }
    #pragma unroll
    for (int j = 0; j < 16; j++)
        atomicAdd(&out[((long)b * 64 + (g + 4 * j)) * 64 + d], acc[j]);
}

// ---------------------------------------------------------------------------
// SE mean + gate.
// ---------------------------------------------------------------------------
__global__ __launch_bounds__(256) void se_mean(
    const float* __restrict__ G, float* __restrict__ gy)
{
    const int c = blockIdx.x, b = blockIdx.y, tid = threadIdx.x;
    const int lane = tid & 63, wid = tid >> 6;
    const float* p = G + ((long)b * 64 + c) * 4096;
    float s = 0.f;
    #pragma unroll
    for (int t = 0; t < 4; t++) {
        f32x4 v = *(const f32x4*)(p + (t * 256 + tid) * 4);
        s += v[0] + v[1] + v[2] + v[3];
    }
    #pragma unroll
    for (int o = 32; o; o >>= 1) s += __shfl_xor(s, o, 64);
    __shared__ float ws[4];
    if (!lane) ws[wid] = s;
    __syncthreads();
    if (tid == 0) gy[b * 64 + c] = (ws[0] + ws[1] + ws[2] + ws[3]) * (1.f / 4096.f);
}

__global__ __launch_bounds__(64) void se_gate(
    const float* __restrict__ gy_in, const float* __restrict__ fc1,
    const float* __restrict__ fc2, float* __restrict__ gy2)
{
    const int b = blockIdx.x, tid = threadIdx.x;
    __shared__ float gy[64], r1[32];
    gy[tid] = gy_in[b * 64 + tid];
    __syncthreads();
    if (tid < 32) {
        float s = 0.f;
        for (int c = 0; c < 64; c++) s += fc1[tid * 64 + c] * gy[c];
        r1[tid] = fmaxf(s, 0.f);
    }
    __syncthreads();
    float s = 0.f;
    for (int r = 0; r < 32; r++) s += fc2[tid * 32 + r] * r1[r];
    gy2[b * 64 + tid] = 1.f / (1.f + __expf(-sane(s)));
}

// ---------------------------------------------------------------------------
// CAM small algebra (64x64 per batch).
// ---------------------------------------------------------------------------
__global__ __launch_bounds__(64) void cam_small(
    const float* __restrict__ gramx, const float* __restrict__ gramg,
    const float* __restrict__ gy2, float* __restrict__ gattc)
{
    const int b = blockIdx.x, tid = threadIdx.x;
    __shared__ float Ac[64][65], Acg[64][65];
    __shared__ float gys[64];
    gys[tid] = gy2[b * 64 + tid];
    __syncthreads();
    {
        const float* r = gramx + ((long)b * 64 + tid) * 64;
        float mx = -1e30f;
        for (int d = 0; d < 64; d++) mx = fmaxf(mx, sane(r[d]));
        float s = 0.f;
        for (int d = 0; d < 64; d++) s += __expf(sane(r[d]) - mx);
        float inv = 1.f / s;
        for (int d = 0; d < 64; d++) Ac[tid][d] = __expf(sane(r[d]) - mx) * inv;
    }
    {
        const float* r = gramg + ((long)b * 64 + tid) * 64;
        float gc = gys[tid];
        float mx = -1e30f;
        for (int d = 0; d < 64; d++) mx = fmaxf(mx, sane(gc * gys[d] * r[d]));
        float s = 0.f;
        for (int d = 0; d < 64; d++) s += __expf(sane(gc * gys[d] * r[d]) - mx);
        float inv = 1.f / s;
        for (int d = 0; d < 64; d++) Acg[tid][d] = __expf(sane(gc * gys[d] * r[d]) - mx) * inv;
    }
    __syncthreads();
    float ge[64];
    float mx1 = -1e30f, mn = 1e30f;
    for (int d = 0; d < 64; d++) {
        float s = 0.f;
        for (int k = 0; k < 64; k++) s += Ac[tid][k] * Acg[k][d];
        ge[d] = s;
        mx1 = fmaxf(mx1, s); mn = fminf(mn, s);
    }
    float M2 = mx1 - mn;
    float s = 0.f;
    for (int d = 0; d < 64; d++) s += __expf((mx1 - ge[d]) - M2);
    float inv = 1.f / s;
    for (int d = 0; d < 64; d++)
        gattc[((long)b * 64 + tid) * 64 + d] = __expf((mx1 - ge[d]) - M2) * inv;
}

// ---------------------------------------------------------------------------
// cam = gamma_c * (gatt_c @ pam2) + pam2   (fp32)
// ---------------------------------------------------------------------------
__global__ __launch_bounds__(256) void cam_apply(
    const float* __restrict__ pam2, const float* __restrict__ gattc,
    const float* __restrict__ gammaPtr, float* __restrict__ cam)
{
    const int b = blockIdx.y, nt = blockIdx.x, tid = threadIdx.x;
    __shared__ float Xs[64][64];
    __shared__ float Gt[64][64];
    for (int f = tid; f < 4096; f += 256) {
        int d = f >> 6, n = f & 63;
        Xs[d][n] = pam2[((long)b * 64 + d) * 4096 + nt * 64 + n];
        Gt[f >> 6][f & 63] = gattc[((long)b * 64 + (f >> 6)) * 64 + (f & 63)];
    }
    __syncthreads();
    const float gamma = gammaPtr[0];
    const int n = tid & 63, g = tid >> 6;
    float acc[16] = {};
    for (int d = 0; d < 64; d++) {
        float xv = Xs[d][n];
        #pragma unroll
        for (int j = 0; j < 16; j++) acc[j] += Gt[g + 4 * j][d] * xv;
    }
    #pragma unroll
    for (int j = 0; j < 16; j++) {
        int c = g + 4 * j;
        cam[((long)b * 64 + c) * 4096 + nt * 64 + n] = gamma * acc[j] + Xs[c][n];
    }
}

// ---------------------------------------------------------------------------
// host
// ---------------------------------------------------------------------------
extern "C" void kernel_launch(void* const* d_in, const int* in_sizes, int n_in,
                              void* d_out, int out_size, void* d_ws, size_t ws_size,
                              hipStream_t stream)
{
    static const int exp_sizes[51] = {
        524288, 524288,
        4096, 64, 4096, 64, 4096, 64, 4096, 64, 4096, 64,
        1, 2048, 2048, 1,
        36864, 64, 64, 64, 64, 64, 1,
        4096, 64, 64, 64, 64, 64, 1,
        36864, 64, 64, 64, 64, 64, 1,
        4096, 64, 64, 64, 64, 64, 1,
        4096, 64, 64, 64, 64, 64, 1
    };
    bool map_ok = (n_in == 51) && (out_size == 524288);
    if (map_ok) for (int i = 0; i < 51; i++) if (in_sizes[i] != exp_sizes[i]) { map_ok = false; break; }

    const int diag_grid = (out_size + 255) / 256;
    if (!map_ok) {
        diag_fill<<<diag_grid, 256, 0, stream>>>((float*)d_out, out_size, 400.0f);
        return;
    }
    const size_t NEED_FULL = 121000000;
    if (ws_size < NEED_FULL) {
        float code = (ws_size >= 88000000) ? 100.0f : (ws_size >= 55000000 ? 200.0f : 300.0f);
        diag_fill<<<diag_grid, 256, 0, stream>>>((float*)d_out, out_size, code);
        return;
    }

    auto IN = [&](int i) { return (const float*)d_in[i]; };
    const float* X = IN(0);
    const float* G = IN(1);

    char* wp_ = (char*)d_ws;
    auto alloc = [&](size_t bytes) -> void* {
        void* p = (void*)wp_;
        wp_ += (bytes + 255) & ~(size_t)255;
        return p;
    };
    unsigned short* qT   = (unsigned short*)alloc(2L * 4096 * 64 * 2);
    unsigned short* kT   = (unsigned short*)alloc(2L * 4096 * 64 * 2);
    unsigned short* qgT  = (unsigned short*)alloc(2L * 4096 * 64 * 2);
    unsigned short* kgT  = (unsigned short*)alloc(2L * 4096 * 64 * 2);
    unsigned short* vC   = (unsigned short*)alloc(2L * 64 * 4096 * 2);
    float* part  = (float*)alloc(8L * 64 * 4096 * 4);     // split-K 8 partials
    float* pam   = (float*)alloc(2L * 64 * 4096 * 4);
    float* tbuf  = (float*)alloc(2L * 64 * 4096 * 4);
    float* pam2  = (float*)alloc(2L * 64 * 4096 * 4);
    float* cam   = (float*)alloc(2L * 64 * 4096 * 4);
    float* gramx = (float*)alloc(2L * 64 * 64 * 4);
    float* gramg = (float*)alloc(2L * 64 * 64 * 4);       // contiguous with gramx
    float* gy    = (float*)alloc(2L * 64 * 4);
    float* gy2   = (float*)alloc(2L * 64 * 4);
    float* gattc = (float*)alloc(2L * 64 * 64 * 4);
    float* pmx   = (float*)alloc(32L * 4096 * 4);
    float* psum  = (float*)alloc(32L * 4096 * 4);
    float* gM    = (float*)alloc(4096L * 4);
    float* gInv  = (float*)alloc(4096L * 4);
    unsigned short* pbuf   = (unsigned short*)alloc(4096L * 4096 * 2);  // scores / P / gatt
    unsigned short* attS   = (unsigned short*)alloc(4096L * 4096 * 2);  // att_g scores (transposed)
    unsigned char*  attF8  = (unsigned char*)alloc(4096L * 4096);      // softmax(att) fp8 x256
    unsigned char*  attgF8 = (unsigned char*)alloc(4096L * 4096);      // colsoftmax(att_g)^T fp8 x256
    float* cam2 = tbuf;   // tbuf free after cconv1; reuse for cam2

    // ---- projections (fp32 -> bf16 operands) ----
    proj_nc<<<dim3(64, 2), 256, 0, stream>>>(X, IN(2),  IN(3),  qT);
    proj_nc<<<dim3(64, 2), 256, 0, stream>>>(X, IN(4),  IN(5),  kT);
    proj_nc<<<dim3(64, 2), 256, 0, stream>>>(G, IN(8),  IN(9),  qgT);
    proj_nc<<<dim3(64, 2), 256, 0, stream>>>(G, IN(10), IN(11), kgT);
    proj_cn<<<dim3(64, 2), 256, 0, stream>>>(X, IN(6),  IN(7),  vC);

    // ---- guided position attention, per batch (reuse big buffers) ----
    for (int b = 0; b < 2; b++) {
        const unsigned short* qTb  = qT  + (long)b * 4096 * 64;
        const unsigned short* kTb  = kT  + (long)b * 4096 * 64;
        const unsigned short* qgTb = qgT + (long)b * 4096 * 64;
        const unsigned short* kgTb = kgT + (long)b * 4096 * 64;
        gemm_score<<<dim3(32, 32), 256, 0, stream>>>(qTb,  kTb,  pbuf, 4096);
        gemm_score<<<dim3(32, 32), 256, 0, stream>>>(kgTb, qgTb, attS, 4096);
        row_softmax_f8<<<4096, 256, 0, stream>>>(pbuf, attF8);
        colsm_partial<<<dim3(8, 32), 256, 0, stream>>>(attS, pmx, psum);
        colsm_combine<<<16, 256, 0, stream>>>(pmx, psum, gM, gInv);
        colsm_norm_f8<<<dim3(8, 32), 256, 0, stream>>>(attS, attgF8, gM, gInv);
        gemm_p8<<<dim3(32, 32), 256, 0, stream>>>(attF8, attgF8, pbuf, 4096, 4096);
        row_softmax<<<4096, 256, 0, stream>>>(pbuf);
        gemm_nt<<<dim3(32, 1, 8), 256, 0, stream>>>(vC + (long)b * 64 * 4096, pbuf, part,
                                                    64, 4096, 4096);
        combine_pam<<<1024, 256, 0, stream>>>(part, X + (long)b * 64 * 4096, IN(12),
                                              pam + (long)b * 64 * 4096, 8);
    }

    // ---- pconv head ----
    conv3x3_bn<<<dim3(64, 2, 4), 256, 0, stream>>>(pam, IN(16), IN(17), IN(18), IN(19), IN(20), IN(21), IN(22), tbuf);
    conv1x1_bn<<<dim3(64, 2), 256, 0, stream>>>(tbuf, IN(23), IN(24), IN(25), IN(26), IN(27), IN(28), IN(29), pam2);

    // ---- guided channel attention ----
    diag_fill<<<64, 256, 0, stream>>>(gramx, 16384, 0.0f);   // gramx+gramg contiguous
    gram_partial<<<dim3(64, 2), 256, 0, stream>>>(pam2, gramx);
    gram_partial<<<dim3(64, 2), 256, 0, stream>>>(G,    gramg);
    se_mean<<<dim3(64, 2), 256, 0, stream>>>(G, gy);
    se_gate<<<2, 64, 0, stream>>>(gy, IN(13), IN(14), gy2);
    cam_small<<<2, 64, 0, stream>>>(gramx, gramg, gy2, gattc);
    cam_apply<<<dim3(64, 2), 256, 0, stream>>>(pam2, gattc, IN(15), cam);

    // ---- cconv + fconv heads ----
    conv3x3_bn<<<dim3(64, 2, 4), 256, 0, stream>>>(cam, IN(30), IN(31), IN(32), IN(33), IN(34), IN(35), IN(36), pam);
    conv1x1_bn<<<dim3(64, 2), 256, 0, stream>>>(pam, IN(37), IN(38), IN(39), IN(40), IN(41), IN(42), IN(43), cam2);
    conv1x1_bn<<<dim3(64, 2), 256, 0, stream>>>(cam2, IN(44), IN(45), IN(46), IN(47), IN(48), IN(49), IN(50), (float*)d_out);
}

// Round 13
// 671.795 us; speedup vs baseline: 4.5810x; 1.1331x over previous
//
#include <hip/hip_runtime.h>
#include <hip/hip_fp8.h>

// ---------------------------------------------------------------------------
// DGNLB fused pipeline.  ALL inputs/outputs are FP32 (reference is jnp.float32).
// B=2, C=64, H=W=64, N=4096.
// R13: attention chain batch-merged (grid z/y = 2) when ws_size >= 248MB,
//      per-batch fallback otherwise.  se_gate folded into cam_small.
//      gemm_p8 (MX K=128) / gemm_nt / gemm_score bodies unchanged from R12.
// ---------------------------------------------------------------------------

typedef float f32x4 __attribute__((ext_vector_type(4)));
typedef __bf16 bf16x8 __attribute__((ext_vector_type(8)));
typedef int int4v __attribute__((ext_vector_type(4)));
typedef int int8v __attribute__((ext_vector_type(8)));
typedef unsigned short ushort8 __attribute__((ext_vector_type(8)));
typedef unsigned char uchar8 __attribute__((ext_vector_type(8)));

#define DI __device__ __forceinline__

DI float bf2f(unsigned short u) { union { unsigned int i; float f; } x; x.i = ((unsigned int)u) << 16; return x.f; }
DI unsigned short f2bf(float f) { union { float f; unsigned int i; } x; x.f = f; unsigned int r = x.i + 0x7fff + ((x.i >> 16) & 1); return (unsigned short)(r >> 16); }
DI unsigned char f2fp8(float f) { __hip_fp8_e4m3 h(f); return (unsigned char)h.__x; }
DI float sane(float x) { return (x > -1e8f) ? ((x < 1e8f) ? x : 1e8f) : -1e8f; }

DI void async16(const unsigned short* g, unsigned short* l) {
    __builtin_amdgcn_global_load_lds(
        (const __attribute__((address_space(1))) void*)g,
        (__attribute__((address_space(3))) void*)l, 16, 0, 0);
}
DI void async16b(const unsigned char* g, unsigned char* l) {
    __builtin_amdgcn_global_load_lds(
        (const __attribute__((address_space(1))) void*)g,
        (__attribute__((address_space(3))) void*)l, 16, 0, 0);
}

__global__ __launch_bounds__(256) void diag_fill(float* __restrict__ out, int n, float val)
{
    int i = blockIdx.x * 256 + threadIdx.x;
    if (i < n) out[i] = val;
}

// ---------------------------------------------------------------------------
// Score GEMM (K=64): C = A[4096][64]*B[4096][64]^T, barrier-free.  z = batch.
// ---------------------------------------------------------------------------
__global__ __launch_bounds__(256) void gemm_score(
    const unsigned short* __restrict__ A,
    const unsigned short* __restrict__ B,
    unsigned short* __restrict__ C, int N, long abStride, long cStride)
{
    A += (long)blockIdx.z * abStride;
    B += (long)blockIdx.z * abStride;
    C += (long)blockIdx.z * cStride;
    const int tid  = threadIdx.x;
    const int bm   = blockIdx.y, bn = blockIdx.x;
    const int lane = tid & 63, wid = tid >> 6;
    const int wm   = (wid >> 1) * 64, wn = (wid & 1) * 64;
    const int l16  = lane & 15, quad = lane >> 4;

    f32x4 acc[4][4] = {};
    bf16x8 af[2][4], bfr[2][4];
    #pragma unroll
    for (int w = 0; w < 2; w++) {
        #pragma unroll
        for (int i = 0; i < 4; i++)
            af[w][i]  = *(const bf16x8*)&A[(long)(bm * 128 + wm + i * 16 + l16) * 64 + w * 32 + quad * 8];
        #pragma unroll
        for (int j = 0; j < 4; j++)
            bfr[w][j] = *(const bf16x8*)&B[(long)(bn * 128 + wn + j * 16 + l16) * 64 + w * 32 + quad * 8];
    }
    #pragma unroll
    for (int w = 0; w < 2; w++)
        #pragma unroll
        for (int i = 0; i < 4; i++)
            #pragma unroll
            for (int j = 0; j < 4; j++)
                acc[i][j] = __builtin_amdgcn_mfma_f32_16x16x32_bf16(af[w][i], bfr[w][j], acc[i][j], 0, 0, 0);

    #pragma unroll
    for (int i = 0; i < 4; i++) {
        int rb = bm * 128 + wm + i * 16 + quad * 4;
        #pragma unroll
        for (int j = 0; j < 4; j++) {
            int col = bn * 128 + wn + j * 16 + l16;
            #pragma unroll
            for (int r = 0; r < 4; r++)
                C[(long)(rb + r) * N + col] = f2bf(acc[i][j][r]);
        }
    }
}

// ---------------------------------------------------------------------------
// NT GEMM bf16 (pam_o): split-K via blockIdx.y (gridDim.y slices), z = batch.
// ---------------------------------------------------------------------------
__global__ __launch_bounds__(256, 3) void gemm_nt(
    const unsigned short* __restrict__ A,
    const unsigned short* __restrict__ B,
    float* __restrict__ C,
    int M, int N, int K, long sA, long sB, long sC)
{
    A += (long)blockIdx.z * sA;
    B += (long)blockIdx.z * sB;
    C += (long)blockIdx.z * sC;
    __shared__ __align__(16) unsigned short As[128 * 32];
    __shared__ __align__(16) unsigned short Bs[128 * 32];
    const int tid  = threadIdx.x;
    const int bn   = blockIdx.x, slice = blockIdx.y;
    const int lane = tid & 63, wid = tid >> 6;
    const int wm   = (wid >> 1) * 64, wn = (wid & 1) * 64;
    const int l16  = lane & 15, quad = lane >> 4;

    f32x4 acc[4][4] = {};

    const int Kc   = K / (int)gridDim.y;
    const int kbeg = slice * Kc;
    const int nIter = Kc / 32;

    const int row0 = tid >> 2,        cp0 = tid & 3;
    const int row1 = (tid + 256) >> 2, cp1 = (tid + 256) & 3;
    int ar0 = row0; if (ar0 > M - 1) ar0 = M - 1;
    int ar1 = row1; if (ar1 > M - 1) ar1 = M - 1;
    const unsigned short* pa0 = &A[(long)ar0 * K + kbeg + ((cp0 ^ (row0 & 3)) * 8)];
    const unsigned short* pa1 = &A[(long)ar1 * K + kbeg + ((cp1 ^ (row1 & 3)) * 8)];
    const unsigned short* pb0 = &B[(long)(bn * 128 + row0) * K + kbeg + ((cp0 ^ (row0 & 3)) * 8)];
    const unsigned short* pb1 = &B[(long)(bn * 128 + row1) * K + kbeg + ((cp1 ^ (row1 & 3)) * 8)];
    unsigned short* la0 = &As[row0 * 32 + cp0 * 8];
    unsigned short* la1 = &As[row1 * 32 + cp1 * 8];
    unsigned short* lb0 = &Bs[row0 * 32 + cp0 * 8];
    unsigned short* lb1 = &Bs[row1 * 32 + cp1 * 8];

    const int sw = (quad ^ (l16 & 3)) * 8;

    for (int it = 0; it < nIter; it++) {
        __syncthreads();
        async16(pa0, la0);
        async16(pa1, la1);
        async16(pb0, lb0);
        async16(pb1, lb1);
        pa0 += 32; pa1 += 32; pb0 += 32; pb1 += 32;
        __syncthreads();
        bf16x8 af[4], bfr[4];
        #pragma unroll
        for (int i = 0; i < 4; i++) af[i]  = *(const bf16x8*)&As[(wm + i * 16 + l16) * 32 + sw];
        #pragma unroll
        for (int j = 0; j < 4; j++) bfr[j] = *(const bf16x8*)&Bs[(wn + j * 16 + l16) * 32 + sw];
        #pragma unroll
        for (int i = 0; i < 4; i++)
            #pragma unroll
            for (int j = 0; j < 4; j++)
                acc[i][j] = __builtin_amdgcn_mfma_f32_16x16x32_bf16(af[i], bfr[j], acc[i][j], 0, 0, 0);
    }

    #pragma unroll
    for (int i = 0; i < 4; i++) {
        int rb = wm + i * 16 + quad * 4;
        #pragma unroll
        for (int j = 0; j < 4; j++) {
            int col = bn * 128 + wn + j * 16 + l16;
            #pragma unroll
            for (int r = 0; r < 4; r++) {
                int row = rb + r;
                if (row < M)
                    C[(long)slice * M * N + (long)row * N + col] = acc[i][j][r];
            }
        }
    }
}

// ---------------------------------------------------------------------------
// MX fp8 NT GEMM: C(bf16) = (A8/256)*(B8/256)^T, K=128 MFMA, BK=128. z=batch.
// ---------------------------------------------------------------------------
__global__ __launch_bounds__(256, 3) void gemm_p8(
    const unsigned char* __restrict__ A,
    const unsigned char* __restrict__ B,
    unsigned short* __restrict__ C, int N, int K,
    long sA, long sB, long sC)
{
    A += (long)blockIdx.z * sA;
    B += (long)blockIdx.z * sB;
    C += (long)blockIdx.z * sC;
    __shared__ __align__(16) unsigned char As[128 * 128];
    __shared__ __align__(16) unsigned char Bs[128 * 128];
    const int tid  = threadIdx.x;
    const int bm   = blockIdx.y, bn = blockIdx.x;
    const int lane = tid & 63, wid = tid >> 6;
    const int wm   = (wid >> 1) * 64, wn = (wid & 1) * 64;
    const int l16  = lane & 15, quad = lane >> 4;

    f32x4 acc[4][4] = {};

    const unsigned char* pa[4];
    const unsigned char* pb[4];
    unsigned char* la[4];
    unsigned char* lb[4];
    #pragma unroll
    for (int m = 0; m < 4; m++) {
        int ch = tid + m * 256;
        int row = ch >> 3, sp = ch & 7;
        int cp = sp ^ (row & 7);
        pa[m] = &A[(long)(bm * 128 + row) * K + cp * 16];
        pb[m] = &B[(long)(bn * 128 + row) * K + cp * 16];
        la[m] = &As[row * 128 + sp * 16];
        lb[m] = &Bs[row * 128 + sp * 16];
    }

    const int s0 = ((2 * quad) ^ (l16 & 7)) * 16;
    const int s1 = ((2 * quad + 1) ^ (l16 & 7)) * 16;

    const int nIter = K / 128;
    for (int it = 0; it < nIter; it++) {
        __syncthreads();
        #pragma unroll
        for (int m = 0; m < 4; m++) {
            async16b(pa[m], la[m]);
            async16b(pb[m], lb[m]);
            pa[m] += 128; pb[m] += 128;
        }
        __syncthreads();
        int8v bfr[4];
        #pragma unroll
        for (int j = 0; j < 4; j++) {
            const unsigned char* base = &Bs[(wn + j * 16 + l16) * 128];
            int4v v0 = *(const int4v*)(base + s0);
            int4v v1 = *(const int4v*)(base + s1);
            bfr[j][0] = v0[0]; bfr[j][1] = v0[1]; bfr[j][2] = v0[2]; bfr[j][3] = v0[3];
            bfr[j][4] = v1[0]; bfr[j][5] = v1[1]; bfr[j][6] = v1[2]; bfr[j][7] = v1[3];
        }
        #pragma unroll
        for (int i = 0; i < 4; i++) {
            const unsigned char* base = &As[(wm + i * 16 + l16) * 128];
            int4v v0 = *(const int4v*)(base + s0);
            int4v v1 = *(const int4v*)(base + s1);
            int8v af;
            af[0] = v0[0]; af[1] = v0[1]; af[2] = v0[2]; af[3] = v0[3];
            af[4] = v1[0]; af[5] = v1[1]; af[6] = v1[2]; af[7] = v1[3];
            #pragma unroll
            for (int j = 0; j < 4; j++)
                acc[i][j] = __builtin_amdgcn_mfma_scale_f32_16x16x128_f8f6f4(
                    af, bfr[j], acc[i][j],
                    0, 0, 0, 0x7f7f7f7f, 0, 0x7f7f7f7f);
        }
    }

    const float ds = 1.f / 65536.f;
    #pragma unroll
    for (int i = 0; i < 4; i++) {
        int rb = bm * 128 + wm + i * 16 + quad * 4;
        #pragma unroll
        for (int j = 0; j < 4; j++) {
            int col = bn * 128 + wn + j * 16 + l16;
            #pragma unroll
            for (int r = 0; r < 4; r++)
                C[(long)(rb + r) * N + col] = f2bf(acc[i][j][r] * ds);
        }
    }
}

// ---------------------------------------------------------------------------
// Row softmax bf16 in-place.  blockIdx.y = batch.
// ---------------------------------------------------------------------------
__global__ __launch_bounds__(256) void row_softmax(unsigned short* __restrict__ buf, long bStride)
{
    unsigned short* p = buf + (long)blockIdx.y * bStride + (long)blockIdx.x * 4096;
    const int tid = threadIdx.x, lane = tid & 63, wid = tid >> 6;
    float v[16]; float mx = -1e30f;
    #pragma unroll
    for (int t = 0; t < 16; t++) {
        float x = sane(bf2f(p[t * 256 + tid]));
        v[t] = x; mx = fmaxf(mx, x);
    }
    #pragma unroll
    for (int o = 32; o; o >>= 1) mx = fmaxf(mx, __shfl_xor(mx, o, 64));
    __shared__ float rmax[4], rsum[4];
    if (!lane) rmax[wid] = mx;
    __syncthreads();
    mx = fmaxf(fmaxf(rmax[0], rmax[1]), fmaxf(rmax[2], rmax[3]));
    float s = 0.f;
    #pragma unroll
    for (int t = 0; t < 16; t++) { v[t] = __expf(v[t] - mx); s += v[t]; }
    #pragma unroll
    for (int o = 32; o; o >>= 1) s += __shfl_xor(s, o, 64);
    if (!lane) rsum[wid] = s;
    __syncthreads();
    s = rsum[0] + rsum[1] + rsum[2] + rsum[3];
    float inv = 1.f / s;
    #pragma unroll
    for (int t = 0; t < 16; t++) p[t * 256 + tid] = f2bf(v[t] * inv);
}

// ---------------------------------------------------------------------------
// Row softmax bf16 -> fp8 x256.  blockIdx.y = batch.
// ---------------------------------------------------------------------------
__global__ __launch_bounds__(256) void row_softmax_f8(
    const unsigned short* __restrict__ in, unsigned char* __restrict__ out,
    long inStride, long outStride)
{
    const unsigned short* p = in + (long)blockIdx.y * inStride + (long)blockIdx.x * 4096;
    unsigned char* q = out + (long)blockIdx.y * outStride + (long)blockIdx.x * 4096;
    const int tid = threadIdx.x, lane = tid & 63, wid = tid >> 6;
    float v[16]; float mx = -1e30f;
    #pragma unroll
    for (int t = 0; t < 16; t++) {
        float x = sane(bf2f(p[t * 256 + tid]));
        v[t] = x; mx = fmaxf(mx, x);
    }
    #pragma unroll
    for (int o = 32; o; o >>= 1) mx = fmaxf(mx, __shfl_xor(mx, o, 64));
    __shared__ float rmax[4], rsum[4];
    if (!lane) rmax[wid] = mx;
    __syncthreads();
    mx = fmaxf(fmaxf(rmax[0], rmax[1]), fmaxf(rmax[2], rmax[3]));
    float s = 0.f;
    #pragma unroll
    for (int t = 0; t < 16; t++) { v[t] = __expf(v[t] - mx); s += v[t]; }
    #pragma unroll
    for (int o = 32; o; o >>= 1) s += __shfl_xor(s, o, 64);
    if (!lane) rsum[wid] = s;
    __syncthreads();
    s = rsum[0] + rsum[1] + rsum[2] + rsum[3];
    float inv = 256.f / s;
    #pragma unroll
    for (int t = 0; t < 16; t++) q[t * 256 + tid] = f2fp8(v[t] * inv);
}

// ---------------------------------------------------------------------------
// Column softmax 3 phases.  blockIdx.z (partial/norm) / blockIdx.y (combine) = batch.
// ---------------------------------------------------------------------------
__global__ __launch_bounds__(256) void colsm_partial(
    const unsigned short* __restrict__ buf,
    float* __restrict__ pmx, float* __restrict__ psum,
    long bufStride, long pStride)
{
    buf  += (long)blockIdx.z * bufStride;
    pmx  += (long)blockIdx.z * pStride;
    psum += (long)blockIdx.z * pStride;
    const int tid = threadIdx.x;
    const int colgrp = tid & 63, rg = tid >> 6;
    const int cbase = blockIdx.x * 512 + colgrp * 8;
    const int r0 = blockIdx.y * 128 + rg * 32;
    const unsigned short* p = buf + (long)r0 * 4096 + cbase;
    float mx[8], s[8];
    #pragma unroll
    for (int j = 0; j < 8; j++) { mx[j] = -1e30f; s[j] = 0.f; }
    for (int r = 0; r < 32; r++) {
        ushort8 v = *(const ushort8*)(p + (long)r * 4096);
        #pragma unroll
        for (int j = 0; j < 8; j++) {
            float x = sane(bf2f(v[j]));
            float nm = fmaxf(mx[j], x);
            s[j] = s[j] * __expf(mx[j] - nm) + __expf(x - nm);
            mx[j] = nm;
        }
    }
    __shared__ float smx[4][512], ssm[4][512];
    #pragma unroll
    for (int j = 0; j < 8; j++) { smx[rg][colgrp * 8 + j] = mx[j]; ssm[rg][colgrp * 8 + j] = s[j]; }
    __syncthreads();
    for (int c = tid; c < 512; c += 256) {
        float M = fmaxf(fmaxf(smx[0][c], smx[1][c]), fmaxf(smx[2][c], smx[3][c]));
        float S = 0.f;
        #pragma unroll
        for (int i = 0; i < 4; i++) S += ssm[i][c] * __expf(smx[i][c] - M);
        int col = blockIdx.x * 512 + c;
        pmx[blockIdx.y * 4096 + col] = M;
        psum[blockIdx.y * 4096 + col] = S;
    }
}

__global__ __launch_bounds__(256) void colsm_combine(
    const float* __restrict__ pmx, const float* __restrict__ psum,
    float* __restrict__ gM, float* __restrict__ gInv,
    long pStride, long gStride)
{
    pmx  += (long)blockIdx.y * pStride;
    psum += (long)blockIdx.y * pStride;
    gM   += (long)blockIdx.y * gStride;
    gInv += (long)blockIdx.y * gStride;
    int col = blockIdx.x * 256 + threadIdx.x;
    float M = -1e30f;
    for (int ch = 0; ch < 32; ch++) M = fmaxf(M, pmx[ch * 4096 + col]);
    float S = 0.f;
    for (int ch = 0; ch < 32; ch++) S += psum[ch * 4096 + col] * __expf(pmx[ch * 4096 + col] - M);
    gM[col] = M;
    gInv[col] = 256.f / S;
}

__global__ __launch_bounds__(256) void colsm_norm_f8(
    const unsigned short* __restrict__ in, unsigned char* __restrict__ out,
    const float* __restrict__ gM, const float* __restrict__ gInv,
    long inStride, long outStride, long gStride)
{
    in   += (long)blockIdx.z * inStride;
    out  += (long)blockIdx.z * outStride;
    gM   += (long)blockIdx.z * gStride;
    gInv += (long)blockIdx.z * gStride;
    const int tid = threadIdx.x;
    const int colgrp = tid & 63, rg = tid >> 6;
    const int cbase = blockIdx.x * 512 + colgrp * 8;
    const int r0 = blockIdx.y * 128 + rg * 32;
    const unsigned short* p = in + (long)r0 * 4096 + cbase;
    unsigned char* q = out + (long)r0 * 4096 + cbase;
    float M[8], inv[8];
    #pragma unroll
    for (int j = 0; j < 8; j++) { M[j] = gM[cbase + j]; inv[j] = gInv[cbase + j]; }
    for (int r = 0; r < 32; r++) {
        ushort8 v = *(const ushort8*)(p + (long)r * 4096);
        uchar8 o;
        #pragma unroll
        for (int j = 0; j < 8; j++) o[j] = f2fp8(__expf(sane(bf2f(v[j])) - M[j]) * inv[j]);
        *(uchar8*)(q + (long)r * 4096) = o;
    }
}

// ---------------------------------------------------------------------------
// 1x1 conv projections (fp32 -> bf16 operands).
// ---------------------------------------------------------------------------
__global__ __launch_bounds__(256) void proj_nc(
    const float* __restrict__ X, const float* __restrict__ W,
    const float* __restrict__ bias, unsigned short* __restrict__ out)
{
    const int b = blockIdx.y, nt = blockIdx.x, tid = threadIdx.x;
    __shared__ float Xs[64][64];
    __shared__ float Ws[64][65];
    __shared__ float Bb[64];
    for (int f = tid; f < 4096; f += 256) {
        int i = f >> 6, n = f & 63;
        Xs[i][n] = X[((long)b * 64 + i) * 4096 + nt * 64 + n];
        Ws[f & 63][f >> 6] = W[f];
    }
    if (tid < 64) Bb[tid] = bias[tid];
    __syncthreads();
    const int c = tid & 63, g = tid >> 6;
    float acc[16];
    #pragma unroll
    for (int j = 0; j < 16; j++) acc[j] = Bb[c];
    for (int i = 0; i < 64; i++) {
        float wv = Ws[i][c];
        #pragma unroll
        for (int j = 0; j < 16; j++) acc[j] += wv * Xs[i][g + 4 * j];
    }
    unsigned short* ob = out + ((long)b * 4096 + nt * 64) * 64;
    #pragma unroll
    for (int j = 0; j < 16; j++) ob[(g + 4 * j) * 64 + c] = f2bf(acc[j]);
}

__global__ __launch_bounds__(256) void proj_cn(
    const float* __restrict__ X, const float* __restrict__ W,
    const float* __restrict__ bias, unsigned short* __restrict__ out)
{
    const int b = blockIdx.y, nt = blockIdx.x, tid = threadIdx.x;
    __shared__ float Xs[64][64];
    __shared__ float Ws[64][64];
    __shared__ float Bb[64];
    for (int f = tid; f < 4096; f += 256) {
        int i = f >> 6, n = f & 63;
        Xs[i][n] = X[((long)b * 64 + i) * 4096 + nt * 64 + n];
        Ws[f >> 6][f & 63] = W[f];
    }
    if (tid < 64) Bb[tid] = bias[tid];
    __syncthreads();
    const int n = tid & 63, g = tid >> 6;
    float acc[16];
    #pragma unroll
    for (int j = 0; j < 16; j++) acc[j] = Bb[g + 4 * j];
    for (int i = 0; i < 64; i++) {
        float xv = Xs[i][n];
        #pragma unroll
        for (int j = 0; j < 16; j++) acc[j] += Ws[g + 4 * j][i] * xv;
    }
    unsigned short* ob = out + ((long)b * 64) * 4096 + nt * 64;
    #pragma unroll
    for (int j = 0; j < 16; j++) ob[(long)(g + 4 * j) * 4096 + n] = f2bf(acc[j]);
}

// ---------------------------------------------------------------------------
// combine split-K partials: pam = gamma*(sum_k part_k) + x.  blockIdx.y = batch.
// ---------------------------------------------------------------------------
__global__ __launch_bounds__(256) void combine_pam(
    const float* __restrict__ part, const float* __restrict__ x,
    const float* __restrict__ gammaPtr, float* __restrict__ pam, int nsplit,
    long sPart, long sX)
{
    part += (long)blockIdx.y * sPart;
    x    += (long)blockIdx.y * sX;
    pam  += (long)blockIdx.y * sX;
    int i = blockIdx.x * 256 + threadIdx.x;
    float s = 0.f;
    for (int k = 0; k < nsplit; k++) s += part[(long)k * 262144 + i];
    pam[i] = gammaPtr[0] * s + x[i];
}

// ---------------------------------------------------------------------------
// 3x3 conv (SAME) + BN + PReLU, fp32.  Grid (64 h, B, 4 co-groups of 16).
// ---------------------------------------------------------------------------
__global__ __launch_bounds__(256) void conv3x3_bn(
    const float* __restrict__ X, const float* __restrict__ W9,
    const float* __restrict__ bias,
    const float* __restrict__ bns, const float* __restrict__ bnb,
    const float* __restrict__ bnm, const float* __restrict__ bnv,
    const float* __restrict__ prelu, float* __restrict__ out)
{
    const int b = blockIdx.y, h = blockIdx.x, co0 = blockIdx.z * 16, tid = threadIdx.x;
    __shared__ float Ls[3][64][66];
    __shared__ float ep0[64], ep1[64], ep2[64];
    __shared__ float alpha;
    for (int f = tid; f < 3 * 64 * 64; f += 256) {
        int ky = f >> 12, rem = f & 4095, ci = rem >> 6, w = rem & 63;
        int hh = h + ky - 1;
        Ls[ky][ci][w + 1] = (hh >= 0 && hh < 64) ? X[(((long)b * 64 + ci) * 64 + hh) * 64 + w] : 0.f;
    }
    for (int f = tid; f < 192; f += 256) {
        int ky = f >> 6, ci = f & 63;
        Ls[ky][ci][0] = 0.f; Ls[ky][ci][65] = 0.f;
    }
    if (tid < 64) {
        float inv = bns[tid] * rsqrtf(fmaxf(bnv[tid], 0.f) + 1e-5f);
        ep0[tid] = inv; ep1[tid] = bnb[tid] - bnm[tid] * inv; ep2[tid] = bias[tid];
    }
    if (tid == 0) alpha = prelu[0];
    __syncthreads();
    const int w = tid & 63, g = tid >> 6;
    float acc[4];
    #pragma unroll
    for (int j = 0; j < 4; j++) acc[j] = ep2[co0 + g * 4 + j];
    for (int ci = 0; ci < 64; ci++) {
        float v0 = Ls[0][ci][w], v1 = Ls[0][ci][w + 1], v2 = Ls[0][ci][w + 2];
        float v3 = Ls[1][ci][w], v4 = Ls[1][ci][w + 1], v5 = Ls[1][ci][w + 2];
        float v6 = Ls[2][ci][w], v7 = Ls[2][ci][w + 1], v8 = Ls[2][ci][w + 2];
        #pragma unroll
        for (int j = 0; j < 4; j++) {
            const float* wp = &W9[((co0 + g * 4 + j) * 64 + ci) * 9];
            acc[j] += wp[0] * v0 + wp[1] * v1 + wp[2] * v2
                    + wp[3] * v3 + wp[4] * v4 + wp[5] * v5
                    + wp[6] * v6 + wp[7] * v7 + wp[8] * v8;
        }
    }
    #pragma unroll
    for (int j = 0; j < 4; j++) {
        int co = co0 + g * 4 + j;
        float y = acc[j] * ep0[co] + ep1[co];
        y = y > 0.f ? y : alpha * y;
        out[(((long)b * 64 + co) * 64 + h) * 64 + w] = y;
    }
}

// ---------------------------------------------------------------------------
// 1x1 conv + BN + PReLU, fp32.
// ---------------------------------------------------------------------------
__global__ __launch_bounds__(256) void conv1x1_bn(
    const float* __restrict__ X, const float* __restrict__ W,
    const float* __restrict__ bias,
    const float* __restrict__ bns, const float* __restrict__ bnb,
    const float* __restrict__ bnm, const float* __restrict__ bnv,
    const float* __restrict__ prelu, float* __restrict__ out)
{
    const int b = blockIdx.y, nt = blockIdx.x, tid = threadIdx.x;
    __shared__ float Xs[64][64];
    __shared__ float Ws[64][64];
    __shared__ float ep0[64], ep1[64], ep2[64];
    __shared__ float alpha;
    for (int f = tid; f < 4096; f += 256) {
        int i = f >> 6, n = f & 63;
        Xs[i][n] = X[((long)b * 64 + i) * 4096 + nt * 64 + n];
        Ws[f >> 6][f & 63] = W[f];
    }
    if (tid < 64) {
        float inv = bns[tid] * rsqrtf(fmaxf(bnv[tid], 0.f) + 1e-5f);
        ep0[tid] = inv; ep1[tid] = bnb[tid] - bnm[tid] * inv; ep2[tid] = bias[tid];
    }
    if (tid == 0) alpha = prelu[0];
    __syncthreads();
    const int n = tid & 63, g = tid >> 6;
    float acc[16];
    #pragma unroll
    for (int j = 0; j < 16; j++) acc[j] = ep2[g + 4 * j];
    for (int i = 0; i < 64; i++) {
        float xv = Xs[i][n];
        #pragma unroll
        for (int j = 0; j < 16; j++) acc[j] += Ws[g + 4 * j][i] * xv;
    }
    #pragma unroll
    for (int j = 0; j < 16; j++) {
        int c = g + 4 * j;
        float y = acc[j] * ep0[c] + ep1[c];
        y = y > 0.f ? y : alpha * y;
        out[((long)b * 64 + c) * 4096 + nt * 64 + n] = y;
    }
}

// ---------------------------------------------------------------------------
// Split-K Gram: grid (64 kchunks, B). atomicAdd; out pre-zeroed.
// ---------------------------------------------------------------------------
__global__ __launch_bounds__(256) void gram_partial(
    const float* __restrict__ X, float* __restrict__ out)
{
    const int ch = blockIdx.x, b = blockIdx.y, tid = threadIdx.x;
    __shared__ float Xs[64][65];
    for (int f = tid; f < 4096; f += 256) {
        int ci = f >> 6, kk = f & 63;
        Xs[ci][kk] = X[((long)b * 64 + ci) * 4096 + ch * 64 + kk];
    }
    __syncthreads();
    const int d = tid & 63, g = tid >> 6;
    float acc[16] = {};
    for (int kk = 0; kk < 64; kk++) {
        float xd = Xs[d][kk];
        #pragma unroll
        for (int j = 0; j < 16; j++) acc[j] += Xs[g + 4 * j][kk] * xd;
    }
    #pragma unroll
    for (int j = 0; j < 16; j++)
        atomicAdd(&out[((long)b * 64 + (g + 4 * j)) * 64 + d], acc[j]);
}

// ---------------------------------------------------------------------------
// SE mean.
// ---------------------------------------------------------------------------
__global__ __launch_bounds__(256) void se_mean(
    const float* __restrict__ G, float* __restrict__ gy)
{
    const int c = blockIdx.x, b = blockIdx.y, tid = threadIdx.x;
    const int lane = tid & 63, wid = tid >> 6;
    const float* p = G + ((long)b * 64 + c) * 4096;
    float s = 0.f;
    #pragma unroll
    for (int t = 0; t < 4; t++) {
        f32x4 v = *(const f32x4*)(p + (t * 256 + tid) * 4);
        s += v[0] + v[1] + v[2] + v[3];
    }
    #pragma unroll
    for (int o = 32; o; o >>= 1) s += __shfl_xor(s, o, 64);
    __shared__ float ws[4];
    if (!lane) ws[wid] = s;
    __syncthreads();
    if (tid == 0) gy[b * 64 + c] = (ws[0] + ws[1] + ws[2] + ws[3]) * (1.f / 4096.f);
}

// ---------------------------------------------------------------------------
// CAM small algebra + SE gate fused (64x64 per batch).
// ---------------------------------------------------------------------------
__global__ __launch_bounds__(64) void cam_small(
    const float* __restrict__ gramx, const float* __restrict__ gramg,
    const float* __restrict__ gy_in, const float* __restrict__ fc1,
    const float* __restrict__ fc2, float* __restrict__ gattc)
{
    const int b = blockIdx.x, tid = threadIdx.x;
    __shared__ float Ac[64][65], Acg[64][65];
    __shared__ float gyv[64], r1[32], gys[64];
    gyv[tid] = gy_in[b * 64 + tid];
    __syncthreads();
    if (tid < 32) {
        float s = 0.f;
        for (int c = 0; c < 64; c++) s += fc1[tid * 64 + c] * gyv[c];
        r1[tid] = fmaxf(s, 0.f);
    }
    __syncthreads();
    {
        float s = 0.f;
        for (int r = 0; r < 32; r++) s += fc2[tid * 32 + r] * r1[r];
        gys[tid] = 1.f / (1.f + __expf(-sane(s)));
    }
    __syncthreads();
    {
        const float* r = gramx + ((long)b * 64 + tid) * 64;
        float mx = -1e30f;
        for (int d = 0; d < 64; d++) mx = fmaxf(mx, sane(r[d]));
        float s = 0.f;
        for (int d = 0; d < 64; d++) s += __expf(sane(r[d]) - mx);
        float inv = 1.f / s;
        for (int d = 0; d < 64; d++) Ac[tid][d] = __expf(sane(r[d]) - mx) * inv;
    }
    {
        const float* r = gramg + ((long)b * 64 + tid) * 64;
        float gc = gys[tid];
        float mx = -1e30f;
        for (int d = 0; d < 64; d++) mx = fmaxf(mx, sane(gc * gys[d] * r[d]));
        float s = 0.f;
        for (int d = 0; d < 64; d++) s += __expf(sane(gc * gys[d] * r[d]) - mx);
        float inv = 1.f / s;
        for (int d = 0; d < 64; d++) Acg[tid][d] = __expf(sane(gc * gys[d] * r[d]) - mx) * inv;
    }
    __syncthreads();
    float ge[64];
    float mx1 = -1e30f, mn = 1e30f;
    for (int d = 0; d < 64; d++) {
        float s = 0.f;
        for (int k = 0; k < 64; k++) s += Ac[tid][k] * Acg[k][d];
        ge[d] = s;
        mx1 = fmaxf(mx1, s); mn = fminf(mn, s);
    }
    float M2 = mx1 - mn;
    float s = 0.f;
    for (int d = 0; d < 64; d++) s += __expf((mx1 - ge[d]) - M2);
    float inv = 1.f / s;
    for (int d = 0; d < 64; d++)
        gattc[((long)b * 64 + tid) * 64 + d] = __expf((mx1 - ge[d]) - M2) * inv;
}

// ---------------------------------------------------------------------------
// cam = gamma_c * (gatt_c @ pam2) + pam2   (fp32)
// ---------------------------------------------------------------------------
__global__ __launch_bounds__(256) void cam_apply(
    const float* __restrict__ pam2, const float* __restrict__ gattc,
    const float* __restrict__ gammaPtr, float* __restrict__ cam)
{
    const int b = blockIdx.y, nt = blockIdx.x, tid = threadIdx.x;
    __shared__ float Xs[64][64];
    __shared__ float Gt[64][64];
    for (int f = tid; f < 4096; f += 256) {
        int d = f >> 6, n = f & 63;
        Xs[d][n] = pam2[((long)b * 64 + d) * 4096 + nt * 64 + n];
        Gt[f >> 6][f & 63] = gattc[((long)b * 64 + (f >> 6)) * 64 + (f & 63)];
    }
    __syncthreads();
    const float gamma = gammaPtr[0];
    const int n = tid & 63, g = tid >> 6;
    float acc[16] = {};
    for (int d = 0; d < 64; d++) {
        float xv = Xs[d][n];
        #pragma unroll
        for (int j = 0; j < 16; j++) acc[j] += Gt[g + 4 * j][d] * xv;
    }
    #pragma unroll
    for (int j = 0; j < 16; j++) {
        int c = g + 4 * j;
        cam[((long)b * 64 + c) * 4096 + nt * 64 + n] = gamma * acc[j] + Xs[c][n];
    }
}

// ---------------------------------------------------------------------------
// host
// ---------------------------------------------------------------------------
extern "C" void kernel_launch(void* const* d_in, const int* in_sizes, int n_in,
                              void* d_out, int out_size, void* d_ws, size_t ws_size,
                              hipStream_t stream)
{
    static const int exp_sizes[51] = {
        524288, 524288,
        4096, 64, 4096, 64, 4096, 64, 4096, 64, 4096, 64,
        1, 2048, 2048, 1,
        36864, 64, 64, 64, 64, 64, 1,
        4096, 64, 64, 64, 64, 64, 1,
        36864, 64, 64, 64, 64, 64, 1,
        4096, 64, 64, 64, 64, 64, 1,
        4096, 64, 64, 64, 64, 64, 1
    };
    bool map_ok = (n_in == 51) && (out_size == 524288);
    if (map_ok) for (int i = 0; i < 51; i++) if (in_sizes[i] != exp_sizes[i]) { map_ok = false; break; }

    const int diag_grid = (out_size + 255) / 256;
    if (!map_ok) {
        diag_fill<<<diag_grid, 256, 0, stream>>>((float*)d_out, out_size, 400.0f);
        return;
    }
    const size_t NEED_FULL = 121000000;
    if (ws_size < NEED_FULL) {
        float code = (ws_size >= 88000000) ? 100.0f : (ws_size >= 55000000 ? 200.0f : 300.0f);
        diag_fill<<<diag_grid, 256, 0, stream>>>((float*)d_out, out_size, code);
        return;
    }
    const bool big = (ws_size >= 248000000);   // two-batch attention buffers
    const int nb = big ? 2 : 1;
    const long NN = 4096L * 4096;

    auto IN = [&](int i) { return (const float*)d_in[i]; };
    const float* X = IN(0);
    const float* G = IN(1);

    char* wp_ = (char*)d_ws;
    auto alloc = [&](size_t bytes) -> void* {
        void* p = (void*)wp_;
        wp_ += (bytes + 255) & ~(size_t)255;
        return p;
    };
    unsigned short* qT   = (unsigned short*)alloc(2L * 4096 * 64 * 2);
    unsigned short* kT   = (unsigned short*)alloc(2L * 4096 * 64 * 2);
    unsigned short* qgT  = (unsigned short*)alloc(2L * 4096 * 64 * 2);
    unsigned short* kgT  = (unsigned short*)alloc(2L * 4096 * 64 * 2);
    unsigned short* vC   = (unsigned short*)alloc(2L * 64 * 4096 * 2);
    float* part  = (float*)alloc((8L * nb) * 64 * 4096 * 4);
    float* pam   = (float*)alloc(2L * 64 * 4096 * 4);
    float* tbuf  = (float*)alloc(2L * 64 * 4096 * 4);
    float* pam2  = (float*)alloc(2L * 64 * 4096 * 4);
    float* cam   = (float*)alloc(2L * 64 * 4096 * 4);
    float* gramx = (float*)alloc(2L * 64 * 64 * 4);
    float* gramg = (float*)alloc(2L * 64 * 64 * 4);
    float* gy    = (float*)alloc(2L * 64 * 4);
    float* gattc = (float*)alloc(2L * 64 * 64 * 4);
    float* pmx   = (float*)alloc((32L * nb) * 4096 * 4);
    float* psum  = (float*)alloc((32L * nb) * 4096 * 4);
    float* gM    = (float*)alloc(4096L * nb * 4);
    float* gInv  = (float*)alloc(4096L * nb * 4);
    unsigned short* pbuf   = (unsigned short*)alloc(NN * 2 * nb);
    unsigned short* attS   = (unsigned short*)alloc(NN * 2 * nb);
    unsigned char*  attF8  = (unsigned char*)alloc(NN * nb);
    unsigned char*  attgF8 = (unsigned char*)alloc(NN * nb);
    float* cam2 = tbuf;

    // ---- projections (fp32 -> bf16 operands) ----
    proj_nc<<<dim3(64, 2), 256, 0, stream>>>(X, IN(2),  IN(3),  qT);
    proj_nc<<<dim3(64, 2), 256, 0, stream>>>(X, IN(4),  IN(5),  kT);
    proj_nc<<<dim3(64, 2), 256, 0, stream>>>(G, IN(8),  IN(9),  qgT);
    proj_nc<<<dim3(64, 2), 256, 0, stream>>>(G, IN(10), IN(11), kgT);
    proj_cn<<<dim3(64, 2), 256, 0, stream>>>(X, IN(6),  IN(7),  vC);

    // ---- guided position attention ----
    const long abStr = 4096L * 64;        // per-batch stride in q/k/v buffers
    const long pStr  = big ? NN : 0;      // per-batch stride in scratch (0 = reuse)
    const long pmStr = big ? 32L * 4096 : 0;
    const long gStr  = big ? 4096L : 0;
    for (int b = 0; b < 2; b += nb) {
        const unsigned short* qTb  = qT  + (long)b * abStr;
        const unsigned short* kTb  = kT  + (long)b * abStr;
        const unsigned short* qgTb = qgT + (long)b * abStr;
        const unsigned short* kgTb = kgT + (long)b * abStr;
        gemm_score<<<dim3(32, 32, nb), 256, 0, stream>>>(qTb,  kTb,  pbuf, 4096, abStr, pStr);
        gemm_score<<<dim3(32, 32, nb), 256, 0, stream>>>(kgTb, qgTb, attS, 4096, abStr, pStr);
        row_softmax_f8<<<dim3(4096, nb), 256, 0, stream>>>(pbuf, attF8, pStr, pStr);
        colsm_partial<<<dim3(8, 32, nb), 256, 0, stream>>>(attS, pmx, psum, pStr, pmStr);
        colsm_combine<<<dim3(16, nb), 256, 0, stream>>>(pmx, psum, gM, gInv, pmStr, gStr);
        colsm_norm_f8<<<dim3(8, 32, nb), 256, 0, stream>>>(attS, attgF8, gM, gInv, pStr, pStr, gStr);
        gemm_p8<<<dim3(32, 32, nb), 256, 0, stream>>>(attF8, attgF8, pbuf, 4096, 4096, pStr, pStr, pStr);
        row_softmax<<<dim3(4096, nb), 256, 0, stream>>>(pbuf, pStr);
        gemm_nt<<<dim3(32, 8, nb), 256, 0, stream>>>(vC + (long)b * abStr, pbuf, part,
                                                     64, 4096, 4096,
                                                     abStr, pStr, big ? 8L * 262144 : 0);
        combine_pam<<<dim3(1024, nb), 256, 0, stream>>>(part, X + (long)b * 262144, IN(12),
                                                        pam + (long)b * 262144, 8,
                                                        big ? 8L * 262144 : 0,
                                                        big ? 262144L : 0);
    }

    // ---- pconv head ----
    conv3x3_bn<<<dim3(64, 2, 4), 256, 0, stream>>>(pam, IN(16), IN(17), IN(18), IN(19), IN(20), IN(21), IN(22), tbuf);
    conv1x1_bn<<<dim3(64, 2), 256, 0, stream>>>(tbuf, IN(23), IN(24), IN(25), IN(26), IN(27), IN(28), IN(29), pam2);

    // ---- guided channel attention ----
    diag_fill<<<64, 256, 0, stream>>>(gramx, 16384, 0.0f);   // gramx+gramg contiguous
    gram_partial<<<dim3(64, 2), 256, 0, stream>>>(pam2, gramx);
    gram_partial<<<dim3(64, 2), 256, 0, stream>>>(G,    gramg);
    se_mean<<<dim3(64, 2), 256, 0, stream>>>(G, gy);
    cam_small<<<2, 64, 0, stream>>>(gramx, gramg, gy, IN(13), IN(14), gattc);
    cam_apply<<<dim3(64, 2), 256, 0, stream>>>(pam2, gattc, IN(15), cam);

    // ---- cconv + fconv heads ----
    conv3x3_bn<<<dim3(64, 2, 4), 256, 0, stream>>>(cam, IN(30), IN(31), IN(32), IN(33), IN(34), IN(35), IN(36), pam);
    conv1x1_bn<<<dim3(64, 2), 256, 0, stream>>>(pam, IN(37), IN(38), IN(39), IN(40), IN(41), IN(42), IN(43), cam2);
    conv1x1_bn<<<dim3(64, 2), 256, 0, stream>>>(cam2, IN(44), IN(45), IN(46), IN(47), IN(48), IN(49), IN(50), (float*)d_out);
}